// Round 2
// baseline (1225.621 us; speedup 1.0000x reference)
//
#include <hip/hip_runtime.h>
#include <hip/hip_fp16.h>
#include <math.h>

#define BB 16
#define HH 512
#define WW 512

__device__ __forceinline__ float ldf(const float* p){ return *p; }
__device__ __forceinline__ float ldf(const __half* p){ return __half2float(*p); }
__device__ __forceinline__ void stf(float* p, float v){ *p = v; }
__device__ __forceinline__ void stf(__half* p, float v){ *p = __float2half(v); }

__device__ __forceinline__ float gelu_tanh(float v){
    float u = 0.7978845608028654f * (v + 0.044715f * v * v * v);
    return 0.5f * v * (1.0f + tanhf(u));
}
__device__ __forceinline__ float diff_round(float x){
    const float TWO_PI = 6.283185307179586f;
    return x - sinf(TWO_PI * x) * (1.0f / TWO_PI);
}

// ---------------- Farid edge filter: edge = sqrt(gx^2+gy^2+1e-8) ----------------
__global__ void farid_kernel(const float* __restrict__ img, float* __restrict__ edge){
    const float p[5] = {0.03032f, 0.249724f, 0.439911f, 0.249724f, 0.03032f};
    const float d[5] = {0.10455f, 0.292315f, 0.0f, -0.292315f, -0.10455f};
    int idx = blockIdx.x * blockDim.x + threadIdx.x;
    if (idx >= BB * HH * WW) return;
    int x = idx % WW;
    int y = (idx / WW) % HH;
    int b = idx / (HH * WW);
    const float* ib = img + (size_t)b * HH * WW;
    float gx = 0.f, gy = 0.f;
    #pragma unroll
    for (int i = 0; i < 5; i++){
        int iy = y + i - 2;
        if (iy < 0 || iy >= HH) continue;
        #pragma unroll
        for (int j = 0; j < 5; j++){
            int ix = x + j - 2;
            if (ix < 0 || ix >= WW) continue;
            float v = ib[iy * WW + ix];
            gx += p[i] * d[j] * v;   // kx = outer(p,d)
            gy += d[i] * p[j] * v;   // ky = outer(d,p)
        }
    }
    edge[idx] = sqrtf(gx * gx + gy * gy + 1e-8f);
}

// ---------------- First conv: 2ch (image,edge) -> 16ch, 3x3, stride 1, pad 1 ----------------
template<typename TOUT>
__global__ void conv_first_kernel(const float* __restrict__ img, const float* __restrict__ edge,
                                  const float* __restrict__ w, const float* __restrict__ bias,
                                  TOUT* __restrict__ out){
    __shared__ float sw[288];
    __shared__ float sb[16];
    for (int i = threadIdx.x; i < 288; i += blockDim.x) sw[i] = w[i];
    if (threadIdx.x < 16) sb[threadIdx.x] = bias[threadIdx.x];
    __syncthreads();
    int idx = blockIdx.x * blockDim.x + threadIdx.x;
    if (idx >= BB * HH * WW) return;
    int x = idx % WW;
    int y = (idx / WW) % HH;
    int b = idx / (HH * WW);
    float acc[16];
    #pragma unroll
    for (int c = 0; c < 16; c++) acc[c] = sb[c];
    for (int ky = 0; ky < 3; ky++){
        int iy = y + ky - 1;
        if (iy < 0 || iy >= HH) continue;
        for (int kx = 0; kx < 3; kx++){
            int ix = x + kx - 1;
            if (ix < 0 || ix >= WW) continue;
            size_t off = ((size_t)b * HH + iy) * WW + ix;
            float v0 = img[off];
            float v1 = edge[off];
            const float* wp = sw + (ky * 3 + kx) * 32;  // (kh,kw,2,16)
            #pragma unroll
            for (int c = 0; c < 16; c++) acc[c] += v0 * wp[c] + v1 * wp[16 + c];
        }
    }
    TOUT* op = out + (size_t)idx * 16;
    #pragma unroll
    for (int c = 0; c < 16; c++) stf(op + c, acc[c]);
}

// ---------------- Generic 3x3 conv, 16 -> 16 channels ----------------
template<typename TIN, typename TOUT>
__global__ void conv3x3_kernel(const TIN* __restrict__ in, const float* __restrict__ w,
                               const float* __restrict__ bias, TOUT* __restrict__ out,
                               int Hin, int Win, int Hout, int Wout, int stride, int pad){
    __shared__ float sw[2304];
    __shared__ float sb[16];
    for (int i = threadIdx.x; i < 2304; i += blockDim.x) sw[i] = w[i];
    if (threadIdx.x < 16) sb[threadIdx.x] = bias[threadIdx.x];
    __syncthreads();
    int idx = blockIdx.x * blockDim.x + threadIdx.x;
    int total = BB * Hout * Wout;
    if (idx >= total) return;
    int x = idx % Wout;
    int y = (idx / Wout) % Hout;
    int b = idx / (Wout * Hout);
    float acc[16];
    #pragma unroll
    for (int c = 0; c < 16; c++) acc[c] = sb[c];
    for (int ky = 0; ky < 3; ky++){
        int iy = y * stride + ky - pad;
        if (iy < 0 || iy >= Hin) continue;
        for (int kx = 0; kx < 3; kx++){
            int ix = x * stride + kx - pad;
            if (ix < 0 || ix >= Win) continue;
            const TIN* ip = in + (((size_t)b * Hin + iy) * Win + ix) * 16;
            const float* wp = sw + (ky * 3 + kx) * 256;  // (kh,kw,16,16)
            #pragma unroll
            for (int ci = 0; ci < 16; ci++){
                float v = ldf(ip + ci);
                #pragma unroll
                for (int co = 0; co < 16; co++) acc[co] += v * wp[ci * 16 + co];
            }
        }
    }
    TOUT* op = out + (size_t)idx * 16;
    #pragma unroll
    for (int c = 0; c < 16; c++) stf(op + c, acc[c]);
}

// ---------------- Instance-norm statistics (sum, sumsq per (b,c)) ----------------
template<typename T>
__global__ void in_stats_kernel(const T* __restrict__ act, float* __restrict__ stats,
                                int HW, int splits){
    __shared__ float s1[256];
    __shared__ float s2[256];
    int b = blockIdx.x / splits;
    int s = blockIdx.x % splits;
    const T* base = act + (size_t)b * HW * 16;
    int total = HW * 16;
    float sum = 0.f, sq = 0.f;
    // stride (splits*256) is a multiple of 16 -> each thread stays on channel (t&15)
    for (int e = s * 256 + threadIdx.x; e < total; e += splits * 256){
        float v = ldf(base + e);
        sum += v;
        sq += v * v;
    }
    int t = threadIdx.x;
    s1[t] = sum; s2[t] = sq;
    __syncthreads();
    for (int off = 128; off >= 16; off >>= 1){
        if (t < off){ s1[t] += s1[t + off]; s2[t] += s2[t + off]; }
        __syncthreads();
    }
    if (t < 16){
        atomicAdd(&stats[b * 16 + t], s1[t]);
        atomicAdd(&stats[256 + b * 16 + t], s2[t]);
    }
}

// ---------------- Normalize + GELU, in place ----------------
template<typename T>
__global__ void in_norm_gelu_kernel(T* __restrict__ act, const float* __restrict__ stats, int HW){
    float invN = 1.f / (float)HW;
    size_t total = (size_t)BB * HW * 16;
    for (size_t idx = (size_t)blockIdx.x * blockDim.x + threadIdx.x; idx < total;
         idx += (size_t)gridDim.x * blockDim.x){
        int c = (int)(idx & 15);
        int b = (int)(idx / ((size_t)HW * 16));
        float mean = stats[b * 16 + c] * invN;
        float var = stats[256 + b * 16 + c] * invN - mean * mean;
        float rstd = rsqrtf(var + 1e-5f);
        float v = (ldf(act + idx) - mean) * rstd;
        stf(act + idx, gelu_tanh(v));
    }
}

// ---------------- Last conv (16->2) + tanh + control points (pads row/col 32 with 0) ----------------
__global__ void conv_last_cps_kernel(const float* __restrict__ act, const float* __restrict__ w,
                                     const float* __restrict__ bias, float* __restrict__ cps){
    int idx = blockIdx.x * blockDim.x + threadIdx.x;
    if (idx >= BB * 33 * 33) return;
    int j = idx % 33;
    int i = (idx / 33) % 33;
    int b = idx / (33 * 33);
    float cy = (float)(i * 16);
    float cx = (float)(j * 16);
    if (i < 32 && j < 32){
        float a0 = bias[0], a1 = bias[1];
        for (int ky = 0; ky < 3; ky++){
            int iy = i + ky - 1;
            if (iy < 0 || iy >= 32) continue;
            for (int kx = 0; kx < 3; kx++){
                int ix = j + kx - 1;
                if (ix < 0 || ix >= 32) continue;
                const float* ip = act + (((size_t)b * 32 + iy) * 32 + ix) * 16;
                const float* wp = w + (ky * 3 + kx) * 32;  // (kh,kw,16,2)
                #pragma unroll
                for (int ci = 0; ci < 16; ci++){
                    float v = ip[ci];
                    a0 += v * wp[ci * 2];
                    a1 += v * wp[ci * 2 + 1];
                }
            }
        }
        cy += tanhf(a0) * 8.f;
        cx += tanhf(a1) * 8.f;
    }
    cps[idx * 2] = cy;
    cps[idx * 2 + 1] = cx;
}

// ---------------- Area loss: one block per superpixel area (16x16) ----------------
__global__ void area_loss_kernel(const float* __restrict__ img, const float* __restrict__ cps,
                                 float* __restrict__ acc){
    __shared__ float s1[256];
    __shared__ float s2[256];
    __shared__ float sh_msum, sh_mean;
    int t = threadIdx.x;
    int aidx = blockIdx.x;            // 0 .. 65535
    int b = aidx >> 12;
    int rem = aidx & 4095;
    int o = rem >> 10;                // offset config: (sy,sx) in {(0,0),(0,8),(8,0),(8,8)}
    int ar = rem & 1023;
    int by = ar >> 5;
    int bx = ar & 31;
    int sy = (o & 2) ? 8 : 0;
    int sx = (o & 1) ? 8 : 0;
    int i = t >> 4;
    int j = t & 15;
    int y = sy - 8 + by * 16 + i;     // original-image coordinates
    int x = sx - 8 + bx * 16 + j;
    float rimg = 0.f;
    if (y >= 0 && y < HH && x >= 0 && x < WW)
        rimg = img[((size_t)b * HH + y) * WW + x];
    float cpy = cps[((b * 33 + by) * 33 + bx) * 2 + 0];
    float cpx = cps[((b * 33 + by) * 33 + bx) * 2 + 1];
    float dy = (float)y - cpy;
    float dx = (float)x - cpx;
    float m = expf(-(dy * dy + dx * dx) * (1.f / 128.f));
    m = diff_round(diff_round(m));
    float masked = rimg * m;
    s1[t] = m; s2[t] = masked;
    __syncthreads();
    for (int off = 128; off > 0; off >>= 1){
        if (t < off){ s1[t] += s1[t + off]; s2[t] += s2[t + off]; }
        __syncthreads();
    }
    if (t == 0){
        float msum = s1[0] + 1e-7f;
        sh_msum = msum;
        sh_mean = (s2[0] + 256.f * 1e-7f) / msum;
    }
    __syncthreads();
    float dev = (masked - sh_mean) * m;
    s1[t] = dev * dev;
    __syncthreads();
    for (int off = 128; off > 0; off >>= 1){
        if (t < off) s1[t] += s1[t + off];
        __syncthreads();
    }
    if (t == 0){
        float varr = (s1[0] + 256.f * 1e-7f) / sh_msum;
        atomicAdd(&acc[blockIdx.x & 63], varr);   // bucketed to reduce contention
    }
}

// ---------------- Edge sampling loss ----------------
__global__ void edge_loss_kernel(const float* __restrict__ edge, const float* __restrict__ cps,
                                 float* __restrict__ acc){
    __shared__ float s1[256];
    int idx = blockIdx.x * blockDim.x + threadIdx.x;
    float v = 0.f;
    if (idx < BB * 1089){
        int b = idx / 1089;
        int p = idx % 1089;
        float y = cps[((size_t)b * 1089 + p) * 2 + 0];
        float x = cps[((size_t)b * 1089 + p) * 2 + 1];
        y = fminf(fmaxf(y, 0.f), 510.999f);
        x = fminf(fmaxf(x, 0.f), 510.999f);
        int y0 = (int)floorf(y);
        int x0 = (int)floorf(x);
        float wy = y - (float)y0;
        float wx = x - (float)x0;
        const float* e = edge + (size_t)b * HH * WW;
        float v00 = e[y0 * WW + x0];
        float v01 = e[y0 * WW + x0 + 1];
        float v10 = e[(y0 + 1) * WW + x0];
        float v11 = e[(y0 + 1) * WW + x0 + 1];
        v = v00 * (1 - wy) * (1 - wx) + v01 * (1 - wy) * wx + v10 * wy * (1 - wx) + v11 * wy * wx;
    }
    int t = threadIdx.x;
    s1[t] = v;
    __syncthreads();
    for (int off = 128; off > 0; off >>= 1){
        if (t < off) s1[t] += s1[t + off];
        __syncthreads();
    }
    if (t == 0) atomicAdd(&acc[64 + (blockIdx.x & 3)], s1[0]);
}

__global__ void finalize_kernel(const float* __restrict__ lacc, float* __restrict__ out){
    float a = 0.f, e = 0.f;
    for (int i = 0; i < 64; i++) a += lacc[i];
    for (int i = 0; i < 4; i++) e += lacc[64 + i];
    out[0] = (a / 65536.f) * (e / 17424.f);
}

extern "C" void kernel_launch(void* const* d_in, const int* in_sizes, int n_in,
                              void* d_out, int out_size, void* d_ws, size_t ws_size,
                              hipStream_t stream) {
    const float* image  = (const float*)d_in[0];
    const float* w_first= (const float*)d_in[1];
    const float* b_first= (const float*)d_in[2];
    const float* w_mid  = (const float*)d_in[3];
    const float* b_mid  = (const float*)d_in[4];
    const float* w_last = (const float*)d_in[5];
    const float* b_last = (const float*)d_in[6];
    float* out = (float*)d_out;
    char* ws = (char*)d_ws;

    // ---- workspace layout (fp16 for the two big activations; ~208 MB total) ----
    float* stats = (float*)ws;                 // 8 layers * 512 floats
    float* lacc  = stats + 8 * 512;            // 128 floats of reduction buckets
    size_t off = (8 * 512 + 128) * sizeof(float);   // 16896 B (multiple of 256)
    float* edge = (float*)(ws + off); off += (size_t)BB * HH * WW * 4;
    float* act4 = (float*)(ws + off); off += (size_t)BB * 64 * 64 * 16 * 4;
    float* act5 = (float*)(ws + off); off += (size_t)BB * 32 * 32 * 16 * 4;
    float* act6 = (float*)(ws + off); off += (size_t)BB * 32 * 32 * 16 * 4;
    float* act3 = (float*)(ws + off); off += (size_t)BB * 128 * 128 * 16 * 4;
    __half* act1 = (__half*)(ws + off); off += (size_t)BB * HH * WW * 16 * 2;
    __half* act2 = (__half*)(ws + off); off += (size_t)BB * 256 * 256 * 16 * 2;

    hipMemsetAsync(ws, 0, (8 * 512 + 128) * sizeof(float), stream);

    int totalPix = BB * HH * WW;               // 4,194,304

    // edge filter
    farid_kernel<<<totalPix / 256, 256, 0, stream>>>(image, edge);

    // layer 0: first conv (2 -> 16) + IN + GELU   (512x512, fp16 storage)
    conv_first_kernel<__half><<<totalPix / 256, 256, 0, stream>>>(image, edge, w_first, b_first, act1);
    in_stats_kernel<__half><<<16 * 64, 256, 0, stream>>>(act1, stats + 0 * 512, 512 * 512, 64);
    in_norm_gelu_kernel<__half><<<8192, 256, 0, stream>>>(act1, stats + 0 * 512, 512 * 512);

    // mid 0: 512 -> 256, stride 2 (SAME pad lo=0)
    conv3x3_kernel<__half, __half><<<(BB * 256 * 256) / 256, 256, 0, stream>>>(
        act1, w_mid + 0 * 2304, b_mid + 0, act2, 512, 512, 256, 256, 2, 0);
    in_stats_kernel<__half><<<16 * 16, 256, 0, stream>>>(act2, stats + 1 * 512, 256 * 256, 16);
    in_norm_gelu_kernel<__half><<<4096, 256, 0, stream>>>(act2, stats + 1 * 512, 256 * 256);

    // mid 1: 256 -> 128, stride 2
    conv3x3_kernel<__half, float><<<(BB * 128 * 128) / 256, 256, 0, stream>>>(
        act2, w_mid + 1 * 2304, b_mid + 16, act3, 256, 256, 128, 128, 2, 0);
    in_stats_kernel<float><<<16 * 4, 256, 0, stream>>>(act3, stats + 2 * 512, 128 * 128, 4);
    in_norm_gelu_kernel<float><<<2048, 256, 0, stream>>>(act3, stats + 2 * 512, 128 * 128);

    // mid 2: 128 -> 64, stride 2
    conv3x3_kernel<float, float><<<(BB * 64 * 64) / 256, 256, 0, stream>>>(
        act3, w_mid + 2 * 2304, b_mid + 32, act4, 128, 128, 64, 64, 2, 0);
    in_stats_kernel<float><<<16 * 4, 256, 0, stream>>>(act4, stats + 3 * 512, 64 * 64, 4);
    in_norm_gelu_kernel<float><<<1024, 256, 0, stream>>>(act4, stats + 3 * 512, 64 * 64);

    // mid 3: 64 -> 32, stride 2
    conv3x3_kernel<float, float><<<(BB * 32 * 32) / 256, 256, 0, stream>>>(
        act4, w_mid + 3 * 2304, b_mid + 48, act5, 64, 64, 32, 32, 2, 0);
    in_stats_kernel<float><<<16 * 4, 256, 0, stream>>>(act5, stats + 4 * 512, 32 * 32, 4);
    in_norm_gelu_kernel<float><<<256, 256, 0, stream>>>(act5, stats + 4 * 512, 32 * 32);

    // mid 4: 32 -> 32, stride 1 (pad 1)
    conv3x3_kernel<float, float><<<(BB * 32 * 32) / 256, 256, 0, stream>>>(
        act5, w_mid + 4 * 2304, b_mid + 64, act6, 32, 32, 32, 32, 1, 1);
    in_stats_kernel<float><<<16 * 4, 256, 0, stream>>>(act6, stats + 5 * 512, 32 * 32, 4);
    in_norm_gelu_kernel<float><<<256, 256, 0, stream>>>(act6, stats + 5 * 512, 32 * 32);

    // mid 5
    conv3x3_kernel<float, float><<<(BB * 32 * 32) / 256, 256, 0, stream>>>(
        act6, w_mid + 5 * 2304, b_mid + 80, act5, 32, 32, 32, 32, 1, 1);
    in_stats_kernel<float><<<16 * 4, 256, 0, stream>>>(act5, stats + 6 * 512, 32 * 32, 4);
    in_norm_gelu_kernel<float><<<256, 256, 0, stream>>>(act5, stats + 6 * 512, 32 * 32);

    // mid 6
    conv3x3_kernel<float, float><<<(BB * 32 * 32) / 256, 256, 0, stream>>>(
        act5, w_mid + 6 * 2304, b_mid + 96, act6, 32, 32, 32, 32, 1, 1);
    in_stats_kernel<float><<<16 * 4, 256, 0, stream>>>(act6, stats + 7 * 512, 32 * 32, 4);
    in_norm_gelu_kernel<float><<<256, 256, 0, stream>>>(act6, stats + 7 * 512, 32 * 32);

    // last conv + tanh + control points -> d_out[1..]
    float* cps_out = out + 1;
    conv_last_cps_kernel<<<(BB * 33 * 33 + 255) / 256, 256, 0, stream>>>(act6, w_last, b_last, cps_out);

    // losses
    area_loss_kernel<<<BB * 4 * 32 * 32, 256, 0, stream>>>(image, cps_out, lacc);
    edge_loss_kernel<<<(BB * 1089 + 255) / 256, 256, 0, stream>>>(edge, cps_out, lacc);
    finalize_kernel<<<1, 1, 0, stream>>>(lacc, out);
}

// Round 3
// 687.603 us; speedup vs baseline: 1.7825x; 1.7825x over previous
//
#include <hip/hip_runtime.h>
#include <hip/hip_fp16.h>
#include <math.h>

#define BB 16
#define HH 512
#define WW 512

// ---------- vector load/store helpers (fp16 <-> fp32 compute) ----------
__device__ __forceinline__ float ldf(const float* p){ return *p; }
__device__ __forceinline__ float ldf(const __half* p){ return __half2float(*p); }

__device__ __forceinline__ float4 ldf4(const float* p){ return *(const float4*)p; }
__device__ __forceinline__ float4 ldf4(const __half* p){
    uint2 u = *(const uint2*)p;
    __half2 h0 = *reinterpret_cast<__half2*>(&u.x);
    __half2 h1 = *reinterpret_cast<__half2*>(&u.y);
    float2 f0 = __half22float2(h0), f1 = __half22float2(h1);
    return make_float4(f0.x, f0.y, f1.x, f1.y);
}
__device__ __forceinline__ void stf4(float* p, float4 v){ *(float4*)p = v; }
__device__ __forceinline__ void stf4(__half* p, float4 v){
    uint2 u;
    __half2 h0 = __floats2half2_rn(v.x, v.y);
    __half2 h1 = __floats2half2_rn(v.z, v.w);
    u.x = *reinterpret_cast<unsigned*>(&h0);
    u.y = *reinterpret_cast<unsigned*>(&h1);
    *(uint2*)p = u;
}

__device__ __forceinline__ void load16(const float* p, float* v){
    #pragma unroll
    for (int i = 0; i < 4; i++){
        float4 f = ((const float4*)p)[i];
        v[4*i] = f.x; v[4*i+1] = f.y; v[4*i+2] = f.z; v[4*i+3] = f.w;
    }
}
__device__ __forceinline__ void load16(const __half* p, float* v){
    #pragma unroll
    for (int i = 0; i < 2; i++){
        uint4 u = ((const uint4*)p)[i];
        unsigned* pu = reinterpret_cast<unsigned*>(&u);
        #pragma unroll
        for (int j = 0; j < 4; j++){
            __half2 h = *reinterpret_cast<__half2*>(&pu[j]);
            float2 f = __half22float2(h);
            v[8*i + 2*j] = f.x; v[8*i + 2*j + 1] = f.y;
        }
    }
}
__device__ __forceinline__ void store16(float* p, const float* v){
    #pragma unroll
    for (int i = 0; i < 4; i++)
        ((float4*)p)[i] = make_float4(v[4*i], v[4*i+1], v[4*i+2], v[4*i+3]);
}
__device__ __forceinline__ void store16(__half* p, const float* v){
    #pragma unroll
    for (int i = 0; i < 2; i++){
        uint4 u;
        unsigned* pu = reinterpret_cast<unsigned*>(&u);
        #pragma unroll
        for (int j = 0; j < 4; j++){
            __half2 h = __floats2half2_rn(v[8*i + 2*j], v[8*i + 2*j + 1]);
            pu[j] = *reinterpret_cast<unsigned*>(&h);
        }
        ((uint4*)p)[i] = u;
    }
}

// ---------- math helpers ----------
__device__ __forceinline__ float gelu_tanh(float v){
    // 0.5*v*(1+tanh(u)) = v - v/(e^{2u}+1)  (saturation-safe: e=inf -> v, e=0 -> 0)
    float u = 0.7978845608028654f * (v + 0.044715f * v * v * v);
    float e = __expf(2.f * u);
    return v - v / (e + 1.f);
}
__device__ __forceinline__ float diff_round(float x){
    const float TWO_PI = 6.283185307179586f;
    const float INV_TWO_PI = 0.15915494309189535f;
    return x - __sinf(TWO_PI * x) * INV_TWO_PI;   // v_sin_f32 after folded mul
}

// ---------------- Farid edge filter: edge = sqrt(gx^2+gy^2+1e-8) ----------------
__global__ void farid_kernel(const float* __restrict__ img, float* __restrict__ edge){
    const float p[5] = {0.03032f, 0.249724f, 0.439911f, 0.249724f, 0.03032f};
    const float d[5] = {0.10455f, 0.292315f, 0.0f, -0.292315f, -0.10455f};
    int idx = blockIdx.x * blockDim.x + threadIdx.x;
    if (idx >= BB * HH * WW) return;
    int x = idx % WW;
    int y = (idx / WW) % HH;
    int b = idx / (HH * WW);
    const float* ib = img + (size_t)b * HH * WW;
    float gx = 0.f, gy = 0.f;
    #pragma unroll
    for (int i = 0; i < 5; i++){
        int iy = y + i - 2;
        if (iy < 0 || iy >= HH) continue;
        #pragma unroll
        for (int j = 0; j < 5; j++){
            int ix = x + j - 2;
            if (ix < 0 || ix >= WW) continue;
            float v = ib[iy * WW + ix];
            gx += p[i] * d[j] * v;
            gy += d[i] * p[j] * v;
        }
    }
    edge[idx] = sqrtf(gx * gx + gy * gy + 1e-8f);
}

// ---------------- First conv: 2ch -> 16ch, 3x3, stride 1, pad 1 ----------------
template<typename TOUT>
__global__ __launch_bounds__(256) void conv_first_kernel(
        const float* __restrict__ img, const float* __restrict__ edge,
        const float* __restrict__ w, const float* __restrict__ bias,
        TOUT* __restrict__ out){
    __shared__ float sw[288];
    __shared__ float sb[16];
    for (int i = threadIdx.x; i < 288; i += blockDim.x) sw[i] = w[i];
    if (threadIdx.x < 16) sb[threadIdx.x] = bias[threadIdx.x];
    __syncthreads();
    int idx = blockIdx.x * blockDim.x + threadIdx.x;
    if (idx >= BB * HH * WW) return;
    int x = idx % WW;
    int y = (idx / WW) % HH;
    int b = idx / (HH * WW);
    float acc[16];
    #pragma unroll
    for (int c = 0; c < 16; c++) acc[c] = sb[c];
    for (int ky = 0; ky < 3; ky++){
        int iy = y + ky - 1;
        if (iy < 0 || iy >= HH) continue;
        for (int kx = 0; kx < 3; kx++){
            int ix = x + kx - 1;
            if (ix < 0 || ix >= WW) continue;
            size_t off = ((size_t)b * HH + iy) * WW + ix;
            float v0 = img[off];
            float v1 = edge[off];
            const float* wp = sw + (ky * 3 + kx) * 32;  // (kh,kw,2,16)
            #pragma unroll
            for (int c = 0; c < 16; c++) acc[c] += v0 * wp[c] + v1 * wp[16 + c];
        }
    }
    store16(out + (size_t)idx * 16, acc);
}

// ---------------- Generic 3x3 conv, 16 -> 16 channels ----------------
template<typename TIN, typename TOUT>
__global__ __launch_bounds__(256) void conv3x3_kernel(
        const TIN* __restrict__ in, const float* __restrict__ w,
        const float* __restrict__ bias, TOUT* __restrict__ out,
        int Hin, int Win, int Hout, int Wout, int stride, int pad){
    __shared__ float sw[2304];
    __shared__ float sb[16];
    for (int i = threadIdx.x; i < 2304; i += blockDim.x) sw[i] = w[i];
    if (threadIdx.x < 16) sb[threadIdx.x] = bias[threadIdx.x];
    __syncthreads();
    int idx = blockIdx.x * blockDim.x + threadIdx.x;
    int total = BB * Hout * Wout;
    if (idx >= total) return;
    int x = idx % Wout;
    int y = (idx / Wout) % Hout;
    int b = idx / (Wout * Hout);
    float acc[16];
    #pragma unroll
    for (int c = 0; c < 16; c++) acc[c] = sb[c];
    for (int ky = 0; ky < 3; ky++){
        int iy = y * stride + ky - pad;
        if (iy < 0 || iy >= Hin) continue;
        for (int kx = 0; kx < 3; kx++){
            int ix = x * stride + kx - pad;
            if (ix < 0 || ix >= Win) continue;
            const TIN* ip = in + (((size_t)b * Hin + iy) * Win + ix) * 16;
            float v[16];
            load16(ip, v);                              // 2x uint4 (half) / 4x float4
            const float* wp = sw + (ky * 3 + kx) * 256; // (kh,kw,16,16)
            #pragma unroll
            for (int ci = 0; ci < 16; ci++){
                #pragma unroll
                for (int co = 0; co < 16; co++) acc[co] += v[ci] * wp[ci * 16 + co];
            }
        }
    }
    store16(out + (size_t)idx * 16, acc);
}

// ---------------- Instance-norm statistics (sum, sumsq per (b,c)), vectorized x4 ----------------
template<typename T>
__global__ __launch_bounds__(256) void in_stats_kernel(
        const T* __restrict__ act, float* __restrict__ stats, int HW, int splits){
    __shared__ float4 s1[256];
    __shared__ float4 s2[256];
    int b = blockIdx.x / splits;
    int s = blockIdx.x % splits;
    const T* base = act + (size_t)b * HW * 16;
    int nvec = HW * 4;                         // groups of 4 channels
    float4 sum = make_float4(0.f,0.f,0.f,0.f);
    float4 sq  = make_float4(0.f,0.f,0.f,0.f);
    for (int g = s * 256 + threadIdx.x; g < nvec; g += splits * 256){
        float4 v = ldf4(base + (size_t)g * 4);
        sum.x += v.x; sum.y += v.y; sum.z += v.z; sum.w += v.w;
        sq.x += v.x*v.x; sq.y += v.y*v.y; sq.z += v.z*v.z; sq.w += v.w*v.w;
    }
    int t = threadIdx.x;
    s1[t] = sum; s2[t] = sq;
    __syncthreads();
    for (int off = 128; off >= 4; off >>= 1){   // off%4==0 keeps channel class
        if (t < off){
            float4 a = s1[t+off], c = s2[t+off];
            s1[t].x += a.x; s1[t].y += a.y; s1[t].z += a.z; s1[t].w += a.w;
            s2[t].x += c.x; s2[t].y += c.y; s2[t].z += c.z; s2[t].w += c.w;
        }
        __syncthreads();
    }
    if (t < 4){
        int c0 = 4 * t;                         // thread t holds channels 4t..4t+3
        float4 a = s1[t], c = s2[t];
        atomicAdd(&stats[b*16 + c0 + 0], a.x);
        atomicAdd(&stats[b*16 + c0 + 1], a.y);
        atomicAdd(&stats[b*16 + c0 + 2], a.z);
        atomicAdd(&stats[b*16 + c0 + 3], a.w);
        atomicAdd(&stats[256 + b*16 + c0 + 0], c.x);
        atomicAdd(&stats[256 + b*16 + c0 + 1], c.y);
        atomicAdd(&stats[256 + b*16 + c0 + 2], c.z);
        atomicAdd(&stats[256 + b*16 + c0 + 3], c.w);
    }
}

// ---------------- Normalize + GELU, in place, vectorized x4 ----------------
template<typename T>
__global__ __launch_bounds__(256) void in_norm_gelu_kernel(
        T* __restrict__ act, const float* __restrict__ stats, int HW){
    __shared__ float smean[256];
    __shared__ float srstd[256];
    int t = threadIdx.x;
    float invN = 1.f / (float)HW;
    {
        float mean = stats[t] * invN;           // t = b*16+c
        float var = stats[256 + t] * invN - mean * mean;
        smean[t] = mean;
        srstd[t] = rsqrtf(var + 1e-5f);
    }
    __syncthreads();
    size_t nvec = (size_t)BB * HW * 4;
    size_t stride = (size_t)gridDim.x * 256;
    for (size_t g = (size_t)blockIdx.x * 256 + t; g < nvec; g += stride){
        int c0 = (int)((g * 4) & 15);
        int bb = (int)(g / ((size_t)HW * 4));
        int si = bb * 16 + c0;
        float4 v = ldf4(act + g * 4);
        v.x = gelu_tanh((v.x - smean[si+0]) * srstd[si+0]);
        v.y = gelu_tanh((v.y - smean[si+1]) * srstd[si+1]);
        v.z = gelu_tanh((v.z - smean[si+2]) * srstd[si+2]);
        v.w = gelu_tanh((v.w - smean[si+3]) * srstd[si+3]);
        stf4(act + g * 4, v);
    }
}

// ---------------- Last conv (16->2) + tanh + control points ----------------
__global__ void conv_last_cps_kernel(const float* __restrict__ act, const float* __restrict__ w,
                                     const float* __restrict__ bias, float* __restrict__ cps){
    int idx = blockIdx.x * blockDim.x + threadIdx.x;
    if (idx >= BB * 33 * 33) return;
    int j = idx % 33;
    int i = (idx / 33) % 33;
    int b = idx / (33 * 33);
    float cy = (float)(i * 16);
    float cx = (float)(j * 16);
    if (i < 32 && j < 32){
        float a0 = bias[0], a1 = bias[1];
        for (int ky = 0; ky < 3; ky++){
            int iy = i + ky - 1;
            if (iy < 0 || iy >= 32) continue;
            for (int kx = 0; kx < 3; kx++){
                int ix = j + kx - 1;
                if (ix < 0 || ix >= 32) continue;
                const float* ip = act + (((size_t)b * 32 + iy) * 32 + ix) * 16;
                const float* wp = w + (ky * 3 + kx) * 32;  // (kh,kw,16,2)
                #pragma unroll
                for (int ci = 0; ci < 16; ci++){
                    float v = ip[ci];
                    a0 += v * wp[ci * 2];
                    a1 += v * wp[ci * 2 + 1];
                }
            }
        }
        cy += tanhf(a0) * 8.f;
        cx += tanhf(a1) * 8.f;
    }
    cps[idx * 2] = cy;
    cps[idx * 2 + 1] = cx;
}

// ---------------- Area loss: one WAVE per 16x16 area, shfl reductions, no barriers ----------------
__global__ __launch_bounds__(256) void area_loss_kernel(
        const float* __restrict__ img, const float* __restrict__ cps,
        float* __restrict__ acc){
    int lane = threadIdx.x & 63;
    int wv = threadIdx.x >> 6;
    int aidx = blockIdx.x * 4 + wv;   // 0 .. 65535
    int b = aidx >> 12;
    int rem = aidx & 4095;
    int o = rem >> 10;                // (sy,sx) in {(0,0),(0,8),(8,0),(8,8)}
    int ar = rem & 1023;
    int by = ar >> 5;
    int bx = ar & 31;
    int sy = (o & 2) ? 8 : 0;
    int sx = (o & 1) ? 8 : 0;
    float cpy = cps[((b * 33 + by) * 33 + bx) * 2 + 0];
    float cpx = cps[((b * 33 + by) * 33 + bx) * 2 + 1];
    int y0 = sy - 8 + by * 16;
    int x0 = sx - 8 + bx * 16;
    float m[4], masked[4];
    float msum = 0.f, s2 = 0.f;
    #pragma unroll
    for (int k = 0; k < 4; k++){
        int t = lane + 64 * k;
        int i = t >> 4, j = t & 15;
        int y = y0 + i, x = x0 + j;
        float r = 0.f;
        if (y >= 0 && y < HH && x >= 0 && x < WW)
            r = img[((size_t)b * HH + y) * WW + x];
        float dy = (float)y - cpy;
        float dx = (float)x - cpx;
        float mm = __expf(-(dy * dy + dx * dx) * (1.f / 128.f));
        mm = diff_round(diff_round(mm));
        m[k] = mm;
        masked[k] = r * mm;
        msum += mm;
        s2 += masked[k];
    }
    #pragma unroll
    for (int off = 32; off >= 1; off >>= 1){
        msum += __shfl_xor(msum, off);
        s2   += __shfl_xor(s2, off);
    }
    msum += 1e-7f;
    float mean = (s2 + 256.f * 1e-7f) / msum;
    float d2 = 0.f;
    #pragma unroll
    for (int k = 0; k < 4; k++){
        float dev = (masked[k] - mean) * m[k];
        d2 += dev * dev;
    }
    #pragma unroll
    for (int off = 32; off >= 1; off >>= 1)
        d2 += __shfl_xor(d2, off);
    if (lane == 0){
        float varr = (d2 + 256.f * 1e-7f) / msum;
        atomicAdd(&acc[aidx & 255], varr);
    }
}

// ---------------- Edge sampling loss ----------------
__global__ void edge_loss_kernel(const float* __restrict__ edge, const float* __restrict__ cps,
                                 float* __restrict__ acc){
    __shared__ float s1[256];
    int idx = blockIdx.x * blockDim.x + threadIdx.x;
    float v = 0.f;
    if (idx < BB * 1089){
        int b = idx / 1089;
        int p = idx % 1089;
        float y = cps[((size_t)b * 1089 + p) * 2 + 0];
        float x = cps[((size_t)b * 1089 + p) * 2 + 1];
        y = fminf(fmaxf(y, 0.f), 510.999f);
        x = fminf(fmaxf(x, 0.f), 510.999f);
        int y0 = (int)floorf(y);
        int x0 = (int)floorf(x);
        float wy = y - (float)y0;
        float wx = x - (float)x0;
        const float* e = edge + (size_t)b * HH * WW;
        float v00 = e[y0 * WW + x0];
        float v01 = e[y0 * WW + x0 + 1];
        float v10 = e[(y0 + 1) * WW + x0];
        float v11 = e[(y0 + 1) * WW + x0 + 1];
        v = v00 * (1 - wy) * (1 - wx) + v01 * (1 - wy) * wx + v10 * wy * (1 - wx) + v11 * wy * wx;
    }
    int t = threadIdx.x;
    s1[t] = v;
    __syncthreads();
    for (int off = 128; off > 0; off >>= 1){
        if (t < off) s1[t] += s1[t + off];
        __syncthreads();
    }
    if (t == 0) atomicAdd(&acc[256 + (blockIdx.x & 3)], s1[0]);
}

__global__ void finalize_kernel(const float* __restrict__ lacc, float* __restrict__ out){
    float a = 0.f, e = 0.f;
    for (int i = 0; i < 256; i++) a += lacc[i];
    for (int i = 0; i < 4; i++) e += lacc[256 + i];
    out[0] = (a / 65536.f) * (e / 17424.f);
}

extern "C" void kernel_launch(void* const* d_in, const int* in_sizes, int n_in,
                              void* d_out, int out_size, void* d_ws, size_t ws_size,
                              hipStream_t stream) {
    const float* image  = (const float*)d_in[0];
    const float* w_first= (const float*)d_in[1];
    const float* b_first= (const float*)d_in[2];
    const float* w_mid  = (const float*)d_in[3];
    const float* b_mid  = (const float*)d_in[4];
    const float* w_last = (const float*)d_in[5];
    const float* b_last = (const float*)d_in[6];
    float* out = (float*)d_out;
    char* ws = (char*)d_ws;

    // ---- workspace layout (fp16 for the two big activations) ----
    float* stats = (float*)ws;                 // 8 layers * 512 floats
    float* lacc  = stats + 8 * 512;            // 512 floats of reduction buckets
    size_t off = (8 * 512 + 512) * sizeof(float);   // 18432 B
    float* edge = (float*)(ws + off); off += (size_t)BB * HH * WW * 4;
    float* act4 = (float*)(ws + off); off += (size_t)BB * 64 * 64 * 16 * 4;
    float* act5 = (float*)(ws + off); off += (size_t)BB * 32 * 32 * 16 * 4;
    float* act6 = (float*)(ws + off); off += (size_t)BB * 32 * 32 * 16 * 4;
    float* act3 = (float*)(ws + off); off += (size_t)BB * 128 * 128 * 16 * 4;
    __half* act1 = (__half*)(ws + off); off += (size_t)BB * HH * WW * 16 * 2;
    __half* act2 = (__half*)(ws + off); off += (size_t)BB * 256 * 256 * 16 * 2;

    hipMemsetAsync(ws, 0, (8 * 512 + 512) * sizeof(float), stream);

    int totalPix = BB * HH * WW;               // 4,194,304

    farid_kernel<<<totalPix / 256, 256, 0, stream>>>(image, edge);

    // layer 0: first conv (2 -> 16) + IN + GELU   (512x512, fp16 storage)
    conv_first_kernel<__half><<<totalPix / 256, 256, 0, stream>>>(image, edge, w_first, b_first, act1);
    in_stats_kernel<__half><<<16 * 64, 256, 0, stream>>>(act1, stats + 0 * 512, 512 * 512, 64);
    in_norm_gelu_kernel<__half><<<4096, 256, 0, stream>>>(act1, stats + 0 * 512, 512 * 512);

    // mid 0: 512 -> 256, stride 2 (SAME pad lo=0)
    conv3x3_kernel<__half, __half><<<(BB * 256 * 256) / 256, 256, 0, stream>>>(
        act1, w_mid + 0 * 2304, b_mid + 0, act2, 512, 512, 256, 256, 2, 0);
    in_stats_kernel<__half><<<16 * 16, 256, 0, stream>>>(act2, stats + 1 * 512, 256 * 256, 16);
    in_norm_gelu_kernel<__half><<<2048, 256, 0, stream>>>(act2, stats + 1 * 512, 256 * 256);

    // mid 1: 256 -> 128, stride 2
    conv3x3_kernel<__half, float><<<(BB * 128 * 128) / 256, 256, 0, stream>>>(
        act2, w_mid + 1 * 2304, b_mid + 16, act3, 256, 256, 128, 128, 2, 0);
    in_stats_kernel<float><<<16 * 4, 256, 0, stream>>>(act3, stats + 2 * 512, 128 * 128, 4);
    in_norm_gelu_kernel<float><<<1024, 256, 0, stream>>>(act3, stats + 2 * 512, 128 * 128);

    // mid 2: 128 -> 64, stride 2
    conv3x3_kernel<float, float><<<(BB * 64 * 64) / 256, 256, 0, stream>>>(
        act3, w_mid + 2 * 2304, b_mid + 32, act4, 128, 128, 64, 64, 2, 0);
    in_stats_kernel<float><<<16 * 4, 256, 0, stream>>>(act4, stats + 3 * 512, 64 * 64, 4);
    in_norm_gelu_kernel<float><<<512, 256, 0, stream>>>(act4, stats + 3 * 512, 64 * 64);

    // mid 3: 64 -> 32, stride 2
    conv3x3_kernel<float, float><<<(BB * 32 * 32) / 256, 256, 0, stream>>>(
        act4, w_mid + 3 * 2304, b_mid + 48, act5, 64, 64, 32, 32, 2, 0);
    in_stats_kernel<float><<<16 * 4, 256, 0, stream>>>(act5, stats + 4 * 512, 32 * 32, 4);
    in_norm_gelu_kernel<float><<<256, 256, 0, stream>>>(act5, stats + 4 * 512, 32 * 32);

    // mid 4: 32 -> 32, stride 1 (pad 1)
    conv3x3_kernel<float, float><<<(BB * 32 * 32) / 256, 256, 0, stream>>>(
        act5, w_mid + 4 * 2304, b_mid + 64, act6, 32, 32, 32, 32, 1, 1);
    in_stats_kernel<float><<<16 * 4, 256, 0, stream>>>(act6, stats + 5 * 512, 32 * 32, 4);
    in_norm_gelu_kernel<float><<<256, 256, 0, stream>>>(act6, stats + 5 * 512, 32 * 32);

    // mid 5
    conv3x3_kernel<float, float><<<(BB * 32 * 32) / 256, 256, 0, stream>>>(
        act6, w_mid + 5 * 2304, b_mid + 80, act5, 32, 32, 32, 32, 1, 1);
    in_stats_kernel<float><<<16 * 4, 256, 0, stream>>>(act5, stats + 6 * 512, 32 * 32, 4);
    in_norm_gelu_kernel<float><<<256, 256, 0, stream>>>(act5, stats + 6 * 512, 32 * 32);

    // mid 6
    conv3x3_kernel<float, float><<<(BB * 32 * 32) / 256, 256, 0, stream>>>(
        act5, w_mid + 6 * 2304, b_mid + 96, act6, 32, 32, 32, 32, 1, 1);
    in_stats_kernel<float><<<16 * 4, 256, 0, stream>>>(act6, stats + 7 * 512, 32 * 32, 4);
    in_norm_gelu_kernel<float><<<256, 256, 0, stream>>>(act6, stats + 7 * 512, 32 * 32);

    // last conv + tanh + control points -> d_out[1..]
    float* cps_out = out + 1;
    conv_last_cps_kernel<<<(BB * 33 * 33 + 255) / 256, 256, 0, stream>>>(act6, w_last, b_last, cps_out);

    // losses
    area_loss_kernel<<<16384, 256, 0, stream>>>(image, cps_out, lacc);
    edge_loss_kernel<<<(BB * 1089 + 255) / 256, 256, 0, stream>>>(edge, cps_out, lacc);
    finalize_kernel<<<1, 1, 0, stream>>>(lacc, out);
}

// Round 4
// 545.071 us; speedup vs baseline: 2.2486x; 1.2615x over previous
//
#include <hip/hip_runtime.h>
#include <hip/hip_fp16.h>
#include <math.h>

#define BB 16
#define HH 512
#define WW 512

// ---------- vector load/store helpers (fp16 <-> fp32 compute) ----------
__device__ __forceinline__ void load16(const float* p, float* v){
    #pragma unroll
    for (int i = 0; i < 4; i++){
        float4 f = ((const float4*)p)[i];
        v[4*i] = f.x; v[4*i+1] = f.y; v[4*i+2] = f.z; v[4*i+3] = f.w;
    }
}
__device__ __forceinline__ void load16(const __half* p, float* v){
    #pragma unroll
    for (int i = 0; i < 2; i++){
        uint4 u = ((const uint4*)p)[i];
        unsigned* pu = reinterpret_cast<unsigned*>(&u);
        #pragma unroll
        for (int j = 0; j < 4; j++){
            __half2 h = *reinterpret_cast<__half2*>(&pu[j]);
            float2 f = __half22float2(h);
            v[8*i + 2*j] = f.x; v[8*i + 2*j + 1] = f.y;
        }
    }
}
__device__ __forceinline__ void store16(float* p, const float* v){
    #pragma unroll
    for (int i = 0; i < 4; i++)
        ((float4*)p)[i] = make_float4(v[4*i], v[4*i+1], v[4*i+2], v[4*i+3]);
}
__device__ __forceinline__ void store16(__half* p, const float* v){
    #pragma unroll
    for (int i = 0; i < 2; i++){
        uint4 u;
        unsigned* pu = reinterpret_cast<unsigned*>(&u);
        #pragma unroll
        for (int j = 0; j < 4; j++){
            __half2 h = __floats2half2_rn(v[8*i + 2*j], v[8*i + 2*j + 1]);
            pu[j] = *reinterpret_cast<unsigned*>(&h);
        }
        ((uint4*)p)[i] = u;
    }
}

// ---------- math helpers ----------
__device__ __forceinline__ float gelu_tanh(float v){
    // 0.5*v*(1+tanh(u)) = v - v/(e^{2u}+1); rcp is v_rcp_f32 (~1 ulp, fine)
    float u = 0.7978845608028654f * (v + 0.044715f * v * v * v);
    float e = __expf(2.f * u);
    return v - v * __builtin_amdgcn_rcpf(e + 1.f);
}
__device__ __forceinline__ void norm_gelu16(float* v, const float* snm){
    #pragma unroll
    for (int c = 0; c < 16; c++){
        float x = (v[c] - snm[c]) * snm[16 + c];
        v[c] = gelu_tanh(x);
    }
}
__device__ __forceinline__ float diff_round(float x){
    const float TWO_PI = 6.283185307179586f;
    const float INV_TWO_PI = 0.15915494309189535f;
    return x - __sinf(TWO_PI * x) * INV_TWO_PI;
}

// ---------------- Farid edge filter ----------------
__global__ void farid_kernel(const float* __restrict__ img, float* __restrict__ edge){
    const float p[5] = {0.03032f, 0.249724f, 0.439911f, 0.249724f, 0.03032f};
    const float d[5] = {0.10455f, 0.292315f, 0.0f, -0.292315f, -0.10455f};
    int idx = blockIdx.x * blockDim.x + threadIdx.x;
    if (idx >= BB * HH * WW) return;
    int x = idx % WW;
    int y = (idx / WW) % HH;
    int b = idx / (HH * WW);
    const float* ib = img + (size_t)b * HH * WW;
    float gx = 0.f, gy = 0.f;
    #pragma unroll
    for (int i = 0; i < 5; i++){
        int iy = y + i - 2;
        if (iy < 0 || iy >= HH) continue;
        #pragma unroll
        for (int j = 0; j < 5; j++){
            int ix = x + j - 2;
            if (ix < 0 || ix >= WW) continue;
            float v = ib[iy * WW + ix];
            gx += p[i] * d[j] * v;
            gy += d[i] * p[j] * v;
        }
    }
    edge[idx] = sqrtf(gx * gx + gy * gy + 1e-8f);
}

// ---------- block stats epilogue: LDS transpose reduce of acc[16] -> atomic sum/sumsq ----------
// smem must have >= 4352 floats free (reused after a sync; sw is dead by then).
__device__ __forceinline__ void stats_epilogue(float* smem, const float* acc,
                                               float* stats_out, int bB){
    int t = threadIdx.x;
    __syncthreads();                       // everyone done with sw region
    #pragma unroll
    for (int c = 0; c < 16; c++) smem[t * 17 + c] = acc[c];
    __syncthreads();
    int cc = t & 15;
    int r0 = (t >> 4) << 4;
    float s = 0.f, q = 0.f;
    #pragma unroll
    for (int i = 0; i < 16; i++){
        float v = smem[(r0 + i) * 17 + cc];
        s += v; q += v * v;
    }
    __syncthreads();
    smem[t] = s; smem[256 + t] = q;
    __syncthreads();
    if (t < 32){
        bool isq = t >= 16;
        int c2 = t & 15;
        const float* p = smem + (isq ? 256 : 0);
        float a = 0.f;
        #pragma unroll
        for (int k = 0; k < 16; k++) a += p[k * 16 + c2];
        atomicAdd(&stats_out[(isq ? 256 : 0) + bB * 16 + c2], a);
    }
}

// ---------------- First conv: 2ch -> 16ch, 3x3, s1 p1, + stats epilogue ----------------
__global__ __launch_bounds__(256) void conv_first_kernel(
        const float* __restrict__ img, const float* __restrict__ edge,
        const float* __restrict__ w, const float* __restrict__ bias,
        __half* __restrict__ out, float* __restrict__ stats_out){
    __shared__ float smem[4352];
    __shared__ float sb[16];
    for (int i = threadIdx.x; i < 288; i += blockDim.x) smem[i] = w[i];
    if (threadIdx.x < 16) sb[threadIdx.x] = bias[threadIdx.x];
    __syncthreads();
    int idx = blockIdx.x * blockDim.x + threadIdx.x;
    int x = idx % WW;
    int y = (idx / WW) % HH;
    int b = idx / (HH * WW);
    float acc[16];
    #pragma unroll
    for (int c = 0; c < 16; c++) acc[c] = sb[c];
    for (int ky = 0; ky < 3; ky++){
        int iy = y + ky - 1;
        if (iy < 0 || iy >= HH) continue;
        for (int kx = 0; kx < 3; kx++){
            int ix = x + kx - 1;
            if (ix < 0 || ix >= WW) continue;
            size_t off = ((size_t)b * HH + iy) * WW + ix;
            float v0 = img[off];
            float v1 = edge[off];
            const float* wp = smem + (ky * 3 + kx) * 32;  // (kh,kw,2,16)
            #pragma unroll
            for (int c = 0; c < 16; c++) acc[c] += v0 * wp[c] + v1 * wp[16 + c];
        }
    }
    store16(out + (size_t)idx * 16, acc);
    stats_epilogue(smem, acc, stats_out, b);
}

// ---------------- Generic 3x3 conv 16->16, norm+gelu on load, stats epilogue ----------------
template<typename TIN, typename TOUT>
__global__ __launch_bounds__(256) void conv3x3_kernel(
        const TIN* __restrict__ in, const float* __restrict__ w,
        const float* __restrict__ bias, TOUT* __restrict__ out,
        const float* __restrict__ stats_in, float* __restrict__ stats_out,
        int Hin, int Win, int Hout, int Wout, int stride, int pad){
    __shared__ float smem[4352];          // sw[2304] during main loop; reduce buffer after
    __shared__ float sb[16];
    __shared__ float snm[32];             // mean[16], rstd[16] (survives main loop)
    int t = threadIdx.x;
    int pixPerB = Hout * Wout;
    int bB = blockIdx.x / (pixPerB >> 8); // 256 threads/block, pixPerB % 256 == 0
    for (int i = t; i < 2304; i += blockDim.x) smem[i] = w[i];
    if (t < 16) sb[t] = bias[t];
    if (t >= 32 && t < 48){
        int c = t - 32;
        float invN = 1.f / (float)(Hin * Win);
        float mean = stats_in[bB * 16 + c] * invN;
        float var = stats_in[256 + bB * 16 + c] * invN - mean * mean;
        snm[c] = mean;
        snm[16 + c] = rsqrtf(var + 1e-5f);
    }
    __syncthreads();
    int idx = blockIdx.x * blockDim.x + t;
    int x = idx % Wout;
    int y = (idx / Wout) % Hout;
    int b = idx / pixPerB;
    float acc[16];
    #pragma unroll
    for (int c = 0; c < 16; c++) acc[c] = sb[c];
    for (int ky = 0; ky < 3; ky++){
        int iy = y * stride + ky - pad;
        if (iy < 0 || iy >= Hin) continue;
        for (int kx = 0; kx < 3; kx++){
            int ix = x * stride + kx - pad;
            if (ix < 0 || ix >= Win) continue;
            const TIN* ip = in + (((size_t)b * Hin + iy) * Win + ix) * 16;
            float v[16];
            load16(ip, v);
            norm_gelu16(v, snm);                       // norm+gelu fused on load
            const float* wp = smem + (ky * 3 + kx) * 256;
            #pragma unroll
            for (int ci = 0; ci < 16; ci++){
                #pragma unroll
                for (int co = 0; co < 16; co++) acc[co] += v[ci] * wp[ci * 16 + co];
            }
        }
    }
    store16(out + (size_t)idx * 16, acc);
    stats_epilogue(smem, acc, stats_out, bB);
}

// ---------------- Last conv (16->2), norm+gelu on load, tanh, control points ----------------
__global__ void conv_last_cps_kernel(const float* __restrict__ act, const float* __restrict__ w,
                                     const float* __restrict__ bias,
                                     const float* __restrict__ stats,
                                     float* __restrict__ cps){
    int idx = blockIdx.x * blockDim.x + threadIdx.x;
    if (idx >= BB * 33 * 33) return;
    int j = idx % 33;
    int i = (idx / 33) % 33;
    int b = idx / (33 * 33);
    float cy = (float)(i * 16);
    float cx = (float)(j * 16);
    if (i < 32 && j < 32){
        float mean[16], rstd[16];
        const float invN = 1.f / 1024.f;
        #pragma unroll
        for (int c = 0; c < 16; c++){
            float mm = stats[b * 16 + c] * invN;
            float vv = stats[256 + b * 16 + c] * invN - mm * mm;
            mean[c] = mm;
            rstd[c] = rsqrtf(vv + 1e-5f);
        }
        float a0 = bias[0], a1 = bias[1];
        for (int ky = 0; ky < 3; ky++){
            int iy = i + ky - 1;
            if (iy < 0 || iy >= 32) continue;
            for (int kx = 0; kx < 3; kx++){
                int ix = j + kx - 1;
                if (ix < 0 || ix >= 32) continue;
                const float* ip = act + (((size_t)b * 32 + iy) * 32 + ix) * 16;
                const float* wp = w + (ky * 3 + kx) * 32;  // (kh,kw,16,2)
                #pragma unroll
                for (int ci = 0; ci < 16; ci++){
                    float v = gelu_tanh((ip[ci] - mean[ci]) * rstd[ci]);
                    a0 += v * wp[ci * 2];
                    a1 += v * wp[ci * 2 + 1];
                }
            }
        }
        cy += tanhf(a0) * 8.f;
        cx += tanhf(a1) * 8.f;
    }
    cps[idx * 2] = cy;
    cps[idx * 2 + 1] = cx;
}

// ---------------- Area loss: 16-lane group per area, single-pass variance ----------------
// varr = (C - 2*mean*D + mean^2*E + n*eps) / (A + eps), mean = (B + n*eps)/(A + eps)
// A=sum(m) B=sum(r*m) C=sum((r*m)^2*m^2) D=sum(r*m^3) E=sum(m^2)
__global__ __launch_bounds__(256) void area_loss_kernel(
        const float* __restrict__ img, const float* __restrict__ cps,
        float* __restrict__ acc){
    __shared__ float sv[16];
    int t = threadIdx.x;
    int lane = t & 63;
    int wv = t >> 6;
    int g = lane >> 4;
    int l2 = lane & 15;
    int aidx = blockIdx.x * 16 + wv * 4 + g;   // 0 .. 65535
    int b = aidx >> 12;
    int rem = aidx & 4095;
    int o = rem >> 10;
    int ar = rem & 1023;
    int by = ar >> 5;
    int bx = ar & 31;
    int sy = (o & 2) ? 8 : 0;
    int sx = (o & 1) ? 8 : 0;
    float cpy = cps[((b * 33 + by) * 33 + bx) * 2 + 0];
    float cpx = cps[((b * 33 + by) * 33 + bx) * 2 + 1];
    int y0 = sy - 8 + by * 16;
    int x0 = sx - 8 + bx * 16;
    int x = x0 + l2;
    bool xok = (x >= 0 && x < WW);
    float dx = (float)x - cpx;
    float dx2 = dx * dx;
    float A = 0.f, Bs = 0.f, C = 0.f, D = 0.f, E = 0.f;
    #pragma unroll
    for (int k = 0; k < 16; k++){
        int y = y0 + k;
        float r = 0.f;
        if (xok && y >= 0 && y < HH)
            r = img[((size_t)b * HH + y) * WW + x];
        float dy = (float)y - cpy;
        float m = __expf(-(dy * dy + dx2) * (1.f / 128.f));
        m = diff_round(diff_round(m));
        float rm = r * m;
        float m2 = m * m;
        A += m; Bs += rm; E += m2;
        D += rm * m2;
        C += rm * rm * m2;
    }
    #pragma unroll
    for (int off = 8; off >= 1; off >>= 1){
        A  += __shfl_xor(A, off);
        Bs += __shfl_xor(Bs, off);
        C  += __shfl_xor(C, off);
        D  += __shfl_xor(D, off);
        E  += __shfl_xor(E, off);
    }
    if (l2 == 0){
        float rden = __builtin_amdgcn_rcpf(A + 1e-7f);
        float mean = (Bs + 256.f * 1e-7f) * rden;
        float sdev = C - 2.f * mean * D + mean * mean * E;
        float varr = (sdev + 256.f * 1e-7f) * rden;
        sv[wv * 4 + g] = varr;
    }
    __syncthreads();
    if (t == 0){
        float s = 0.f;
        #pragma unroll
        for (int i2 = 0; i2 < 16; i2++) s += sv[i2];
        atomicAdd(&acc[blockIdx.x & 63], s);
    }
}

// ---------------- Edge sampling loss ----------------
__global__ void edge_loss_kernel(const float* __restrict__ edge, const float* __restrict__ cps,
                                 float* __restrict__ acc){
    __shared__ float s1[256];
    int idx = blockIdx.x * blockDim.x + threadIdx.x;
    float v = 0.f;
    if (idx < BB * 1089){
        int b = idx / 1089;
        int p = idx % 1089;
        float y = cps[((size_t)b * 1089 + p) * 2 + 0];
        float x = cps[((size_t)b * 1089 + p) * 2 + 1];
        y = fminf(fmaxf(y, 0.f), 510.999f);
        x = fminf(fmaxf(x, 0.f), 510.999f);
        int y0 = (int)floorf(y);
        int x0 = (int)floorf(x);
        float wy = y - (float)y0;
        float wx = x - (float)x0;
        const float* e = edge + (size_t)b * HH * WW;
        float v00 = e[y0 * WW + x0];
        float v01 = e[y0 * WW + x0 + 1];
        float v10 = e[(y0 + 1) * WW + x0];
        float v11 = e[(y0 + 1) * WW + x0 + 1];
        v = v00 * (1 - wy) * (1 - wx) + v01 * (1 - wy) * wx + v10 * wy * (1 - wx) + v11 * wy * wx;
    }
    int t = threadIdx.x;
    s1[t] = v;
    __syncthreads();
    for (int off = 128; off > 0; off >>= 1){
        if (t < off) s1[t] += s1[t + off];
        __syncthreads();
    }
    if (t == 0) atomicAdd(&acc[64 + (blockIdx.x & 3)], s1[0]);
}

__global__ void finalize_kernel(const float* __restrict__ lacc, float* __restrict__ out){
    float a = 0.f, e = 0.f;
    for (int i = 0; i < 64; i++) a += lacc[i];
    for (int i = 0; i < 4; i++) e += lacc[64 + i];
    out[0] = (a / 65536.f) * (e / 17424.f);
}

extern "C" void kernel_launch(void* const* d_in, const int* in_sizes, int n_in,
                              void* d_out, int out_size, void* d_ws, size_t ws_size,
                              hipStream_t stream) {
    const float* image  = (const float*)d_in[0];
    const float* w_first= (const float*)d_in[1];
    const float* b_first= (const float*)d_in[2];
    const float* w_mid  = (const float*)d_in[3];
    const float* b_mid  = (const float*)d_in[4];
    const float* w_last = (const float*)d_in[5];
    const float* b_last = (const float*)d_in[6];
    float* out = (float*)d_out;
    char* ws = (char*)d_ws;

    // ---- workspace layout ----
    float* stats = (float*)ws;                 // 8 layers * 512 floats (sum[256], sumsq[256])
    float* lacc  = stats + 8 * 512;            // 128 floats of reduction buckets
    size_t off = (8 * 512 + 128) * sizeof(float);   // 16896 B
    float* edge = (float*)(ws + off); off += (size_t)BB * HH * WW * 4;
    float* act4 = (float*)(ws + off); off += (size_t)BB * 64 * 64 * 16 * 4;
    float* act5 = (float*)(ws + off); off += (size_t)BB * 32 * 32 * 16 * 4;
    float* act6 = (float*)(ws + off); off += (size_t)BB * 32 * 32 * 16 * 4;
    float* act3 = (float*)(ws + off); off += (size_t)BB * 128 * 128 * 16 * 4;
    __half* act1 = (__half*)(ws + off); off += (size_t)BB * HH * WW * 16 * 2;
    __half* act2 = (__half*)(ws + off); off += (size_t)BB * 256 * 256 * 16 * 2;

    hipMemsetAsync(ws, 0, (8 * 512 + 128) * sizeof(float), stream);

    int totalPix = BB * HH * WW;               // 4,194,304

    farid_kernel<<<totalPix / 256, 256, 0, stream>>>(image, edge);

    // layer 0: conv_first + fused stats0 (acts stored RAW; norm applied by consumer)
    conv_first_kernel<<<totalPix / 256, 256, 0, stream>>>(image, edge, w_first, b_first,
                                                          act1, stats + 0 * 512);
    // mid 0: 512 -> 256 s2 p0 : norm(stats0) on load, stats1 out
    conv3x3_kernel<__half, __half><<<(BB * 256 * 256) / 256, 256, 0, stream>>>(
        act1, w_mid + 0 * 2304, b_mid + 0, act2, stats + 0 * 512, stats + 1 * 512,
        512, 512, 256, 256, 2, 0);
    // mid 1: 256 -> 128 s2
    conv3x3_kernel<__half, float><<<(BB * 128 * 128) / 256, 256, 0, stream>>>(
        act2, w_mid + 1 * 2304, b_mid + 16, act3, stats + 1 * 512, stats + 2 * 512,
        256, 256, 128, 128, 2, 0);
    // mid 2: 128 -> 64 s2
    conv3x3_kernel<float, float><<<(BB * 64 * 64) / 256, 256, 0, stream>>>(
        act3, w_mid + 2 * 2304, b_mid + 32, act4, stats + 2 * 512, stats + 3 * 512,
        128, 128, 64, 64, 2, 0);
    // mid 3: 64 -> 32 s2
    conv3x3_kernel<float, float><<<(BB * 32 * 32) / 256, 256, 0, stream>>>(
        act4, w_mid + 3 * 2304, b_mid + 48, act5, stats + 3 * 512, stats + 4 * 512,
        64, 64, 32, 32, 2, 0);
    // mid 4: 32 -> 32 s1 p1
    conv3x3_kernel<float, float><<<(BB * 32 * 32) / 256, 256, 0, stream>>>(
        act5, w_mid + 4 * 2304, b_mid + 64, act6, stats + 4 * 512, stats + 5 * 512,
        32, 32, 32, 32, 1, 1);
    // mid 5
    conv3x3_kernel<float, float><<<(BB * 32 * 32) / 256, 256, 0, stream>>>(
        act6, w_mid + 5 * 2304, b_mid + 80, act5, stats + 5 * 512, stats + 6 * 512,
        32, 32, 32, 32, 1, 1);
    // mid 6
    conv3x3_kernel<float, float><<<(BB * 32 * 32) / 256, 256, 0, stream>>>(
        act5, w_mid + 6 * 2304, b_mid + 96, act6, stats + 6 * 512, stats + 7 * 512,
        32, 32, 32, 32, 1, 1);

    // last conv (norm(stats7) on load) + tanh + control points -> d_out[1..]
    float* cps_out = out + 1;
    conv_last_cps_kernel<<<(BB * 33 * 33 + 255) / 256, 256, 0, stream>>>(
        act6, w_last, b_last, stats + 7 * 512, cps_out);

    // losses
    area_loss_kernel<<<4096, 256, 0, stream>>>(image, cps_out, lacc);
    edge_loss_kernel<<<(BB * 1089 + 255) / 256, 256, 0, stream>>>(edge, cps_out, lacc);
    finalize_kernel<<<1, 1, 0, stream>>>(lacc, out);
}

// Round 5
// 467.027 us; speedup vs baseline: 2.6243x; 1.1671x over previous
//
#include <hip/hip_runtime.h>
#include <hip/hip_fp16.h>
#include <math.h>

#define BB 16
#define HH 512
#define WW 512

typedef _Float16 half8 __attribute__((ext_vector_type(8)));
typedef float f32x4 __attribute__((ext_vector_type(4)));

// ---------- helpers ----------
__device__ __forceinline__ void store16(__half* p, const float* v){
    #pragma unroll
    for (int i = 0; i < 2; i++){
        uint4 u;
        unsigned* pu = reinterpret_cast<unsigned*>(&u);
        #pragma unroll
        for (int j = 0; j < 4; j++){
            __half2 h = __floats2half2_rn(v[8*i + 2*j], v[8*i + 2*j + 1]);
            pu[j] = *reinterpret_cast<unsigned*>(&h);
        }
        ((uint4*)p)[i] = u;
    }
}

__device__ __forceinline__ float gelu_tanh(float v){
    float u = 0.7978845608028654f * (v + 0.044715f * v * v * v);
    float e = __expf(2.f * u);
    return v - v * __builtin_amdgcn_rcpf(e + 1.f);
}
__device__ __forceinline__ float diff_round(float x){
    const float TWO_PI = 6.283185307179586f;
    const float INV_TWO_PI = 0.15915494309189535f;
    return x - __sinf(TWO_PI * x) * INV_TWO_PI;
}

// ---------------- Farid edge filter ----------------
__global__ void farid_kernel(const float* __restrict__ img, float* __restrict__ edge){
    const float p[5] = {0.03032f, 0.249724f, 0.439911f, 0.249724f, 0.03032f};
    const float d[5] = {0.10455f, 0.292315f, 0.0f, -0.292315f, -0.10455f};
    int idx = blockIdx.x * blockDim.x + threadIdx.x;
    if (idx >= BB * HH * WW) return;
    int x = idx % WW;
    int y = (idx / WW) % HH;
    int b = idx / (HH * WW);
    const float* ib = img + (size_t)b * HH * WW;
    float gx = 0.f, gy = 0.f;
    #pragma unroll
    for (int i = 0; i < 5; i++){
        int iy = y + i - 2;
        if (iy < 0 || iy >= HH) continue;
        #pragma unroll
        for (int j = 0; j < 5; j++){
            int ix = x + j - 2;
            if (ix < 0 || ix >= WW) continue;
            float v = ib[iy * WW + ix];
            gx += p[i] * d[j] * v;
            gy += d[i] * p[j] * v;
        }
    }
    edge[idx] = sqrtf(gx * gx + gy * gy + 1e-8f);
}

// ---------- block stats epilogue (conv_first only): LDS transpose reduce ----------
__device__ __forceinline__ void stats_epilogue(float* smem, const float* acc,
                                               float* stats_out, int bB){
    int t = threadIdx.x;
    __syncthreads();
    #pragma unroll
    for (int c = 0; c < 16; c++) smem[t * 17 + c] = acc[c];
    __syncthreads();
    int cc = t & 15;
    int r0 = (t >> 4) << 4;
    float s = 0.f, q = 0.f;
    #pragma unroll
    for (int i = 0; i < 16; i++){
        float v = smem[(r0 + i) * 17 + cc];
        s += v; q += v * v;
    }
    __syncthreads();
    smem[t] = s; smem[256 + t] = q;
    __syncthreads();
    if (t < 32){
        bool isq = t >= 16;
        int c2 = t & 15;
        const float* p = smem + (isq ? 256 : 0);
        float a = 0.f;
        #pragma unroll
        for (int k = 0; k < 16; k++) a += p[k * 16 + c2];
        atomicAdd(&stats_out[(isq ? 256 : 0) + bB * 16 + c2], a);
    }
}

// ---------------- First conv: 2ch -> 16ch, 3x3, s1 p1, + stats epilogue ----------------
__global__ __launch_bounds__(256) void conv_first_kernel(
        const float* __restrict__ img, const float* __restrict__ edge,
        const float* __restrict__ w, const float* __restrict__ bias,
        __half* __restrict__ out, float* __restrict__ stats_out){
    __shared__ float smem[4352];
    __shared__ float sb[16];
    for (int i = threadIdx.x; i < 288; i += blockDim.x) smem[i] = w[i];
    if (threadIdx.x < 16) sb[threadIdx.x] = bias[threadIdx.x];
    __syncthreads();
    int idx = blockIdx.x * blockDim.x + threadIdx.x;
    int x = idx % WW;
    int y = (idx / WW) % HH;
    int b = idx / (HH * WW);
    float acc[16];
    #pragma unroll
    for (int c = 0; c < 16; c++) acc[c] = sb[c];
    for (int ky = 0; ky < 3; ky++){
        int iy = y + ky - 1;
        if (iy < 0 || iy >= HH) continue;
        for (int kx = 0; kx < 3; kx++){
            int ix = x + kx - 1;
            if (ix < 0 || ix >= WW) continue;
            size_t off = ((size_t)b * HH + iy) * WW + ix;
            float v0 = img[off];
            float v1 = edge[off];
            const float* wp = smem + (ky * 3 + kx) * 32;  // (kh,kw,2,16)
            #pragma unroll
            for (int c = 0; c < 16; c++) acc[c] += v0 * wp[c] + v1 * wp[16 + c];
        }
    }
    store16(out + (size_t)idx * 16, acc);
    stats_epilogue(smem, acc, stats_out, b);
}

// ---------------- MFMA conv 16->16: norm+gelu on load, 16x16 out tile / block ----------------
// Wave computes 4 M-tiles (rows) of 16 pixels x 16 out-ch via mfma_f32_16x16x32_f16.
// K = 9 taps x 16 ci packed as 5 MFMA ops of 2 taps (tap 9 zero-padded).
// Layout facts used (HW-verified family): A.m = lane&15, B.n = lane&15,
// D: col = lane&15, row = (lane>>4)*4 + reg. The k-labeling only needs A/B consistency.
template<int STRIDE, int PAD>
__global__ __launch_bounds__(256) void conv_mfma_kernel(
        const __half* __restrict__ in, const float* __restrict__ w,
        const float* __restrict__ bias, __half* __restrict__ out,
        const float* __restrict__ stats_in, float* __restrict__ stats_out,
        int Hin, int Win, int Hout, int Wout){
    __shared__ float sred[2][4][16];
    int t = threadIdx.x;
    int lane = t & 63;
    int wv = t >> 6;
    int col = lane & 15;          // A pixel-x offset / B-D out-channel
    int g = lane >> 4;            // k-group
    int ci0 = (g & 1) * 8;        // channel slice of this lane's k chunk
    int tsel = g >> 1;            // which tap of the pair

    int nTx = Wout >> 4;
    int nTy = Hout >> 4;
    int bid = blockIdx.x;
    int tx = bid % nTx;
    int ty = (bid / nTx) % nTy;
    int b  = bid / (nTx * nTy);

    // per-lane norm params for channels ci0..ci0+7
    float mean[8], rstd[8];
    float invN = 1.f / (float)(Hin * Win);
    #pragma unroll
    for (int j = 0; j < 8; j++){
        int c = ci0 + j;
        float mm = stats_in[b * 16 + c] * invN;
        float vv = stats_in[256 + b * 16 + c] * invN - mm * mm;
        mean[j] = mm;
        rstd[j] = rsqrtf(vv + 1e-5f);
    }

    // B fragments: weights (kh,kw,ci,co) fp32 -> fp16, 5 tap-pairs
    half8 bfrag[5];
    #pragma unroll
    for (int p = 0; p < 5; p++){
        int tp = 2 * p + tsel;
        #pragma unroll
        for (int j = 0; j < 8; j++)
            bfrag[p][j] = (tp < 9) ? (_Float16)w[(tp * 16 + ci0 + j) * 16 + col]
                                   : (_Float16)0.f;
    }
    float bia = bias[col];

    int xg = tx * 16 + col;       // this lane's A-row output x
    float ssum = 0.f, ssq = 0.f;

    #pragma unroll
    for (int s = 0; s < 4; s++){
        int r = ty * 16 + wv * 4 + s;     // output y
        f32x4 acc = {bia, bia, bia, bia};
        #pragma unroll
        for (int p = 0; p < 5; p++){
            int tp = 2 * p + tsel;
            int ky = tp / 3, kx = tp - ky * 3;
            int iy = r * STRIDE + ky - PAD;
            int ix = xg * STRIDE + kx - PAD;
            bool valid = (tp < 9) && (iy >= 0) && (iy < Hin) && (ix >= 0) && (ix < Win);
            half8 afrag;
            #pragma unroll
            for (int j = 0; j < 8; j++) afrag[j] = (_Float16)0.f;
            if (valid){
                const __half* ap = in + ((((size_t)b * Hin + iy) * Win + ix) << 4) + ci0;
                uint4 u = *(const uint4*)ap;
                unsigned* pu = reinterpret_cast<unsigned*>(&u);
                #pragma unroll
                for (int q = 0; q < 4; q++){
                    __half2 h = *reinterpret_cast<__half2*>(&pu[q]);
                    float2 f = __half22float2(h);
                    float a0 = gelu_tanh((f.x - mean[2*q])   * rstd[2*q]);
                    float a1 = gelu_tanh((f.y - mean[2*q+1]) * rstd[2*q+1]);
                    afrag[2*q]   = (_Float16)a0;
                    afrag[2*q+1] = (_Float16)a1;
                }
            }
            acc = __builtin_amdgcn_mfma_f32_16x16x32_f16(afrag, bfrag[p], acc, 0, 0, 0);
        }
        // store D + accumulate stats: lane holds pixels x = tx*16 + 4g + reg, ch = col
        #pragma unroll
        for (int rg = 0; rg < 4; rg++){
            int px = tx * 16 + 4 * g + rg;
            float v = acc[rg];
            out[(((size_t)b * Hout + r) * Wout + px) * 16 + col] = __float2half(v);
            ssum += v;
            ssq += v * v;
        }
    }

    // reduce over pixel groups (lanes sharing col)
    ssum += __shfl_xor(ssum, 16); ssq += __shfl_xor(ssq, 16);
    ssum += __shfl_xor(ssum, 32); ssq += __shfl_xor(ssq, 32);
    if (lane < 16){ sred[0][wv][lane] = ssum; sred[1][wv][lane] = ssq; }
    __syncthreads();
    if (t < 32){
        int isq = t >> 4, c = t & 15;
        float a = sred[isq][0][c] + sred[isq][1][c] + sred[isq][2][c] + sred[isq][3][c];
        atomicAdd(&stats_out[isq * 256 + b * 16 + c], a);
    }
}

// ---------------- Last conv (16->2), norm+gelu on load, tanh, control points ----------------
__global__ void conv_last_cps_kernel(const __half* __restrict__ act, const float* __restrict__ w,
                                     const float* __restrict__ bias,
                                     const float* __restrict__ stats,
                                     float* __restrict__ cps){
    int idx = blockIdx.x * blockDim.x + threadIdx.x;
    if (idx >= BB * 33 * 33) return;
    int j = idx % 33;
    int i = (idx / 33) % 33;
    int b = idx / (33 * 33);
    float cy = (float)(i * 16);
    float cx = (float)(j * 16);
    if (i < 32 && j < 32){
        float mean[16], rstd[16];
        const float invN = 1.f / 1024.f;
        #pragma unroll
        for (int c = 0; c < 16; c++){
            float mm = stats[b * 16 + c] * invN;
            float vv = stats[256 + b * 16 + c] * invN - mm * mm;
            mean[c] = mm;
            rstd[c] = rsqrtf(vv + 1e-5f);
        }
        float a0 = bias[0], a1 = bias[1];
        for (int ky = 0; ky < 3; ky++){
            int iy = i + ky - 1;
            if (iy < 0 || iy >= 32) continue;
            for (int kx = 0; kx < 3; kx++){
                int ix = j + kx - 1;
                if (ix < 0 || ix >= 32) continue;
                const __half* ip = act + (((size_t)b * 32 + iy) * 32 + ix) * 16;
                const float* wp = w + (ky * 3 + kx) * 32;  // (kh,kw,16,2)
                #pragma unroll
                for (int ci = 0; ci < 16; ci++){
                    float v = gelu_tanh((__half2float(ip[ci]) - mean[ci]) * rstd[ci]);
                    a0 += v * wp[ci * 2];
                    a1 += v * wp[ci * 2 + 1];
                }
            }
        }
        cy += tanhf(a0) * 8.f;
        cx += tanhf(a1) * 8.f;
    }
    cps[idx * 2] = cy;
    cps[idx * 2 + 1] = cx;
}

// ---------------- Area loss: 16-lane group per area, single-pass variance ----------------
__global__ __launch_bounds__(256) void area_loss_kernel(
        const float* __restrict__ img, const float* __restrict__ cps,
        float* __restrict__ acc){
    __shared__ float sv[16];
    int t = threadIdx.x;
    int lane = t & 63;
    int wv = t >> 6;
    int g = lane >> 4;
    int l2 = lane & 15;
    int aidx = blockIdx.x * 16 + wv * 4 + g;   // 0 .. 65535
    int b = aidx >> 12;
    int rem = aidx & 4095;
    int o = rem >> 10;
    int ar = rem & 1023;
    int by = ar >> 5;
    int bx = ar & 31;
    int sy = (o & 2) ? 8 : 0;
    int sx = (o & 1) ? 8 : 0;
    float cpy = cps[((b * 33 + by) * 33 + bx) * 2 + 0];
    float cpx = cps[((b * 33 + by) * 33 + bx) * 2 + 1];
    int y0 = sy - 8 + by * 16;
    int x0 = sx - 8 + bx * 16;
    int x = x0 + l2;
    bool xok = (x >= 0 && x < WW);
    float dx = (float)x - cpx;
    float dx2 = dx * dx;
    float A = 0.f, Bs = 0.f, C = 0.f, D = 0.f, E = 0.f;
    #pragma unroll
    for (int k = 0; k < 16; k++){
        int y = y0 + k;
        float r = 0.f;
        if (xok && y >= 0 && y < HH)
            r = img[((size_t)b * HH + y) * WW + x];
        float dy = (float)y - cpy;
        float m = __expf(-(dy * dy + dx2) * (1.f / 128.f));
        m = diff_round(diff_round(m));
        float rm = r * m;
        float m2 = m * m;
        A += m; Bs += rm; E += m2;
        D += rm * m2;
        C += rm * rm * m2;
    }
    #pragma unroll
    for (int off = 8; off >= 1; off >>= 1){
        A  += __shfl_xor(A, off);
        Bs += __shfl_xor(Bs, off);
        C  += __shfl_xor(C, off);
        D  += __shfl_xor(D, off);
        E  += __shfl_xor(E, off);
    }
    if (l2 == 0){
        float rden = __builtin_amdgcn_rcpf(A + 1e-7f);
        float mean = (Bs + 256.f * 1e-7f) * rden;
        float sdev = C - 2.f * mean * D + mean * mean * E;
        float varr = (sdev + 256.f * 1e-7f) * rden;
        sv[wv * 4 + g] = varr;
    }
    __syncthreads();
    if (t == 0){
        float s = 0.f;
        #pragma unroll
        for (int i2 = 0; i2 < 16; i2++) s += sv[i2];
        atomicAdd(&acc[blockIdx.x & 63], s);
    }
}

// ---------------- Edge sampling loss ----------------
__global__ void edge_loss_kernel(const float* __restrict__ edge, const float* __restrict__ cps,
                                 float* __restrict__ acc){
    __shared__ float s1[256];
    int idx = blockIdx.x * blockDim.x + threadIdx.x;
    float v = 0.f;
    if (idx < BB * 1089){
        int b = idx / 1089;
        int p = idx % 1089;
        float y = cps[((size_t)b * 1089 + p) * 2 + 0];
        float x = cps[((size_t)b * 1089 + p) * 2 + 1];
        y = fminf(fmaxf(y, 0.f), 510.999f);
        x = fminf(fmaxf(x, 0.f), 510.999f);
        int y0 = (int)floorf(y);
        int x0 = (int)floorf(x);
        float wy = y - (float)y0;
        float wx = x - (float)x0;
        const float* e = edge + (size_t)b * HH * WW;
        float v00 = e[y0 * WW + x0];
        float v01 = e[y0 * WW + x0 + 1];
        float v10 = e[(y0 + 1) * WW + x0];
        float v11 = e[(y0 + 1) * WW + x0 + 1];
        v = v00 * (1 - wy) * (1 - wx) + v01 * (1 - wy) * wx + v10 * wy * (1 - wx) + v11 * wy * wx;
    }
    int t = threadIdx.x;
    s1[t] = v;
    __syncthreads();
    for (int off = 128; off > 0; off >>= 1){
        if (t < off) s1[t] += s1[t + off];
        __syncthreads();
    }
    if (t == 0) atomicAdd(&acc[64 + (blockIdx.x & 3)], s1[0]);
}

__global__ void finalize_kernel(const float* __restrict__ lacc, float* __restrict__ out){
    float a = 0.f, e = 0.f;
    for (int i = 0; i < 64; i++) a += lacc[i];
    for (int i = 0; i < 4; i++) e += lacc[64 + i];
    out[0] = (a / 65536.f) * (e / 17424.f);
}

extern "C" void kernel_launch(void* const* d_in, const int* in_sizes, int n_in,
                              void* d_out, int out_size, void* d_ws, size_t ws_size,
                              hipStream_t stream) {
    const float* image  = (const float*)d_in[0];
    const float* w_first= (const float*)d_in[1];
    const float* b_first= (const float*)d_in[2];
    const float* w_mid  = (const float*)d_in[3];
    const float* b_mid  = (const float*)d_in[4];
    const float* w_last = (const float*)d_in[5];
    const float* b_last = (const float*)d_in[6];
    float* out = (float*)d_out;
    char* ws = (char*)d_ws;

    // ---- workspace layout (all activations fp16, stored pre-norm) ----
    float* stats = (float*)ws;                 // 8 layers * 512 floats
    float* lacc  = stats + 8 * 512;            // 128 floats
    size_t off = (8 * 512 + 128) * sizeof(float);
    float* edge = (float*)(ws + off); off += (size_t)BB * HH * WW * 4;
    __half* act1 = (__half*)(ws + off); off += (size_t)BB * 512 * 512 * 16 * 2;
    __half* act2 = (__half*)(ws + off); off += (size_t)BB * 256 * 256 * 16 * 2;
    __half* act3 = (__half*)(ws + off); off += (size_t)BB * 128 * 128 * 16 * 2;
    __half* act4 = (__half*)(ws + off); off += (size_t)BB * 64 * 64 * 16 * 2;
    __half* act5 = (__half*)(ws + off); off += (size_t)BB * 32 * 32 * 16 * 2;
    __half* act6 = (__half*)(ws + off); off += (size_t)BB * 32 * 32 * 16 * 2;

    hipMemsetAsync(ws, 0, (8 * 512 + 128) * sizeof(float), stream);

    int totalPix = BB * HH * WW;

    farid_kernel<<<totalPix / 256, 256, 0, stream>>>(image, edge);

    // layer 0: conv_first + fused stats0 (act stored RAW; norm applied by consumer)
    conv_first_kernel<<<totalPix / 256, 256, 0, stream>>>(image, edge, w_first, b_first,
                                                          act1, stats + 0 * 512);
    // mid 0: 512 -> 256, s2 p0
    conv_mfma_kernel<2,0><<<16 * 16 * 16, 256, 0, stream>>>(
        act1, w_mid + 0 * 2304, b_mid + 0, act2, stats + 0 * 512, stats + 1 * 512,
        512, 512, 256, 256);
    // mid 1: 256 -> 128, s2 p0
    conv_mfma_kernel<2,0><<<16 * 8 * 8, 256, 0, stream>>>(
        act2, w_mid + 1 * 2304, b_mid + 16, act3, stats + 1 * 512, stats + 2 * 512,
        256, 256, 128, 128);
    // mid 2: 128 -> 64, s2 p0
    conv_mfma_kernel<2,0><<<16 * 4 * 4, 256, 0, stream>>>(
        act3, w_mid + 2 * 2304, b_mid + 32, act4, stats + 2 * 512, stats + 3 * 512,
        128, 128, 64, 64);
    // mid 3: 64 -> 32, s2 p0
    conv_mfma_kernel<2,0><<<16 * 2 * 2, 256, 0, stream>>>(
        act4, w_mid + 3 * 2304, b_mid + 48, act5, stats + 3 * 512, stats + 4 * 512,
        64, 64, 32, 32);
    // mid 4: 32 -> 32, s1 p1
    conv_mfma_kernel<1,1><<<16 * 2 * 2, 256, 0, stream>>>(
        act5, w_mid + 4 * 2304, b_mid + 64, act6, stats + 4 * 512, stats + 5 * 512,
        32, 32, 32, 32);
    // mid 5
    conv_mfma_kernel<1,1><<<16 * 2 * 2, 256, 0, stream>>>(
        act6, w_mid + 5 * 2304, b_mid + 80, act5, stats + 5 * 512, stats + 6 * 512,
        32, 32, 32, 32);
    // mid 6
    conv_mfma_kernel<1,1><<<16 * 2 * 2, 256, 0, stream>>>(
        act5, w_mid + 6 * 2304, b_mid + 96, act6, stats + 6 * 512, stats + 7 * 512,
        32, 32, 32, 32);

    // last conv + tanh + control points -> d_out[1..]
    float* cps_out = out + 1;
    conv_last_cps_kernel<<<(BB * 33 * 33 + 255) / 256, 256, 0, stream>>>(
        act6, w_last, b_last, stats + 7 * 512, cps_out);

    // losses
    area_loss_kernel<<<4096, 256, 0, stream>>>(image, cps_out, lacc);
    edge_loss_kernel<<<(BB * 1089 + 255) / 256, 256, 0, stream>>>(edge, cps_out, lacc);
    finalize_kernel<<<1, 1, 0, stream>>>(lacc, out);
}

// Round 7
// 417.205 us; speedup vs baseline: 2.9377x; 1.1194x over previous
//
#include <hip/hip_runtime.h>
#include <hip/hip_fp16.h>
#include <math.h>

#define BB 16
#define HH 512
#define WW 512

typedef _Float16 half8 __attribute__((ext_vector_type(8)));
typedef float f32x4 __attribute__((ext_vector_type(4)));

// ---------- helpers ----------
__device__ __forceinline__ void store16(__half* p, const float* v){
    #pragma unroll
    for (int i = 0; i < 2; i++){
        uint4 u;
        unsigned* pu = reinterpret_cast<unsigned*>(&u);
        #pragma unroll
        for (int j = 0; j < 4; j++){
            __half2 h = __floats2half2_rn(v[8*i + 2*j], v[8*i + 2*j + 1]);
            pu[j] = *reinterpret_cast<unsigned*>(&h);
        }
        ((uint4*)p)[i] = u;
    }
}

__device__ __forceinline__ float gelu_tanh(float v){
    float u = 0.7978845608028654f * (v + 0.044715f * v * v * v);
    float e = __expf(2.f * u);
    return v - v * __builtin_amdgcn_rcpf(e + 1.f);
}
__device__ __forceinline__ float diff_round(float x){
    const float TWO_PI = 6.283185307179586f;
    const float INV_TWO_PI = 0.15915494309189535f;
    return x - __sinf(TWO_PI * x) * INV_TWO_PI;
}

// ---------------- Fused Farid + first conv (2ch -> 16ch, 3x3 s1 p1) + stats ----------------
// Block = 32x8 output pixels. LDS: img tile 14x38 (halo 3), edge tile 10x34 (halo 1).
// Edge outside the image is forced to 0 (matches reference zero-pad of concat(img,edge)).
__global__ __launch_bounds__(256) void farid_conv_first_kernel(
        const float* __restrict__ img, const float* __restrict__ w,
        const float* __restrict__ bias, float* __restrict__ edge_out,
        __half* __restrict__ out, float* __restrict__ stats_out){
    __shared__ float smem[4368];      // [0,288) w; [288,848) img 14x40; [848,1248) edge 10x40
    __shared__ float sb[16];
    float* simg = smem + 288;
    float* sedge = smem + 848;
    int t = threadIdx.x;
    int bid = blockIdx.x;
    int tx0 = (bid & 15) << 5;          // 16 x-tiles of 32
    int ty0 = ((bid >> 4) & 63) << 3;   // 64 y-tiles of 8
    int b   = bid >> 10;
    const float* ib = img + (size_t)b * HH * WW;

    for (int i = t; i < 288; i += 256) smem[i] = w[i];
    if (t < 16) sb[t] = bias[t];
    // stage img tile [ty0-3, ty0+11) x [tx0-3, tx0+35), zero OOB
    for (int i = t; i < 14 * 38; i += 256){
        int r = i / 38, c = i - r * 38;
        int gy = ty0 - 3 + r, gx = tx0 - 3 + c;
        float v = 0.f;
        if (gy >= 0 && gy < HH && gx >= 0 && gx < WW) v = ib[gy * WW + gx];
        simg[r * 40 + c] = v;
    }
    __syncthreads();

    // compute edge region [ty0-1, ty0+9) x [tx0-1, tx0+33): 10x34
    const float fp[5] = {0.03032f, 0.249724f, 0.439911f, 0.249724f, 0.03032f};
    const float fd[5] = {0.10455f, 0.292315f, 0.0f, -0.292315f, -0.10455f};
    for (int i = t; i < 10 * 34; i += 256){
        int r = i / 34, c = i - r * 34;
        int gy = ty0 - 1 + r, gx = tx0 - 1 + c;
        float e = 0.f;
        if (gy >= 0 && gy < HH && gx >= 0 && gx < WW){
            float gxx = 0.f, gyy = 0.f;
            #pragma unroll
            for (int di = 0; di < 5; di++){
                #pragma unroll
                for (int dj = 0; dj < 5; dj++){
                    float v = simg[(r + di) * 40 + (c + dj)];
                    gxx += fp[di] * fd[dj] * v;
                    gyy += fd[di] * fp[dj] * v;
                }
            }
            e = sqrtf(gxx * gxx + gyy * gyy + 1e-8f);
        }
        sedge[r * 40 + c] = e;
    }
    __syncthreads();

    int tx = t & 31, ty = t >> 5;       // thread's output pixel
    int y = ty0 + ty, x = tx0 + tx;
    // write edge (interior)
    edge_out[((size_t)b * HH + y) * WW + x] = sedge[(ty + 1) * 40 + (tx + 1)];

    float acc[16];
    #pragma unroll
    for (int c = 0; c < 16; c++) acc[c] = sb[c];
    #pragma unroll
    for (int dy = -1; dy <= 1; dy++){
        #pragma unroll
        for (int dx = -1; dx <= 1; dx++){
            float v0 = simg[(ty + 3 + dy) * 40 + (tx + 3 + dx)];
            float v1 = sedge[(ty + 1 + dy) * 40 + (tx + 1 + dx)];
            const float* wp = smem + ((dy + 1) * 3 + (dx + 1)) * 32;  // (kh,kw,2,16)
            #pragma unroll
            for (int c = 0; c < 16; c++) acc[c] += v0 * wp[c] + v1 * wp[16 + c];
        }
    }
    size_t idx = ((size_t)b * HH + y) * WW + x;
    store16(out + idx * 16, acc);

    // ---- stats epilogue (reuses smem) ----
    __syncthreads();
    #pragma unroll
    for (int c = 0; c < 16; c++) smem[t * 17 + c] = acc[c];
    __syncthreads();
    int cc = t & 15;
    int r0 = (t >> 4) << 4;
    float s = 0.f, q = 0.f;
    #pragma unroll
    for (int i = 0; i < 16; i++){
        float v = smem[(r0 + i) * 17 + cc];
        s += v; q += v * v;
    }
    __syncthreads();
    smem[t] = s; smem[256 + t] = q;
    __syncthreads();
    if (t < 32){
        bool isq = t >= 16;
        int c2 = t & 15;
        const float* p = smem + (isq ? 256 : 0);
        float a = 0.f;
        #pragma unroll
        for (int k = 0; k < 16; k++) a += p[k * 16 + c2];
        atomicAdd(&stats_out[(isq ? 256 : 0) + b * 16 + c2], a);
    }
}

// ---------------- MFMA conv 16->16: norm+gelu on load, 16x16 out tile / block ----------------
template<int STRIDE, int PAD>
__global__ __launch_bounds__(256) void conv_mfma_kernel(
        const __half* __restrict__ in, const float* __restrict__ w,
        const float* __restrict__ bias, __half* __restrict__ out,
        const float* __restrict__ stats_in, float* __restrict__ stats_out,
        int Hin, int Win, int Hout, int Wout){
    __shared__ float sred[2][4][16];
    int t = threadIdx.x;
    int lane = t & 63;
    int wv = t >> 6;
    int col = lane & 15;          // A pixel-x offset / B-D out-channel
    int g = lane >> 4;            // k-group
    int ci0 = (g & 1) * 8;        // channel slice of this lane's k chunk
    int tsel = g >> 1;            // which tap of the pair

    int nTx = Wout >> 4;
    int nTy = Hout >> 4;
    int bid = blockIdx.x;
    int tx = bid % nTx;
    int ty = (bid / nTx) % nTy;
    int b  = bid / (nTx * nTy);

    float mean[8], rstd[8];
    float invN = 1.f / (float)(Hin * Win);
    #pragma unroll
    for (int j = 0; j < 8; j++){
        int c = ci0 + j;
        float mm = stats_in[b * 16 + c] * invN;
        float vv = stats_in[256 + b * 16 + c] * invN - mm * mm;
        mean[j] = mm;
        rstd[j] = rsqrtf(vv + 1e-5f);
    }

    half8 bfrag[5];
    #pragma unroll
    for (int p = 0; p < 5; p++){
        int tp = 2 * p + tsel;
        #pragma unroll
        for (int j = 0; j < 8; j++)
            bfrag[p][j] = (tp < 9) ? (_Float16)w[(tp * 16 + ci0 + j) * 16 + col]
                                   : (_Float16)0.f;
    }
    float bia = bias[col];

    int xg = tx * 16 + col;
    float ssum = 0.f, ssq = 0.f;

    #pragma unroll
    for (int s = 0; s < 4; s++){
        int r = ty * 16 + wv * 4 + s;
        f32x4 acc = {bia, bia, bia, bia};
        #pragma unroll
        for (int p = 0; p < 5; p++){
            int tp = 2 * p + tsel;
            int ky = tp / 3, kx = tp - ky * 3;
            int iy = r * STRIDE + ky - PAD;
            int ix = xg * STRIDE + kx - PAD;
            bool valid = (tp < 9) && (iy >= 0) && (iy < Hin) && (ix >= 0) && (ix < Win);
            half8 afrag;
            #pragma unroll
            for (int j = 0; j < 8; j++) afrag[j] = (_Float16)0.f;
            if (valid){
                const __half* ap = in + ((((size_t)b * Hin + iy) * Win + ix) << 4) + ci0;
                uint4 u = *(const uint4*)ap;
                unsigned* pu = reinterpret_cast<unsigned*>(&u);
                #pragma unroll
                for (int q = 0; q < 4; q++){
                    __half2 h = *reinterpret_cast<__half2*>(&pu[q]);
                    float2 f = __half22float2(h);
                    float a0 = gelu_tanh((f.x - mean[2*q])   * rstd[2*q]);
                    float a1 = gelu_tanh((f.y - mean[2*q+1]) * rstd[2*q+1]);
                    afrag[2*q]   = (_Float16)a0;
                    afrag[2*q+1] = (_Float16)a1;
                }
            }
            acc = __builtin_amdgcn_mfma_f32_16x16x32_f16(afrag, bfrag[p], acc, 0, 0, 0);
        }
        #pragma unroll
        for (int rg = 0; rg < 4; rg++){
            int px = tx * 16 + 4 * g + rg;
            float v = acc[rg];
            out[(((size_t)b * Hout + r) * Wout + px) * 16 + col] = __float2half(v);
            ssum += v;
            ssq += v * v;
        }
    }

    ssum += __shfl_xor(ssum, 16); ssq += __shfl_xor(ssq, 16);
    ssum += __shfl_xor(ssum, 32); ssq += __shfl_xor(ssq, 32);
    if (lane < 16){ sred[0][wv][lane] = ssum; sred[1][wv][lane] = ssq; }
    __syncthreads();
    if (t < 32){
        int isq = t >> 4, c = t & 15;
        float a = sred[isq][0][c] + sred[isq][1][c] + sred[isq][2][c] + sred[isq][3][c];
        atomicAdd(&stats_out[isq * 256 + b * 16 + c], a);
    }
}

// ---------------- Last conv (16->2), norm+gelu on load, tanh, control points ----------------
__global__ void conv_last_cps_kernel(const __half* __restrict__ act, const float* __restrict__ w,
                                     const float* __restrict__ bias,
                                     const float* __restrict__ stats,
                                     float* __restrict__ cps){
    int idx = blockIdx.x * blockDim.x + threadIdx.x;
    if (idx >= BB * 33 * 33) return;
    int j = idx % 33;
    int i = (idx / 33) % 33;
    int b = idx / (33 * 33);
    float cy = (float)(i * 16);
    float cx = (float)(j * 16);
    if (i < 32 && j < 32){
        float mean[16], rstd[16];
        const float invN = 1.f / 1024.f;
        #pragma unroll
        for (int c = 0; c < 16; c++){
            float mm = stats[b * 16 + c] * invN;
            float vv = stats[256 + b * 16 + c] * invN - mm * mm;
            mean[c] = mm;
            rstd[c] = rsqrtf(vv + 1e-5f);
        }
        float a0 = bias[0], a1 = bias[1];
        for (int ky = 0; ky < 3; ky++){
            int iy = i + ky - 1;
            if (iy < 0 || iy >= 32) continue;
            for (int kx = 0; kx < 3; kx++){
                int ix = j + kx - 1;
                if (ix < 0 || ix >= 32) continue;
                const __half* ip = act + (((size_t)b * 32 + iy) * 32 + ix) * 16;
                const float* wp = w + (ky * 3 + kx) * 32;  // (kh,kw,16,2)
                #pragma unroll
                for (int ci = 0; ci < 16; ci++){
                    float v = gelu_tanh((__half2float(ip[ci]) - mean[ci]) * rstd[ci]);
                    a0 += v * wp[ci * 2];
                    a1 += v * wp[ci * 2 + 1];
                }
            }
        }
        cy += tanhf(a0) * 8.f;
        cx += tanhf(a1) * 8.f;
    }
    cps[idx * 2] = cy;
    cps[idx * 2 + 1] = cx;
}

// ---------------- Area loss: 16-lane group per area, single-pass variance ----------------
__global__ __launch_bounds__(256) void area_loss_kernel(
        const float* __restrict__ img, const float* __restrict__ cps,
        float* __restrict__ acc){
    __shared__ float sv[16];
    int t = threadIdx.x;
    int lane = t & 63;
    int wv = t >> 6;
    int g = lane >> 4;
    int l2 = lane & 15;
    int aidx = blockIdx.x * 16 + wv * 4 + g;   // 0 .. 65535
    int b = aidx >> 12;
    int rem = aidx & 4095;
    int o = rem >> 10;
    int ar = rem & 1023;
    int by = ar >> 5;
    int bx = ar & 31;
    int sy = (o & 2) ? 8 : 0;
    int sx = (o & 1) ? 8 : 0;
    float cpy = cps[((b * 33 + by) * 33 + bx) * 2 + 0];
    float cpx = cps[((b * 33 + by) * 33 + bx) * 2 + 1];
    int y0 = sy - 8 + by * 16;
    int x0 = sx - 8 + bx * 16;
    int x = x0 + l2;
    bool xok = (x >= 0 && x < WW);
    float dx = (float)x - cpx;
    float dx2 = dx * dx;
    float A = 0.f, Bs = 0.f, C = 0.f, D = 0.f, E = 0.f;
    #pragma unroll
    for (int k = 0; k < 16; k++){
        int y = y0 + k;
        float r = 0.f;
        if (xok && y >= 0 && y < HH)
            r = img[((size_t)b * HH + y) * WW + x];
        float dy = (float)y - cpy;
        float m = __expf(-(dy * dy + dx2) * (1.f / 128.f));
        m = diff_round(diff_round(m));
        float rm = r * m;
        float m2 = m * m;
        A += m; Bs += rm; E += m2;
        D += rm * m2;
        C += rm * rm * m2;
    }
    #pragma unroll
    for (int off = 8; off >= 1; off >>= 1){
        A  += __shfl_xor(A, off);
        Bs += __shfl_xor(Bs, off);
        C  += __shfl_xor(C, off);
        D  += __shfl_xor(D, off);
        E  += __shfl_xor(E, off);
    }
    if (l2 == 0){
        float rden = __builtin_amdgcn_rcpf(A + 1e-7f);
        float mean = (Bs + 256.f * 1e-7f) * rden;
        float sdev = C - 2.f * mean * D + mean * mean * E;
        float varr = (sdev + 256.f * 1e-7f) * rden;
        sv[wv * 4 + g] = varr;
    }
    __syncthreads();
    if (t == 0){
        float s = 0.f;
        #pragma unroll
        for (int i2 = 0; i2 < 16; i2++) s += sv[i2];
        atomicAdd(&acc[blockIdx.x & 63], s);
    }
}

// ---------------- Edge sampling loss ----------------
__global__ void edge_loss_kernel(const float* __restrict__ edge, const float* __restrict__ cps,
                                 float* __restrict__ acc){
    __shared__ float s1[256];
    int idx = blockIdx.x * blockDim.x + threadIdx.x;
    float v = 0.f;
    if (idx < BB * 1089){
        int b = idx / 1089;
        int p = idx % 1089;
        float y = cps[((size_t)b * 1089 + p) * 2 + 0];
        float x = cps[((size_t)b * 1089 + p) * 2 + 1];
        y = fminf(fmaxf(y, 0.f), 510.999f);
        x = fminf(fmaxf(x, 0.f), 510.999f);
        int y0 = (int)floorf(y);
        int x0 = (int)floorf(x);
        float wy = y - (float)y0;
        float wx = x - (float)x0;
        const float* e = edge + (size_t)b * HH * WW;
        float v00 = e[y0 * WW + x0];
        float v01 = e[y0 * WW + x0 + 1];
        float v10 = e[(y0 + 1) * WW + x0];
        float v11 = e[(y0 + 1) * WW + x0 + 1];
        v = v00 * (1 - wy) * (1 - wx) + v01 * (1 - wy) * wx + v10 * wy * (1 - wx) + v11 * wy * wx;
    }
    int t = threadIdx.x;
    s1[t] = v;
    __syncthreads();
    for (int off = 128; off > 0; off >>= 1){
        if (t < off) s1[t] += s1[t + off];
        __syncthreads();
    }
    if (t == 0) atomicAdd(&acc[64 + (blockIdx.x & 3)], s1[0]);
}

__global__ void finalize_kernel(const float* __restrict__ lacc, float* __restrict__ out){
    float a = 0.f, e = 0.f;
    for (int i = 0; i < 64; i++) a += lacc[i];
    for (int i = 0; i < 4; i++) e += lacc[64 + i];
    out[0] = (a / 65536.f) * (e / 17424.f);
}

extern "C" void kernel_launch(void* const* d_in, const int* in_sizes, int n_in,
                              void* d_out, int out_size, void* d_ws, size_t ws_size,
                              hipStream_t stream) {
    const float* image  = (const float*)d_in[0];
    const float* w_first= (const float*)d_in[1];
    const float* b_first= (const float*)d_in[2];
    const float* w_mid  = (const float*)d_in[3];
    const float* b_mid  = (const float*)d_in[4];
    const float* w_last = (const float*)d_in[5];
    const float* b_last = (const float*)d_in[6];
    float* out = (float*)d_out;
    char* ws = (char*)d_ws;

    // ---- workspace layout (all activations fp16, stored pre-norm) ----
    float* stats = (float*)ws;                 // 8 layers * 512 floats
    float* lacc  = stats + 8 * 512;            // 128 floats
    size_t off = (8 * 512 + 128) * sizeof(float);
    float* edge = (float*)(ws + off); off += (size_t)BB * HH * WW * 4;
    __half* act1 = (__half*)(ws + off); off += (size_t)BB * 512 * 512 * 16 * 2;
    __half* act2 = (__half*)(ws + off); off += (size_t)BB * 256 * 256 * 16 * 2;
    __half* act3 = (__half*)(ws + off); off += (size_t)BB * 128 * 128 * 16 * 2;
    __half* act4 = (__half*)(ws + off); off += (size_t)BB * 64 * 64 * 16 * 2;
    __half* act5 = (__half*)(ws + off); off += (size_t)BB * 32 * 32 * 16 * 2;
    __half* act6 = (__half*)(ws + off); off += (size_t)BB * 32 * 32 * 16 * 2;

    hipMemsetAsync(ws, 0, (8 * 512 + 128) * sizeof(float), stream);

    // fused farid + conv_first + stats0 (edge written for edge_loss)
    farid_conv_first_kernel<<<16 * 64 * 16, 256, 0, stream>>>(
        image, w_first, b_first, edge, act1, stats + 0 * 512);

    // mid 0: 512 -> 256, s2 p0
    conv_mfma_kernel<2,0><<<16 * 16 * 16, 256, 0, stream>>>(
        act1, w_mid + 0 * 2304, b_mid + 0, act2, stats + 0 * 512, stats + 1 * 512,
        512, 512, 256, 256);
    // mid 1: 256 -> 128, s2 p0
    conv_mfma_kernel<2,0><<<16 * 8 * 8, 256, 0, stream>>>(
        act2, w_mid + 1 * 2304, b_mid + 16, act3, stats + 1 * 512, stats + 2 * 512,
        256, 256, 128, 128);
    // mid 2: 128 -> 64, s2 p0
    conv_mfma_kernel<2,0><<<16 * 4 * 4, 256, 0, stream>>>(
        act3, w_mid + 2 * 2304, b_mid + 32, act4, stats + 2 * 512, stats + 3 * 512,
        128, 128, 64, 64);
    // mid 3: 64 -> 32, s2 p0
    conv_mfma_kernel<2,0><<<16 * 2 * 2, 256, 0, stream>>>(
        act4, w_mid + 3 * 2304, b_mid + 48, act5, stats + 3 * 512, stats + 4 * 512,
        64, 64, 32, 32);
    // mid 4: 32 -> 32, s1 p1
    conv_mfma_kernel<1,1><<<16 * 2 * 2, 256, 0, stream>>>(
        act5, w_mid + 4 * 2304, b_mid + 64, act6, stats + 4 * 512, stats + 5 * 512,
        32, 32, 32, 32);
    // mid 5
    conv_mfma_kernel<1,1><<<16 * 2 * 2, 256, 0, stream>>>(
        act6, w_mid + 5 * 2304, b_mid + 80, act5, stats + 5 * 512, stats + 6 * 512,
        32, 32, 32, 32);
    // mid 6
    conv_mfma_kernel<1,1><<<16 * 2 * 2, 256, 0, stream>>>(
        act5, w_mid + 6 * 2304, b_mid + 96, act6, stats + 6 * 512, stats + 7 * 512,
        32, 32, 32, 32);

    // last conv + tanh + control points -> d_out[1..]
    float* cps_out = out + 1;
    conv_last_cps_kernel<<<(BB * 33 * 33 + 255) / 256, 256, 0, stream>>>(
        act6, w_last, b_last, stats + 7 * 512, cps_out);

    // losses
    area_loss_kernel<<<4096, 256, 0, stream>>>(image, cps_out, lacc);
    edge_loss_kernel<<<(BB * 1089 + 255) / 256, 256, 0, stream>>>(edge, cps_out, lacc);
    finalize_kernel<<<1, 1, 0, stream>>>(lacc, out);
}

// Round 8
// 406.126 us; speedup vs baseline: 3.0178x; 1.0273x over previous
//
#include <hip/hip_runtime.h>
#include <hip/hip_fp16.h>
#include <math.h>

#define BB 16
#define HH 512
#define WW 512

typedef _Float16 half8 __attribute__((ext_vector_type(8)));
typedef float f32x4 __attribute__((ext_vector_type(4)));

// ---------- helpers ----------
__device__ __forceinline__ void store16(__half* p, const float* v){
    #pragma unroll
    for (int i = 0; i < 2; i++){
        uint4 u;
        unsigned* pu = reinterpret_cast<unsigned*>(&u);
        #pragma unroll
        for (int j = 0; j < 4; j++){
            __half2 h = __floats2half2_rn(v[8*i + 2*j], v[8*i + 2*j + 1]);
            pu[j] = *reinterpret_cast<unsigned*>(&h);
        }
        ((uint4*)p)[i] = u;
    }
}

__device__ __forceinline__ float gelu_tanh(float v){
    float u = 0.7978845608028654f * (v + 0.044715f * v * v * v);
    float e = __expf(2.f * u);
    return v - v * __builtin_amdgcn_rcpf(e + 1.f);
}
__device__ __forceinline__ float diff_round(float x){
    const float TWO_PI = 6.283185307179586f;
    const float INV_TWO_PI = 0.15915494309189535f;
    return x - __sinf(TWO_PI * x) * INV_TWO_PI;
}

// ---------------- Fused Farid + first conv: 32x16 tile, 2 outputs/thread ----------------
// LDS: w[0,288) | img 22x38 (stride 40) | edge 18x34 (stride 40). Epilogue reuses [0,4352).
// Edge outside the image is 0 (matches reference zero-pad of concat(img,edge)).
__global__ __launch_bounds__(256) void farid_conv_first_kernel(
        const float* __restrict__ img, const float* __restrict__ w,
        const float* __restrict__ bias,
        __half* __restrict__ out, float* __restrict__ stats_out){
    __shared__ float smem[4608];
    __shared__ float sb[16];
    float* simg = smem + 288;          // 22 rows x 40
    float* sedge = smem + 1168;        // 18 rows x 40
    int t = threadIdx.x;
    int bid = blockIdx.x;
    int tx0 = (bid & 15) << 5;           // 16 x-tiles of 32
    int ty0 = ((bid >> 4) & 31) << 4;    // 32 y-tiles of 16
    int b   = bid >> 9;
    const float* ib = img + (size_t)b * HH * WW;

    for (int i = t; i < 288; i += 256) smem[i] = w[i];
    if (t < 16) sb[t] = bias[t];
    // stage img tile [ty0-3, ty0+19) x [tx0-3, tx0+35)
    for (int i = t; i < 22 * 38; i += 256){
        int r = i / 38, c = i - r * 38;
        int gy = ty0 - 3 + r, gx = tx0 - 3 + c;
        float v = 0.f;
        if (gy >= 0 && gy < HH && gx >= 0 && gx < WW) v = ib[gy * WW + gx];
        simg[r * 40 + c] = v;
    }
    __syncthreads();

    // edge region [ty0-1, ty0+17) x [tx0-1, tx0+33): 18x34
    const float fp[5] = {0.03032f, 0.249724f, 0.439911f, 0.249724f, 0.03032f};
    const float fd[5] = {0.10455f, 0.292315f, 0.0f, -0.292315f, -0.10455f};
    for (int i = t; i < 18 * 34; i += 256){
        int r = i / 34, c = i - r * 34;
        int gy = ty0 - 1 + r, gx = tx0 - 1 + c;
        float e = 0.f;
        if (gy >= 0 && gy < HH && gx >= 0 && gx < WW){
            float gxx = 0.f, gyy = 0.f;
            #pragma unroll
            for (int di = 0; di < 5; di++){
                #pragma unroll
                for (int dj = 0; dj < 5; dj++){
                    float v = simg[(r + di) * 40 + (c + dj)];
                    gxx += fp[di] * fd[dj] * v;
                    gyy += fd[di] * fp[dj] * v;
                }
            }
            e = sqrtf(gxx * gxx + gyy * gyy + 1e-8f);
        }
        sedge[r * 40 + c] = e;
    }
    __syncthreads();

    int tx = t & 31, ty = t >> 5;       // 2 output pixels: rows ty and ty+8
    float acc0[16], acc1[16];
    #pragma unroll
    for (int c = 0; c < 16; c++){ acc0[c] = sb[c]; acc1[c] = sb[c]; }
    #pragma unroll
    for (int dy = -1; dy <= 1; dy++){
        #pragma unroll
        for (int dx = -1; dx <= 1; dx++){
            const float* wp = smem + ((dy + 1) * 3 + (dx + 1)) * 32;  // (kh,kw,2,16)
            float a0 = simg[(ty + 3 + dy) * 40 + (tx + 3 + dx)];
            float e0 = sedge[(ty + 1 + dy) * 40 + (tx + 1 + dx)];
            float a1 = simg[(ty + 11 + dy) * 40 + (tx + 3 + dx)];
            float e1 = sedge[(ty + 9 + dy) * 40 + (tx + 1 + dx)];
            #pragma unroll
            for (int c = 0; c < 16; c++){
                float wc0 = wp[c], wc1 = wp[16 + c];
                acc0[c] += a0 * wc0 + e0 * wc1;
                acc1[c] += a1 * wc0 + e1 * wc1;
            }
        }
    }
    size_t idx0 = ((size_t)b * HH + ty0 + ty) * WW + tx0 + tx;
    size_t idx1 = ((size_t)b * HH + ty0 + ty + 8) * WW + tx0 + tx;
    store16(out + idx0 * 16, acc0);
    store16(out + idx1 * 16, acc1);

    // ---- stats epilogue (reuses smem) ----
    float sumc[16], sqc[16];
    #pragma unroll
    for (int c = 0; c < 16; c++){
        sumc[c] = acc0[c] + acc1[c];
        sqc[c]  = acc0[c] * acc0[c] + acc1[c] * acc1[c];
    }
    __syncthreads();
    #pragma unroll
    for (int c = 0; c < 16; c++) smem[t * 17 + c] = sumc[c];
    __syncthreads();
    int cc = t & 15;
    int r0 = (t >> 4) << 4;
    float s = 0.f;
    #pragma unroll
    for (int i = 0; i < 16; i++) s += smem[(r0 + i) * 17 + cc];
    __syncthreads();
    #pragma unroll
    for (int c = 0; c < 16; c++) smem[t * 17 + c] = sqc[c];
    __syncthreads();
    float q = 0.f;
    #pragma unroll
    for (int i = 0; i < 16; i++) q += smem[(r0 + i) * 17 + cc];
    __syncthreads();
    smem[t] = s; smem[256 + t] = q;
    __syncthreads();
    if (t < 32){
        bool isq = t >= 16;
        int c2 = t & 15;
        const float* p = smem + (isq ? 256 : 0);
        float a = 0.f;
        #pragma unroll
        for (int k = 0; k < 16; k++) a += p[k * 16 + c2];
        atomicAdd(&stats_out[(isq ? 256 : 0) + b * 16 + c2], a);
    }
}

// ---------------- MFMA conv 16->16: norm+gelu on load, 16x16 out tile / block ----------------
template<int STRIDE, int PAD>
__global__ __launch_bounds__(256) void conv_mfma_kernel(
        const __half* __restrict__ in, const float* __restrict__ w,
        const float* __restrict__ bias, __half* __restrict__ out,
        const float* __restrict__ stats_in, float* __restrict__ stats_out,
        int Hin, int Win, int Hout, int Wout){
    __shared__ float sred[2][4][16];
    int t = threadIdx.x;
    int lane = t & 63;
    int wv = t >> 6;
    int col = lane & 15;          // A pixel-x offset / B-D out-channel
    int g = lane >> 4;            // k-group
    int ci0 = (g & 1) * 8;        // channel slice of this lane's k chunk
    int tsel = g >> 1;            // which tap of the pair

    int nTx = Wout >> 4;
    int nTy = Hout >> 4;
    int bid = blockIdx.x;
    int tx = bid % nTx;
    int ty = (bid / nTx) % nTy;
    int b  = bid / (nTx * nTy);

    float mean[8], rstd[8];
    float invN = 1.f / (float)(Hin * Win);
    #pragma unroll
    for (int j = 0; j < 8; j++){
        int c = ci0 + j;
        float mm = stats_in[b * 16 + c] * invN;
        float vv = stats_in[256 + b * 16 + c] * invN - mm * mm;
        mean[j] = mm;
        rstd[j] = rsqrtf(vv + 1e-5f);
    }

    half8 bfrag[5];
    #pragma unroll
    for (int p = 0; p < 5; p++){
        int tp = 2 * p + tsel;
        #pragma unroll
        for (int j = 0; j < 8; j++)
            bfrag[p][j] = (tp < 9) ? (_Float16)w[(tp * 16 + ci0 + j) * 16 + col]
                                   : (_Float16)0.f;
    }
    float bia = bias[col];

    int xg = tx * 16 + col;
    float ssum = 0.f, ssq = 0.f;

    #pragma unroll
    for (int s = 0; s < 4; s++){
        int r = ty * 16 + wv * 4 + s;
        f32x4 acc = {bia, bia, bia, bia};
        #pragma unroll
        for (int p = 0; p < 5; p++){
            int tp = 2 * p + tsel;
            int ky = tp / 3, kx = tp - ky * 3;
            int iy = r * STRIDE + ky - PAD;
            int ix = xg * STRIDE + kx - PAD;
            bool valid = (tp < 9) && (iy >= 0) && (iy < Hin) && (ix >= 0) && (ix < Win);
            half8 afrag;
            #pragma unroll
            for (int j = 0; j < 8; j++) afrag[j] = (_Float16)0.f;
            if (valid){
                const __half* ap = in + ((((size_t)b * Hin + iy) * Win + ix) << 4) + ci0;
                uint4 u = *(const uint4*)ap;
                unsigned* pu = reinterpret_cast<unsigned*>(&u);
                #pragma unroll
                for (int q = 0; q < 4; q++){
                    __half2 h = *reinterpret_cast<__half2*>(&pu[q]);
                    float2 f = __half22float2(h);
                    float a0 = gelu_tanh((f.x - mean[2*q])   * rstd[2*q]);
                    float a1 = gelu_tanh((f.y - mean[2*q+1]) * rstd[2*q+1]);
                    afrag[2*q]   = (_Float16)a0;
                    afrag[2*q+1] = (_Float16)a1;
                }
            }
            acc = __builtin_amdgcn_mfma_f32_16x16x32_f16(afrag, bfrag[p], acc, 0, 0, 0);
        }
        #pragma unroll
        for (int rg = 0; rg < 4; rg++){
            int px = tx * 16 + 4 * g + rg;
            float v = acc[rg];
            out[(((size_t)b * Hout + r) * Wout + px) * 16 + col] = __float2half(v);
            ssum += v;
            ssq += v * v;
        }
    }

    ssum += __shfl_xor(ssum, 16); ssq += __shfl_xor(ssq, 16);
    ssum += __shfl_xor(ssum, 32); ssq += __shfl_xor(ssq, 32);
    if (lane < 16){ sred[0][wv][lane] = ssum; sred[1][wv][lane] = ssq; }
    __syncthreads();
    if (t < 32){
        int isq = t >> 4, c = t & 15;
        float a = sred[isq][0][c] + sred[isq][1][c] + sred[isq][2][c] + sred[isq][3][c];
        atomicAdd(&stats_out[isq * 256 + b * 16 + c], a);
    }
}

// ---------------- Last conv (16->2), norm+gelu on load, tanh, control points ----------------
__global__ void conv_last_cps_kernel(const __half* __restrict__ act, const float* __restrict__ w,
                                     const float* __restrict__ bias,
                                     const float* __restrict__ stats,
                                     float* __restrict__ cps){
    int idx = blockIdx.x * blockDim.x + threadIdx.x;
    if (idx >= BB * 33 * 33) return;
    int j = idx % 33;
    int i = (idx / 33) % 33;
    int b = idx / (33 * 33);
    float cy = (float)(i * 16);
    float cx = (float)(j * 16);
    if (i < 32 && j < 32){
        float mean[16], rstd[16];
        const float invN = 1.f / 1024.f;
        #pragma unroll
        for (int c = 0; c < 16; c++){
            float mm = stats[b * 16 + c] * invN;
            float vv = stats[256 + b * 16 + c] * invN - mm * mm;
            mean[c] = mm;
            rstd[c] = rsqrtf(vv + 1e-5f);
        }
        float a0 = bias[0], a1 = bias[1];
        for (int ky = 0; ky < 3; ky++){
            int iy = i + ky - 1;
            if (iy < 0 || iy >= 32) continue;
            for (int kx = 0; kx < 3; kx++){
                int ix = j + kx - 1;
                if (ix < 0 || ix >= 32) continue;
                const __half* ip = act + (((size_t)b * 32 + iy) * 32 + ix) * 16;
                const float* wp = w + (ky * 3 + kx) * 32;  // (kh,kw,16,2)
                #pragma unroll
                for (int ci = 0; ci < 16; ci++){
                    float v = gelu_tanh((__half2float(ip[ci]) - mean[ci]) * rstd[ci]);
                    a0 += v * wp[ci * 2];
                    a1 += v * wp[ci * 2 + 1];
                }
            }
        }
        cy += tanhf(a0) * 8.f;
        cx += tanhf(a1) * 8.f;
    }
    cps[idx * 2] = cy;
    cps[idx * 2 + 1] = cx;
}

// ---------------- Area loss: 16-lane group per area, single-pass variance ----------------
__global__ __launch_bounds__(256) void area_loss_kernel(
        const float* __restrict__ img, const float* __restrict__ cps,
        float* __restrict__ acc){
    __shared__ float sv[16];
    int t = threadIdx.x;
    int lane = t & 63;
    int wv = t >> 6;
    int g = lane >> 4;
    int l2 = lane & 15;
    int aidx = blockIdx.x * 16 + wv * 4 + g;   // 0 .. 65535
    int b = aidx >> 12;
    int rem = aidx & 4095;
    int o = rem >> 10;
    int ar = rem & 1023;
    int by = ar >> 5;
    int bx = ar & 31;
    int sy = (o & 2) ? 8 : 0;
    int sx = (o & 1) ? 8 : 0;
    float cpy = cps[((b * 33 + by) * 33 + bx) * 2 + 0];
    float cpx = cps[((b * 33 + by) * 33 + bx) * 2 + 1];
    int y0 = sy - 8 + by * 16;
    int x0 = sx - 8 + bx * 16;
    int x = x0 + l2;
    bool xok = (x >= 0 && x < WW);
    float dx = (float)x - cpx;
    float dx2 = dx * dx;
    float A = 0.f, Bs = 0.f, C = 0.f, D = 0.f, E = 0.f;
    #pragma unroll
    for (int k = 0; k < 16; k++){
        int y = y0 + k;
        float r = 0.f;
        if (xok && y >= 0 && y < HH)
            r = img[((size_t)b * HH + y) * WW + x];
        float dy = (float)y - cpy;
        float m = __expf(-(dy * dy + dx2) * (1.f / 128.f));
        m = diff_round(diff_round(m));
        float rm = r * m;
        float m2 = m * m;
        A += m; Bs += rm; E += m2;
        D += rm * m2;
        C += rm * rm * m2;
    }
    #pragma unroll
    for (int off = 8; off >= 1; off >>= 1){
        A  += __shfl_xor(A, off);
        Bs += __shfl_xor(Bs, off);
        C  += __shfl_xor(C, off);
        D  += __shfl_xor(D, off);
        E  += __shfl_xor(E, off);
    }
    if (l2 == 0){
        float rden = __builtin_amdgcn_rcpf(A + 1e-7f);
        float mean = (Bs + 256.f * 1e-7f) * rden;
        float sdev = C - 2.f * mean * D + mean * mean * E;
        float varr = (sdev + 256.f * 1e-7f) * rden;
        sv[wv * 4 + g] = varr;
    }
    __syncthreads();
    if (t == 0){
        float s = 0.f;
        #pragma unroll
        for (int i2 = 0; i2 < 16; i2++) s += sv[i2];
        atomicAdd(&acc[blockIdx.x & 63], s);
    }
}

// ---------------- Edge sampling loss (recomputes farid inline; no edge buffer) ----------------
__device__ __forceinline__ float farid_at(const float* __restrict__ ib, int y, int x){
    const float fp[5] = {0.03032f, 0.249724f, 0.439911f, 0.249724f, 0.03032f};
    const float fd[5] = {0.10455f, 0.292315f, 0.0f, -0.292315f, -0.10455f};
    float gxx = 0.f, gyy = 0.f;
    #pragma unroll
    for (int i = 0; i < 5; i++){
        int yy = y + i - 2;
        if (yy < 0 || yy >= HH) continue;
        #pragma unroll
        for (int j = 0; j < 5; j++){
            int xx = x + j - 2;
            if (xx < 0 || xx >= WW) continue;
            float v = ib[yy * WW + xx];
            gxx += fp[i] * fd[j] * v;
            gyy += fd[i] * fp[j] * v;
        }
    }
    return sqrtf(gxx * gxx + gyy * gyy + 1e-8f);
}

__global__ void edge_loss_kernel(const float* __restrict__ img, const float* __restrict__ cps,
                                 float* __restrict__ acc){
    __shared__ float s1[256];
    int idx = blockIdx.x * blockDim.x + threadIdx.x;
    float v = 0.f;
    if (idx < BB * 1089){
        int b = idx / 1089;
        int p = idx % 1089;
        float y = cps[((size_t)b * 1089 + p) * 2 + 0];
        float x = cps[((size_t)b * 1089 + p) * 2 + 1];
        y = fminf(fmaxf(y, 0.f), 510.999f);
        x = fminf(fmaxf(x, 0.f), 510.999f);
        int y0 = (int)floorf(y);
        int x0 = (int)floorf(x);
        float wy = y - (float)y0;
        float wx = x - (float)x0;
        const float* ib = img + (size_t)b * HH * WW;
        float v00 = farid_at(ib, y0, x0);
        float v01 = farid_at(ib, y0, x0 + 1);
        float v10 = farid_at(ib, y0 + 1, x0);
        float v11 = farid_at(ib, y0 + 1, x0 + 1);
        v = v00 * (1 - wy) * (1 - wx) + v01 * (1 - wy) * wx + v10 * wy * (1 - wx) + v11 * wy * wx;
    }
    int t = threadIdx.x;
    s1[t] = v;
    __syncthreads();
    for (int off = 128; off > 0; off >>= 1){
        if (t < off) s1[t] += s1[t + off];
        __syncthreads();
    }
    if (t == 0) atomicAdd(&acc[64 + (blockIdx.x & 3)], s1[0]);
}

__global__ void finalize_kernel(const float* __restrict__ lacc, float* __restrict__ out){
    float a = 0.f, e = 0.f;
    for (int i = 0; i < 64; i++) a += lacc[i];
    for (int i = 0; i < 4; i++) e += lacc[64 + i];
    out[0] = (a / 65536.f) * (e / 17424.f);
}

extern "C" void kernel_launch(void* const* d_in, const int* in_sizes, int n_in,
                              void* d_out, int out_size, void* d_ws, size_t ws_size,
                              hipStream_t stream) {
    const float* image  = (const float*)d_in[0];
    const float* w_first= (const float*)d_in[1];
    const float* b_first= (const float*)d_in[2];
    const float* w_mid  = (const float*)d_in[3];
    const float* b_mid  = (const float*)d_in[4];
    const float* w_last = (const float*)d_in[5];
    const float* b_last = (const float*)d_in[6];
    float* out = (float*)d_out;
    char* ws = (char*)d_ws;

    // ---- workspace layout (all activations fp16, stored pre-norm; no edge buffer) ----
    float* stats = (float*)ws;                 // 8 layers * 512 floats
    float* lacc  = stats + 8 * 512;            // 128 floats
    size_t off = (8 * 512 + 128) * sizeof(float);
    __half* act1 = (__half*)(ws + off); off += (size_t)BB * 512 * 512 * 16 * 2;
    __half* act2 = (__half*)(ws + off); off += (size_t)BB * 256 * 256 * 16 * 2;
    __half* act3 = (__half*)(ws + off); off += (size_t)BB * 128 * 128 * 16 * 2;
    __half* act4 = (__half*)(ws + off); off += (size_t)BB * 64 * 64 * 16 * 2;
    __half* act5 = (__half*)(ws + off); off += (size_t)BB * 32 * 32 * 16 * 2;
    __half* act6 = (__half*)(ws + off); off += (size_t)BB * 32 * 32 * 16 * 2;

    hipMemsetAsync(ws, 0, (8 * 512 + 128) * sizeof(float), stream);

    // fused farid + conv_first + stats0
    farid_conv_first_kernel<<<16 * 32 * 16, 256, 0, stream>>>(
        image, w_first, b_first, act1, stats + 0 * 512);

    // mid 0: 512 -> 256, s2 p0
    conv_mfma_kernel<2,0><<<16 * 16 * 16, 256, 0, stream>>>(
        act1, w_mid + 0 * 2304, b_mid + 0, act2, stats + 0 * 512, stats + 1 * 512,
        512, 512, 256, 256);
    // mid 1: 256 -> 128, s2 p0
    conv_mfma_kernel<2,0><<<16 * 8 * 8, 256, 0, stream>>>(
        act2, w_mid + 1 * 2304, b_mid + 16, act3, stats + 1 * 512, stats + 2 * 512,
        256, 256, 128, 128);
    // mid 2: 128 -> 64, s2 p0
    conv_mfma_kernel<2,0><<<16 * 4 * 4, 256, 0, stream>>>(
        act3, w_mid + 2 * 2304, b_mid + 32, act4, stats + 2 * 512, stats + 3 * 512,
        128, 128, 64, 64);
    // mid 3: 64 -> 32, s2 p0
    conv_mfma_kernel<2,0><<<16 * 2 * 2, 256, 0, stream>>>(
        act4, w_mid + 3 * 2304, b_mid + 48, act5, stats + 3 * 512, stats + 4 * 512,
        64, 64, 32, 32);
    // mid 4: 32 -> 32, s1 p1
    conv_mfma_kernel<1,1><<<16 * 2 * 2, 256, 0, stream>>>(
        act5, w_mid + 4 * 2304, b_mid + 64, act6, stats + 4 * 512, stats + 5 * 512,
        32, 32, 32, 32);
    // mid 5
    conv_mfma_kernel<1,1><<<16 * 2 * 2, 256, 0, stream>>>(
        act6, w_mid + 5 * 2304, b_mid + 80, act5, stats + 5 * 512, stats + 6 * 512,
        32, 32, 32, 32);
    // mid 6
    conv_mfma_kernel<1,1><<<16 * 2 * 2, 256, 0, stream>>>(
        act5, w_mid + 6 * 2304, b_mid + 96, act6, stats + 6 * 512, stats + 7 * 512,
        32, 32, 32, 32);

    // last conv + tanh + control points -> d_out[1..]
    float* cps_out = out + 1;
    conv_last_cps_kernel<<<(BB * 33 * 33 + 255) / 256, 256, 0, stream>>>(
        act6, w_last, b_last, stats + 7 * 512, cps_out);

    // losses
    area_loss_kernel<<<4096, 256, 0, stream>>>(image, cps_out, lacc);
    edge_loss_kernel<<<(BB * 1089 + 255) / 256, 256, 0, stream>>>(image, cps_out, lacc);
    finalize_kernel<<<1, 1, 0, stream>>>(lacc, out);
}

// Round 9
// 350.150 us; speedup vs baseline: 3.5003x; 1.1599x over previous
//
#include <hip/hip_runtime.h>
#include <hip/hip_fp16.h>
#include <math.h>

#define BB 16
#define HH 512
#define WW 512

typedef _Float16 half8 __attribute__((ext_vector_type(8)));
typedef float f32x4 __attribute__((ext_vector_type(4)));

// ---------- helpers ----------
__device__ __forceinline__ void store16(__half* p, const float* v){
    #pragma unroll
    for (int i = 0; i < 2; i++){
        uint4 u;
        unsigned* pu = reinterpret_cast<unsigned*>(&u);
        #pragma unroll
        for (int j = 0; j < 4; j++){
            __half2 h = __floats2half2_rn(v[8*i + 2*j], v[8*i + 2*j + 1]);
            pu[j] = *reinterpret_cast<unsigned*>(&h);
        }
        ((uint4*)p)[i] = u;
    }
}

__device__ __forceinline__ float gelu_tanh(float v){
    float u = 0.7978845608028654f * (v + 0.044715f * v * v * v);
    float e = __expf(2.f * u);
    return v - v * __builtin_amdgcn_rcpf(e + 1.f);
}
__device__ __forceinline__ float diff_round(float x){
    const float TWO_PI = 6.283185307179586f;
    const float INV_TWO_PI = 0.15915494309189535f;
    return x - __sinf(TWO_PI * x) * INV_TWO_PI;
}

// ---------------- Fused Farid + first conv: 32x16 tile, 2 outputs/thread ----------------
__global__ __launch_bounds__(256) void farid_conv_first_kernel(
        const float* __restrict__ img, const float* __restrict__ w,
        const float* __restrict__ bias,
        __half* __restrict__ out, float* __restrict__ stats_out){
    __shared__ float smem[4608];
    __shared__ float sb[16];
    float* simg = smem + 288;          // 22 rows x 40
    float* sedge = smem + 1168;        // 18 rows x 40
    int t = threadIdx.x;
    int bid = blockIdx.x;
    int tx0 = (bid & 15) << 5;           // 16 x-tiles of 32
    int ty0 = ((bid >> 4) & 31) << 4;    // 32 y-tiles of 16
    int b   = bid >> 9;
    const float* ib = img + (size_t)b * HH * WW;

    for (int i = t; i < 288; i += 256) smem[i] = w[i];
    if (t < 16) sb[t] = bias[t];
    for (int i = t; i < 22 * 38; i += 256){
        int r = i / 38, c = i - r * 38;
        int gy = ty0 - 3 + r, gx = tx0 - 3 + c;
        float v = 0.f;
        if (gy >= 0 && gy < HH && gx >= 0 && gx < WW) v = ib[gy * WW + gx];
        simg[r * 40 + c] = v;
    }
    __syncthreads();

    const float fp[5] = {0.03032f, 0.249724f, 0.439911f, 0.249724f, 0.03032f};
    const float fd[5] = {0.10455f, 0.292315f, 0.0f, -0.292315f, -0.10455f};
    for (int i = t; i < 18 * 34; i += 256){
        int r = i / 34, c = i - r * 34;
        int gy = ty0 - 1 + r, gx = tx0 - 1 + c;
        float e = 0.f;
        if (gy >= 0 && gy < HH && gx >= 0 && gx < WW){
            float gxx = 0.f, gyy = 0.f;
            #pragma unroll
            for (int di = 0; di < 5; di++){
                #pragma unroll
                for (int dj = 0; dj < 5; dj++){
                    float v = simg[(r + di) * 40 + (c + dj)];
                    gxx += fp[di] * fd[dj] * v;
                    gyy += fd[di] * fp[dj] * v;
                }
            }
            e = sqrtf(gxx * gxx + gyy * gyy + 1e-8f);
        }
        sedge[r * 40 + c] = e;
    }
    __syncthreads();

    int tx = t & 31, ty = t >> 5;       // 2 output pixels: rows ty and ty+8
    float acc0[16], acc1[16];
    #pragma unroll
    for (int c = 0; c < 16; c++){ acc0[c] = sb[c]; acc1[c] = sb[c]; }
    #pragma unroll
    for (int dy = -1; dy <= 1; dy++){
        #pragma unroll
        for (int dx = -1; dx <= 1; dx++){
            const float* wp = smem + ((dy + 1) * 3 + (dx + 1)) * 32;  // (kh,kw,2,16)
            float a0 = simg[(ty + 3 + dy) * 40 + (tx + 3 + dx)];
            float e0 = sedge[(ty + 1 + dy) * 40 + (tx + 1 + dx)];
            float a1 = simg[(ty + 11 + dy) * 40 + (tx + 3 + dx)];
            float e1 = sedge[(ty + 9 + dy) * 40 + (tx + 1 + dx)];
            #pragma unroll
            for (int c = 0; c < 16; c++){
                float wc0 = wp[c], wc1 = wp[16 + c];
                acc0[c] += a0 * wc0 + e0 * wc1;
                acc1[c] += a1 * wc0 + e1 * wc1;
            }
        }
    }
    size_t idx0 = ((size_t)b * HH + ty0 + ty) * WW + tx0 + tx;
    size_t idx1 = ((size_t)b * HH + ty0 + ty + 8) * WW + tx0 + tx;
    store16(out + idx0 * 16, acc0);
    store16(out + idx1 * 16, acc1);

    // ---- stats epilogue ----
    float sumc[16], sqc[16];
    #pragma unroll
    for (int c = 0; c < 16; c++){
        sumc[c] = acc0[c] + acc1[c];
        sqc[c]  = acc0[c] * acc0[c] + acc1[c] * acc1[c];
    }
    __syncthreads();
    #pragma unroll
    for (int c = 0; c < 16; c++) smem[t * 17 + c] = sumc[c];
    __syncthreads();
    int cc = t & 15;
    int r0 = (t >> 4) << 4;
    float s = 0.f;
    #pragma unroll
    for (int i = 0; i < 16; i++) s += smem[(r0 + i) * 17 + cc];
    __syncthreads();
    #pragma unroll
    for (int c = 0; c < 16; c++) smem[t * 17 + c] = sqc[c];
    __syncthreads();
    float q = 0.f;
    #pragma unroll
    for (int i = 0; i < 16; i++) q += smem[(r0 + i) * 17 + cc];
    __syncthreads();
    smem[t] = s; smem[256 + t] = q;
    __syncthreads();
    if (t < 32){
        bool isq = t >= 16;
        int c2 = t & 15;
        const float* p = smem + (isq ? 256 : 0);
        float a = 0.f;
        #pragma unroll
        for (int k = 0; k < 16; k++) a += p[k * 16 + c2];
        atomicAdd(&stats_out[(isq ? 256 : 0) + b * 16 + c2], a);
    }
}

// ---------------- Stride-2 MFMA conv with LDS-staged normalized input ----------------
// Block = 16x16 outputs. Input tile 33x33x16 fp16 staged post-norm+gelu into LDS.
// LDS layout [parity=lc&1][h=chhalf][me=lc>>1 (17)][lr (33)] x 16B, me-stride 33 (odd)
// -> stride-2 fragment reads are bank-spread. OOB pixels staged as 0 (= reference pad).
__global__ __launch_bounds__(256) void conv_mfma_s2_kernel(
        const __half* __restrict__ in, const float* __restrict__ w,
        const float* __restrict__ bias, __half* __restrict__ out,
        const float* __restrict__ stats_in, float* __restrict__ stats_out,
        int Hin, int Win, int Hout, int Wout){
    __shared__ uint4 stile[2244];          // 2*2*17*33 blocks of 16B = 35904 B
    __shared__ float snm[32];
    __shared__ float sred[2][4][16];
    int t = threadIdx.x;
    int nTx = Wout >> 4;
    int nTy = Hout >> 4;
    int bid = blockIdx.x;
    int tx = bid % nTx;
    int ty = (bid / nTx) % nTy;
    int b  = bid / (nTx * nTy);

    if (t < 16){
        float invN = 1.f / (float)(Hin * Win);
        float mm = stats_in[b * 16 + t] * invN;
        float vv = stats_in[256 + b * 16 + t] * invN - mm * mm;
        snm[t] = mm;
        snm[16 + t] = rsqrtf(vv + 1e-5f);
    }
    __syncthreads();

    // ---- stage 33x33 normalized tile ----
    int iy0 = ty << 5, ix0 = tx << 5;
    for (int i = t; i < 33 * 33; i += 256){
        int lr = i / 33, lc = i - lr * 33;
        int gy = iy0 + lr, gx = ix0 + lc;
        uint4 h0 = {0,0,0,0}, h1 = {0,0,0,0};
        if (gy < Hin && gx < Win){
            const uint4* ap = (const uint4*)(in + ((((size_t)b * Hin + gy) * Win + gx) << 4));
            uint4 u0 = ap[0], u1 = ap[1];
            unsigned* pu0 = reinterpret_cast<unsigned*>(&u0);
            unsigned* pr0 = reinterpret_cast<unsigned*>(&h0);
            unsigned* pu1 = reinterpret_cast<unsigned*>(&u1);
            unsigned* pr1 = reinterpret_cast<unsigned*>(&h1);
            #pragma unroll
            for (int q = 0; q < 4; q++){
                __half2 hh = *reinterpret_cast<__half2*>(&pu0[q]);
                float2 f = __half22float2(hh);
                float a0 = gelu_tanh((f.x - snm[2*q])   * snm[16 + 2*q]);
                float a1 = gelu_tanh((f.y - snm[2*q+1]) * snm[16 + 2*q+1]);
                __half2 o = __floats2half2_rn(a0, a1);
                pr0[q] = *reinterpret_cast<unsigned*>(&o);
            }
            #pragma unroll
            for (int q = 0; q < 4; q++){
                __half2 hh = *reinterpret_cast<__half2*>(&pu1[q]);
                float2 f = __half22float2(hh);
                float a0 = gelu_tanh((f.x - snm[8 + 2*q])   * snm[24 + 2*q]);
                float a1 = gelu_tanh((f.y - snm[8 + 2*q+1]) * snm[24 + 2*q+1]);
                __half2 o = __floats2half2_rn(a0, a1);
                pr1[q] = *reinterpret_cast<unsigned*>(&o);
            }
        }
        int parity = lc & 1, me = lc >> 1;
        stile[((parity * 2 + 0) * 17 + me) * 33 + lr] = h0;
        stile[((parity * 2 + 1) * 17 + me) * 33 + lr] = h1;
    }
    __syncthreads();

    // ---- MFMA main loop ----
    int lane = t & 63;
    int wv = t >> 6;
    int col = lane & 15;          // output pixel x within tile / out-channel for B,D
    int g = lane >> 4;
    int h = g & 1;
    int ci0 = h * 8;
    int tsel = g >> 1;

    half8 bfrag[5];
    #pragma unroll
    for (int p = 0; p < 5; p++){
        int tp = 2 * p + tsel;
        #pragma unroll
        for (int j = 0; j < 8; j++)
            bfrag[p][j] = (tp < 9) ? (_Float16)w[(tp * 16 + ci0 + j) * 16 + col]
                                   : (_Float16)0.f;
    }
    float bia = bias[col];
    float ssum = 0.f, ssq = 0.f;

    #pragma unroll
    for (int s = 0; s < 4; s++){
        int rl = wv * 4 + s;              // local out row
        f32x4 acc = {bia, bia, bia, bia};
        #pragma unroll
        for (int p = 0; p < 5; p++){
            int tp = 2 * p + tsel;
            half8 afrag;
            #pragma unroll
            for (int j = 0; j < 8; j++) afrag[j] = (_Float16)0.f;
            if (tp < 9){
                int ky = tp / 3, kx = tp - ky * 3;
                int lr = 2 * rl + ky;
                int lc = 2 * col + kx;
                int parity = lc & 1, me = lc >> 1;
                afrag = *(const half8*)&stile[((parity * 2 + h) * 17 + me) * 33 + lr];
            }
            acc = __builtin_amdgcn_mfma_f32_16x16x32_f16(afrag, bfrag[p], acc, 0, 0, 0);
        }
        int r = (ty << 4) + rl;
        #pragma unroll
        for (int rg = 0; rg < 4; rg++){
            int px = (tx << 4) + 4 * g + rg;
            float v = acc[rg];
            out[(((size_t)b * Hout + r) * Wout + px) * 16 + col] = __float2half(v);
            ssum += v;
            ssq += v * v;
        }
    }

    ssum += __shfl_xor(ssum, 16); ssq += __shfl_xor(ssq, 16);
    ssum += __shfl_xor(ssum, 32); ssq += __shfl_xor(ssq, 32);
    if (lane < 16){ sred[0][wv][lane] = ssum; sred[1][wv][lane] = ssq; }
    __syncthreads();
    if (t < 32){
        int isq = t >> 4, c = t & 15;
        float a = sred[isq][0][c] + sred[isq][1][c] + sred[isq][2][c] + sred[isq][3][c];
        atomicAdd(&stats_out[isq * 256 + b * 16 + c], a);
    }
}

// ---------------- Stride-1 MFMA conv (small 32x32 layers), unstaged ----------------
template<int STRIDE, int PAD>
__global__ __launch_bounds__(256) void conv_mfma_kernel(
        const __half* __restrict__ in, const float* __restrict__ w,
        const float* __restrict__ bias, __half* __restrict__ out,
        const float* __restrict__ stats_in, float* __restrict__ stats_out,
        int Hin, int Win, int Hout, int Wout){
    __shared__ float sred[2][4][16];
    int t = threadIdx.x;
    int lane = t & 63;
    int wv = t >> 6;
    int col = lane & 15;
    int g = lane >> 4;
    int ci0 = (g & 1) * 8;
    int tsel = g >> 1;

    int nTx = Wout >> 4;
    int nTy = Hout >> 4;
    int bid = blockIdx.x;
    int tx = bid % nTx;
    int ty = (bid / nTx) % nTy;
    int b  = bid / (nTx * nTy);

    float mean[8], rstd[8];
    float invN = 1.f / (float)(Hin * Win);
    #pragma unroll
    for (int j = 0; j < 8; j++){
        int c = ci0 + j;
        float mm = stats_in[b * 16 + c] * invN;
        float vv = stats_in[256 + b * 16 + c] * invN - mm * mm;
        mean[j] = mm;
        rstd[j] = rsqrtf(vv + 1e-5f);
    }

    half8 bfrag[5];
    #pragma unroll
    for (int p = 0; p < 5; p++){
        int tp = 2 * p + tsel;
        #pragma unroll
        for (int j = 0; j < 8; j++)
            bfrag[p][j] = (tp < 9) ? (_Float16)w[(tp * 16 + ci0 + j) * 16 + col]
                                   : (_Float16)0.f;
    }
    float bia = bias[col];

    int xg = tx * 16 + col;
    float ssum = 0.f, ssq = 0.f;

    #pragma unroll
    for (int s = 0; s < 4; s++){
        int r = ty * 16 + wv * 4 + s;
        f32x4 acc = {bia, bia, bia, bia};
        #pragma unroll
        for (int p = 0; p < 5; p++){
            int tp = 2 * p + tsel;
            int ky = tp / 3, kx = tp - ky * 3;
            int iy = r * STRIDE + ky - PAD;
            int ix = xg * STRIDE + kx - PAD;
            bool valid = (tp < 9) && (iy >= 0) && (iy < Hin) && (ix >= 0) && (ix < Win);
            half8 afrag;
            #pragma unroll
            for (int j = 0; j < 8; j++) afrag[j] = (_Float16)0.f;
            if (valid){
                const __half* ap = in + ((((size_t)b * Hin + iy) * Win + ix) << 4) + ci0;
                uint4 u = *(const uint4*)ap;
                unsigned* pu = reinterpret_cast<unsigned*>(&u);
                #pragma unroll
                for (int q = 0; q < 4; q++){
                    __half2 hh = *reinterpret_cast<__half2*>(&pu[q]);
                    float2 f = __half22float2(hh);
                    float a0 = gelu_tanh((f.x - mean[2*q])   * rstd[2*q]);
                    float a1 = gelu_tanh((f.y - mean[2*q+1]) * rstd[2*q+1]);
                    afrag[2*q]   = (_Float16)a0;
                    afrag[2*q+1] = (_Float16)a1;
                }
            }
            acc = __builtin_amdgcn_mfma_f32_16x16x32_f16(afrag, bfrag[p], acc, 0, 0, 0);
        }
        #pragma unroll
        for (int rg = 0; rg < 4; rg++){
            int px = tx * 16 + 4 * g + rg;
            float v = acc[rg];
            out[(((size_t)b * Hout + r) * Wout + px) * 16 + col] = __float2half(v);
            ssum += v;
            ssq += v * v;
        }
    }

    ssum += __shfl_xor(ssum, 16); ssq += __shfl_xor(ssq, 16);
    ssum += __shfl_xor(ssum, 32); ssq += __shfl_xor(ssq, 32);
    if (lane < 16){ sred[0][wv][lane] = ssum; sred[1][wv][lane] = ssq; }
    __syncthreads();
    if (t < 32){
        int isq = t >> 4, c = t & 15;
        float a = sred[isq][0][c] + sred[isq][1][c] + sred[isq][2][c] + sred[isq][3][c];
        atomicAdd(&stats_out[isq * 256 + b * 16 + c], a);
    }
}

// ---------------- Last conv (16->2), norm+gelu on load, tanh, control points ----------------
__global__ void conv_last_cps_kernel(const __half* __restrict__ act, const float* __restrict__ w,
                                     const float* __restrict__ bias,
                                     const float* __restrict__ stats,
                                     float* __restrict__ cps){
    int idx = blockIdx.x * blockDim.x + threadIdx.x;
    if (idx >= BB * 33 * 33) return;
    int j = idx % 33;
    int i = (idx / 33) % 33;
    int b = idx / (33 * 33);
    float cy = (float)(i * 16);
    float cx = (float)(j * 16);
    if (i < 32 && j < 32){
        float mean[16], rstd[16];
        const float invN = 1.f / 1024.f;
        #pragma unroll
        for (int c = 0; c < 16; c++){
            float mm = stats[b * 16 + c] * invN;
            float vv = stats[256 + b * 16 + c] * invN - mm * mm;
            mean[c] = mm;
            rstd[c] = rsqrtf(vv + 1e-5f);
        }
        float a0 = bias[0], a1 = bias[1];
        for (int ky = 0; ky < 3; ky++){
            int iy = i + ky - 1;
            if (iy < 0 || iy >= 32) continue;
            for (int kx = 0; kx < 3; kx++){
                int ix = j + kx - 1;
                if (ix < 0 || ix >= 32) continue;
                const __half* ip = act + (((size_t)b * 32 + iy) * 32 + ix) * 16;
                const float* wp = w + (ky * 3 + kx) * 32;  // (kh,kw,16,2)
                #pragma unroll
                for (int ci = 0; ci < 16; ci++){
                    float v = gelu_tanh((__half2float(ip[ci]) - mean[ci]) * rstd[ci]);
                    a0 += v * wp[ci * 2];
                    a1 += v * wp[ci * 2 + 1];
                }
            }
        }
        cy += tanhf(a0) * 8.f;
        cx += tanhf(a1) * 8.f;
    }
    cps[idx * 2] = cy;
    cps[idx * 2 + 1] = cx;
}

// ---------------- Area loss: 16-lane group per area, single-pass variance ----------------
__global__ __launch_bounds__(256) void area_loss_kernel(
        const float* __restrict__ img, const float* __restrict__ cps,
        float* __restrict__ acc){
    __shared__ float sv[16];
    int t = threadIdx.x;
    int lane = t & 63;
    int wv = t >> 6;
    int g = lane >> 4;
    int l2 = lane & 15;
    int aidx = blockIdx.x * 16 + wv * 4 + g;   // 0 .. 65535
    int b = aidx >> 12;
    int rem = aidx & 4095;
    int o = rem >> 10;
    int ar = rem & 1023;
    int by = ar >> 5;
    int bx = ar & 31;
    int sy = (o & 2) ? 8 : 0;
    int sx = (o & 1) ? 8 : 0;
    float cpy = cps[((b * 33 + by) * 33 + bx) * 2 + 0];
    float cpx = cps[((b * 33 + by) * 33 + bx) * 2 + 1];
    int y0 = sy - 8 + by * 16;
    int x0 = sx - 8 + bx * 16;
    int x = x0 + l2;
    bool xok = (x >= 0 && x < WW);
    float dx = (float)x - cpx;
    float dx2 = dx * dx;
    float A = 0.f, Bs = 0.f, C = 0.f, D = 0.f, E = 0.f;
    #pragma unroll
    for (int k = 0; k < 16; k++){
        int y = y0 + k;
        float r = 0.f;
        if (xok && y >= 0 && y < HH)
            r = img[((size_t)b * HH + y) * WW + x];
        float dy = (float)y - cpy;
        float m = __expf(-(dy * dy + dx2) * (1.f / 128.f));
        m = diff_round(diff_round(m));
        float rm = r * m;
        float m2 = m * m;
        A += m; Bs += rm; E += m2;
        D += rm * m2;
        C += rm * rm * m2;
    }
    #pragma unroll
    for (int off = 8; off >= 1; off >>= 1){
        A  += __shfl_xor(A, off);
        Bs += __shfl_xor(Bs, off);
        C  += __shfl_xor(C, off);
        D  += __shfl_xor(D, off);
        E  += __shfl_xor(E, off);
    }
    if (l2 == 0){
        float rden = __builtin_amdgcn_rcpf(A + 1e-7f);
        float mean = (Bs + 256.f * 1e-7f) * rden;
        float sdev = C - 2.f * mean * D + mean * mean * E;
        float varr = (sdev + 256.f * 1e-7f) * rden;
        sv[wv * 4 + g] = varr;
    }
    __syncthreads();
    if (t == 0){
        float s = 0.f;
        #pragma unroll
        for (int i2 = 0; i2 < 16; i2++) s += sv[i2];
        atomicAdd(&acc[blockIdx.x & 63], s);
    }
}

// ---------------- Edge sampling loss (recomputes farid inline; no edge buffer) ----------------
__device__ __forceinline__ float farid_at(const float* __restrict__ ib, int y, int x){
    const float fp[5] = {0.03032f, 0.249724f, 0.439911f, 0.249724f, 0.03032f};
    const float fd[5] = {0.10455f, 0.292315f, 0.0f, -0.292315f, -0.10455f};
    float gxx = 0.f, gyy = 0.f;
    #pragma unroll
    for (int i = 0; i < 5; i++){
        int yy = y + i - 2;
        if (yy < 0 || yy >= HH) continue;
        #pragma unroll
        for (int j = 0; j < 5; j++){
            int xx = x + j - 2;
            if (xx < 0 || xx >= WW) continue;
            float v = ib[yy * WW + xx];
            gxx += fp[i] * fd[j] * v;
            gyy += fd[i] * fp[j] * v;
        }
    }
    return sqrtf(gxx * gxx + gyy * gyy + 1e-8f);
}

__global__ void edge_loss_kernel(const float* __restrict__ img, const float* __restrict__ cps,
                                 float* __restrict__ acc){
    __shared__ float s1[256];
    int idx = blockIdx.x * blockDim.x + threadIdx.x;
    float v = 0.f;
    if (idx < BB * 1089){
        int b = idx / 1089;
        int p = idx % 1089;
        float y = cps[((size_t)b * 1089 + p) * 2 + 0];
        float x = cps[((size_t)b * 1089 + p) * 2 + 1];
        y = fminf(fmaxf(y, 0.f), 510.999f);
        x = fminf(fmaxf(x, 0.f), 510.999f);
        int y0 = (int)floorf(y);
        int x0 = (int)floorf(x);
        float wy = y - (float)y0;
        float wx = x - (float)x0;
        const float* ib = img + (size_t)b * HH * WW;
        float v00 = farid_at(ib, y0, x0);
        float v01 = farid_at(ib, y0, x0 + 1);
        float v10 = farid_at(ib, y0 + 1, x0);
        float v11 = farid_at(ib, y0 + 1, x0 + 1);
        v = v00 * (1 - wy) * (1 - wx) + v01 * (1 - wy) * wx + v10 * wy * (1 - wx) + v11 * wy * wx;
    }
    int t = threadIdx.x;
    s1[t] = v;
    __syncthreads();
    for (int off = 128; off > 0; off >>= 1){
        if (t < off) s1[t] += s1[t + off];
        __syncthreads();
    }
    if (t == 0) atomicAdd(&acc[64 + (blockIdx.x & 3)], s1[0]);
}

__global__ void finalize_kernel(const float* __restrict__ lacc, float* __restrict__ out){
    float a = 0.f, e = 0.f;
    for (int i = 0; i < 64; i++) a += lacc[i];
    for (int i = 0; i < 4; i++) e += lacc[64 + i];
    out[0] = (a / 65536.f) * (e / 17424.f);
}

extern "C" void kernel_launch(void* const* d_in, const int* in_sizes, int n_in,
                              void* d_out, int out_size, void* d_ws, size_t ws_size,
                              hipStream_t stream) {
    const float* image  = (const float*)d_in[0];
    const float* w_first= (const float*)d_in[1];
    const float* b_first= (const float*)d_in[2];
    const float* w_mid  = (const float*)d_in[3];
    const float* b_mid  = (const float*)d_in[4];
    const float* w_last = (const float*)d_in[5];
    const float* b_last = (const float*)d_in[6];
    float* out = (float*)d_out;
    char* ws = (char*)d_ws;

    // ---- workspace layout (all activations fp16, stored pre-norm; no edge buffer) ----
    float* stats = (float*)ws;                 // 8 layers * 512 floats
    float* lacc  = stats + 8 * 512;            // 128 floats
    size_t off = (8 * 512 + 128) * sizeof(float);
    __half* act1 = (__half*)(ws + off); off += (size_t)BB * 512 * 512 * 16 * 2;
    __half* act2 = (__half*)(ws + off); off += (size_t)BB * 256 * 256 * 16 * 2;
    __half* act3 = (__half*)(ws + off); off += (size_t)BB * 128 * 128 * 16 * 2;
    __half* act4 = (__half*)(ws + off); off += (size_t)BB * 64 * 64 * 16 * 2;
    __half* act5 = (__half*)(ws + off); off += (size_t)BB * 32 * 32 * 16 * 2;
    __half* act6 = (__half*)(ws + off); off += (size_t)BB * 32 * 32 * 16 * 2;

    hipMemsetAsync(ws, 0, (8 * 512 + 128) * sizeof(float), stream);

    // fused farid + conv_first + stats0
    farid_conv_first_kernel<<<16 * 32 * 16, 256, 0, stream>>>(
        image, w_first, b_first, act1, stats + 0 * 512);

    // mid 0: 512 -> 256, s2 p0 (LDS-staged)
    conv_mfma_s2_kernel<<<16 * 16 * 16, 256, 0, stream>>>(
        act1, w_mid + 0 * 2304, b_mid + 0, act2, stats + 0 * 512, stats + 1 * 512,
        512, 512, 256, 256);
    // mid 1: 256 -> 128, s2 p0
    conv_mfma_s2_kernel<<<16 * 8 * 8, 256, 0, stream>>>(
        act2, w_mid + 1 * 2304, b_mid + 16, act3, stats + 1 * 512, stats + 2 * 512,
        256, 256, 128, 128);
    // mid 2: 128 -> 64, s2 p0
    conv_mfma_s2_kernel<<<16 * 4 * 4, 256, 0, stream>>>(
        act3, w_mid + 2 * 2304, b_mid + 32, act4, stats + 2 * 512, stats + 3 * 512,
        128, 128, 64, 64);
    // mid 3: 64 -> 32, s2 p0
    conv_mfma_s2_kernel<<<16 * 2 * 2, 256, 0, stream>>>(
        act4, w_mid + 3 * 2304, b_mid + 48, act5, stats + 3 * 512, stats + 4 * 512,
        64, 64, 32, 32);
    // mid 4: 32 -> 32, s1 p1
    conv_mfma_kernel<1,1><<<16 * 2 * 2, 256, 0, stream>>>(
        act5, w_mid + 4 * 2304, b_mid + 64, act6, stats + 4 * 512, stats + 5 * 512,
        32, 32, 32, 32);
    // mid 5
    conv_mfma_kernel<1,1><<<16 * 2 * 2, 256, 0, stream>>>(
        act6, w_mid + 5 * 2304, b_mid + 80, act5, stats + 5 * 512, stats + 6 * 512,
        32, 32, 32, 32);
    // mid 6
    conv_mfma_kernel<1,1><<<16 * 2 * 2, 256, 0, stream>>>(
        act5, w_mid + 6 * 2304, b_mid + 96, act6, stats + 6 * 512, stats + 7 * 512,
        32, 32, 32, 32);

    // last conv + tanh + control points -> d_out[1..]
    float* cps_out = out + 1;
    conv_last_cps_kernel<<<(BB * 33 * 33 + 255) / 256, 256, 0, stream>>>(
        act6, w_last, b_last, stats + 7 * 512, cps_out);

    // losses
    area_loss_kernel<<<4096, 256, 0, stream>>>(image, cps_out, lacc);
    edge_loss_kernel<<<(BB * 1089 + 255) / 256, 256, 0, stream>>>(image, cps_out, lacc);
    finalize_kernel<<<1, 1, 0, stream>>>(lacc, out);
}

// Round 11
// 322.377 us; speedup vs baseline: 3.8018x; 1.0862x over previous
//
#include <hip/hip_runtime.h>
#include <hip/hip_fp16.h>
#include <math.h>

#define BB 16
#define HH 512
#define WW 512

typedef _Float16 half8 __attribute__((ext_vector_type(8)));
typedef float f32x4 __attribute__((ext_vector_type(4)));

// ---------- helpers ----------
__device__ __forceinline__ float gelu_tanh(float v){
    float u = 0.7978845608028654f * (v + 0.044715f * v * v * v);
    float e = __expf(2.f * u);
    return v - v * __builtin_amdgcn_rcpf(e + 1.f);
}
__device__ __forceinline__ float diff_round(float x){
    const float TWO_PI = 6.283185307179586f;
    const float INV_TWO_PI = 0.15915494309189535f;
    return x - __sinf(TWO_PI * x) * INV_TWO_PI;
}

// ---------------- Fused Farid + first conv via MFMA ----------------
// Block = 32x16 outputs. Stage img fp32 (22x38, halo3) -> edge pass -> combined
// half2{img,edge} tile 18x34 (halo1) -> 1 MFMA per 16-pixel tile (K=18 of 32).
// k-labeling: k = tap*2 + ch (ch: 0=img, 1=edge); lane k-group g covers taps 4g..4g+3.
__global__ __launch_bounds__(256) void farid_conv_first_kernel(
        const float* __restrict__ img, const float* __restrict__ w,
        const float* __restrict__ bias,
        __half* __restrict__ out, float* __restrict__ stats_out){
    __shared__ float simg[22 * 40];        // img tile, halo 3
    __shared__ __half2 stile[18 * 34];     // {img, edge} tile, halo 1
    __shared__ float sred[2][4][16];
    int t = threadIdx.x;
    int bid = blockIdx.x;
    int tx0 = (bid & 15) << 5;             // 16 x-tiles of 32
    int ty0 = ((bid >> 4) & 31) << 4;      // 32 y-tiles of 16
    int b   = bid >> 9;
    const float* ib = img + (size_t)b * HH * WW;

    // stage img [ty0-3, ty0+19) x [tx0-3, tx0+35), zero OOB
    for (int i = t; i < 22 * 38; i += 256){
        int r = i / 38, c = i - r * 38;
        int gy = ty0 - 3 + r, gx = tx0 - 3 + c;
        float v = 0.f;
        if (gy >= 0 && gy < HH && gx >= 0 && gx < WW) v = ib[gy * WW + gx];
        simg[r * 40 + c] = v;
    }
    __syncthreads();

    // edge pass -> combined tile [ty0-1, ty0+17) x [tx0-1, tx0+33)
    const float fp[5] = {0.03032f, 0.249724f, 0.439911f, 0.249724f, 0.03032f};
    const float fd[5] = {0.10455f, 0.292315f, 0.0f, -0.292315f, -0.10455f};
    for (int i = t; i < 18 * 34; i += 256){
        int r = i / 34, c = i - r * 34;
        int gy = ty0 - 1 + r, gx = tx0 - 1 + c;
        float e = 0.f;
        float iv = simg[(r + 2) * 40 + (c + 2)];
        if (gy >= 0 && gy < HH && gx >= 0 && gx < WW){
            float gxx = 0.f, gyy = 0.f;
            #pragma unroll
            for (int di = 0; di < 5; di++){
                #pragma unroll
                for (int dj = 0; dj < 5; dj++){
                    float v = simg[(r + di) * 40 + (c + dj)];
                    gxx += fp[di] * fd[dj] * v;
                    gyy += fd[di] * fp[dj] * v;
                }
            }
            e = sqrtf(gxx * gxx + gyy * gyy + 1e-8f);
        } else {
            iv = 0.f;   // outside image: both channels zero (reference zero-pad)
        }
        stile[i] = __floats2half2_rn(iv, e);
    }
    __syncthreads();

    // ---- MFMA conv: 32 tiles of (16 px x 16 outch), 8 per wave ----
    int lane = t & 63;
    int wv = t >> 6;
    int col = lane & 15;      // A: pixel; B/D: out-channel
    int g = lane >> 4;        // k-group: taps 4g..4g+3

    // B fragment + per-lane tap offsets (once)
    union { half8 v; _Float16 e[8]; } bf;
    #pragma unroll
    for (int j = 0; j < 8; j++){
        int k = 8 * g + j;
        int tap = k >> 1;
        bf.e[j] = (tap < 9) ? (_Float16)w[tap * 32 + (k & 1) * 16 + col] : (_Float16)0.f;
    }
    int dd[4]; int tv[4];
    #pragma unroll
    for (int jj = 0; jj < 4; jj++){
        int tap = 4 * g + jj;
        tv[jj] = (tap < 9);
        int tp = tv[jj] ? tap : 0;
        dd[jj] = (tp / 3) * 34 + (tp % 3);
    }
    float bia = bias[col];
    float ssum = 0.f, ssq = 0.f;

    #pragma unroll
    for (int i = 0; i < 8; i++){
        int tid = wv * 8 + i;
        int row = tid >> 1, xt = tid & 1;
        int base = row * 34 + xt * 16 + col;
        union { half8 v; unsigned u[4]; } af;
        #pragma unroll
        for (int jj = 0; jj < 4; jj++)
            af.u[jj] = tv[jj] ? *(const unsigned*)&stile[base + dd[jj]] : 0u;
        f32x4 acc = {bia, bia, bia, bia};
        acc = __builtin_amdgcn_mfma_f32_16x16x32_f16(af.v, bf.v, acc, 0, 0, 0);
        int y = ty0 + row;
        int xb = tx0 + xt * 16 + 4 * g;
        #pragma unroll
        for (int rg = 0; rg < 4; rg++){
            float v = acc[rg];
            out[(((size_t)b * HH + y) * WW + xb + rg) * 16 + col] = __float2half(v);
            ssum += v;
            ssq += v * v;
        }
    }

    // ---- stats epilogue ----
    ssum += __shfl_xor(ssum, 16); ssq += __shfl_xor(ssq, 16);
    ssum += __shfl_xor(ssum, 32); ssq += __shfl_xor(ssq, 32);
    if (lane < 16){ sred[0][wv][lane] = ssum; sred[1][wv][lane] = ssq; }
    __syncthreads();
    if (t < 32){
        int isq = t >> 4, c = t & 15;
        float a = sred[isq][0][c] + sred[isq][1][c] + sred[isq][2][c] + sred[isq][3][c];
        atomicAdd(&stats_out[isq * 256 + b * 16 + c], a);
    }
}

// ---------------- Stride-2 MFMA conv with LDS-staged normalized input ----------------
__global__ __launch_bounds__(256) void conv_mfma_s2_kernel(
        const __half* __restrict__ in, const float* __restrict__ w,
        const float* __restrict__ bias, __half* __restrict__ out,
        const float* __restrict__ stats_in, float* __restrict__ stats_out,
        int Hin, int Win, int Hout, int Wout){
    __shared__ uint4 stile[2244];          // 2*2*17*33 blocks of 16B = 35904 B
    __shared__ float snm[32];
    __shared__ float sred[2][4][16];
    int t = threadIdx.x;
    int nTx = Wout >> 4;
    int nTy = Hout >> 4;
    int bid = blockIdx.x;
    int tx = bid % nTx;
    int ty = (bid / nTx) % nTy;
    int b  = bid / (nTx * nTy);

    if (t < 16){
        float invN = 1.f / (float)(Hin * Win);
        float mm = stats_in[b * 16 + t] * invN;
        float vv = stats_in[256 + b * 16 + t] * invN - mm * mm;
        snm[t] = mm;
        snm[16 + t] = rsqrtf(vv + 1e-5f);
    }
    __syncthreads();

    int iy0 = ty << 5, ix0 = tx << 5;
    for (int i = t; i < 33 * 33; i += 256){
        int lr = i / 33, lc = i - lr * 33;
        int gy = iy0 + lr, gx = ix0 + lc;
        uint4 h0 = {0,0,0,0}, h1 = {0,0,0,0};
        if (gy < Hin && gx < Win){
            const uint4* ap = (const uint4*)(in + ((((size_t)b * Hin + gy) * Win + gx) << 4));
            uint4 u0 = ap[0], u1 = ap[1];
            unsigned* pu0 = reinterpret_cast<unsigned*>(&u0);
            unsigned* pr0 = reinterpret_cast<unsigned*>(&h0);
            unsigned* pu1 = reinterpret_cast<unsigned*>(&u1);
            unsigned* pr1 = reinterpret_cast<unsigned*>(&h1);
            #pragma unroll
            for (int q = 0; q < 4; q++){
                __half2 hh = *reinterpret_cast<__half2*>(&pu0[q]);
                float2 f = __half22float2(hh);
                float a0 = gelu_tanh((f.x - snm[2*q])   * snm[16 + 2*q]);
                float a1 = gelu_tanh((f.y - snm[2*q+1]) * snm[16 + 2*q+1]);
                __half2 o = __floats2half2_rn(a0, a1);
                pr0[q] = *reinterpret_cast<unsigned*>(&o);
            }
            #pragma unroll
            for (int q = 0; q < 4; q++){
                __half2 hh = *reinterpret_cast<__half2*>(&pu1[q]);
                float2 f = __half22float2(hh);
                float a0 = gelu_tanh((f.x - snm[8 + 2*q])   * snm[24 + 2*q]);
                float a1 = gelu_tanh((f.y - snm[8 + 2*q+1]) * snm[24 + 2*q+1]);
                __half2 o = __floats2half2_rn(a0, a1);
                pr1[q] = *reinterpret_cast<unsigned*>(&o);
            }
        }
        int parity = lc & 1, me = lc >> 1;
        stile[((parity * 2 + 0) * 17 + me) * 33 + lr] = h0;
        stile[((parity * 2 + 1) * 17 + me) * 33 + lr] = h1;
    }
    __syncthreads();

    int lane = t & 63;
    int wv = t >> 6;
    int col = lane & 15;
    int g = lane >> 4;
    int h = g & 1;
    int ci0 = h * 8;
    int tsel = g >> 1;

    half8 bfrag[5];
    #pragma unroll
    for (int p = 0; p < 5; p++){
        int tp = 2 * p + tsel;
        #pragma unroll
        for (int j = 0; j < 8; j++)
            bfrag[p][j] = (tp < 9) ? (_Float16)w[(tp * 16 + ci0 + j) * 16 + col]
                                   : (_Float16)0.f;
    }
    float bia = bias[col];
    float ssum = 0.f, ssq = 0.f;

    #pragma unroll
    for (int s = 0; s < 4; s++){
        int rl = wv * 4 + s;
        f32x4 acc = {bia, bia, bia, bia};
        #pragma unroll
        for (int p = 0; p < 5; p++){
            int tp = 2 * p + tsel;
            half8 afrag;
            #pragma unroll
            for (int j = 0; j < 8; j++) afrag[j] = (_Float16)0.f;
            if (tp < 9){
                int ky = tp / 3, kx = tp - ky * 3;
                int lr = 2 * rl + ky;
                int lc = 2 * col + kx;
                int parity = lc & 1, me = lc >> 1;
                afrag = *(const half8*)&stile[((parity * 2 + h) * 17 + me) * 33 + lr];
            }
            acc = __builtin_amdgcn_mfma_f32_16x16x32_f16(afrag, bfrag[p], acc, 0, 0, 0);
        }
        int r = (ty << 4) + rl;
        #pragma unroll
        for (int rg = 0; rg < 4; rg++){
            int px = (tx << 4) + 4 * g + rg;
            float v = acc[rg];
            out[(((size_t)b * Hout + r) * Wout + px) * 16 + col] = __float2half(v);
            ssum += v;
            ssq += v * v;
        }
    }

    ssum += __shfl_xor(ssum, 16); ssq += __shfl_xor(ssq, 16);
    ssum += __shfl_xor(ssum, 32); ssq += __shfl_xor(ssq, 32);
    if (lane < 16){ sred[0][wv][lane] = ssum; sred[1][wv][lane] = ssq; }
    __syncthreads();
    if (t < 32){
        int isq = t >> 4, c = t & 15;
        float a = sred[isq][0][c] + sred[isq][1][c] + sred[isq][2][c] + sred[isq][3][c];
        atomicAdd(&stats_out[isq * 256 + b * 16 + c], a);
    }
}

// ---------------- Stride-1 MFMA conv (small 32x32 layers), unstaged ----------------
template<int STRIDE, int PAD>
__global__ __launch_bounds__(256) void conv_mfma_kernel(
        const __half* __restrict__ in, const float* __restrict__ w,
        const float* __restrict__ bias, __half* __restrict__ out,
        const float* __restrict__ stats_in, float* __restrict__ stats_out,
        int Hin, int Win, int Hout, int Wout){
    __shared__ float sred[2][4][16];
    int t = threadIdx.x;
    int lane = t & 63;
    int wv = t >> 6;
    int col = lane & 15;
    int g = lane >> 4;
    int ci0 = (g & 1) * 8;
    int tsel = g >> 1;

    int nTx = Wout >> 4;
    int nTy = Hout >> 4;
    int bid = blockIdx.x;
    int tx = bid % nTx;
    int ty = (bid / nTx) % nTy;
    int b  = bid / (nTx * nTy);

    float mean[8], rstd[8];
    float invN = 1.f / (float)(Hin * Win);
    #pragma unroll
    for (int j = 0; j < 8; j++){
        int c = ci0 + j;
        float mm = stats_in[b * 16 + c] * invN;
        float vv = stats_in[256 + b * 16 + c] * invN - mm * mm;
        mean[j] = mm;
        rstd[j] = rsqrtf(vv + 1e-5f);
    }

    half8 bfrag[5];
    #pragma unroll
    for (int p = 0; p < 5; p++){
        int tp = 2 * p + tsel;
        #pragma unroll
        for (int j = 0; j < 8; j++)
            bfrag[p][j] = (tp < 9) ? (_Float16)w[(tp * 16 + ci0 + j) * 16 + col]
                                   : (_Float16)0.f;
    }
    float bia = bias[col];

    int xg = tx * 16 + col;
    float ssum = 0.f, ssq = 0.f;

    #pragma unroll
    for (int s = 0; s < 4; s++){
        int r = ty * 16 + wv * 4 + s;
        f32x4 acc = {bia, bia, bia, bia};
        #pragma unroll
        for (int p = 0; p < 5; p++){
            int tp = 2 * p + tsel;
            int ky = tp / 3, kx = tp - ky * 3;
            int iy = r * STRIDE + ky - PAD;
            int ix = xg * STRIDE + kx - PAD;
            bool valid = (tp < 9) && (iy >= 0) && (iy < Hin) && (ix >= 0) && (ix < Win);
            half8 afrag;
            #pragma unroll
            for (int j = 0; j < 8; j++) afrag[j] = (_Float16)0.f;
            if (valid){
                const __half* ap = in + ((((size_t)b * Hin + iy) * Win + ix) << 4) + ci0;
                uint4 u = *(const uint4*)ap;
                unsigned* pu = reinterpret_cast<unsigned*>(&u);
                #pragma unroll
                for (int q = 0; q < 4; q++){
                    __half2 hh = *reinterpret_cast<__half2*>(&pu[q]);
                    float2 f = __half22float2(hh);
                    float a0 = gelu_tanh((f.x - mean[2*q])   * rstd[2*q]);
                    float a1 = gelu_tanh((f.y - mean[2*q+1]) * rstd[2*q+1]);
                    afrag[2*q]   = (_Float16)a0;
                    afrag[2*q+1] = (_Float16)a1;
                }
            }
            acc = __builtin_amdgcn_mfma_f32_16x16x32_f16(afrag, bfrag[p], acc, 0, 0, 0);
        }
        #pragma unroll
        for (int rg = 0; rg < 4; rg++){
            int px = tx * 16 + 4 * g + rg;
            float v = acc[rg];
            out[(((size_t)b * Hout + r) * Wout + px) * 16 + col] = __float2half(v);
            ssum += v;
            ssq += v * v;
        }
    }

    ssum += __shfl_xor(ssum, 16); ssq += __shfl_xor(ssq, 16);
    ssum += __shfl_xor(ssum, 32); ssq += __shfl_xor(ssq, 32);
    if (lane < 16){ sred[0][wv][lane] = ssum; sred[1][wv][lane] = ssq; }
    __syncthreads();
    if (t < 32){
        int isq = t >> 4, c = t & 15;
        float a = sred[isq][0][c] + sred[isq][1][c] + sred[isq][2][c] + sred[isq][3][c];
        atomicAdd(&stats_out[isq * 256 + b * 16 + c], a);
    }
}

// ---------------- Last conv (16->2), norm+gelu on load, tanh, control points ----------------
__global__ void conv_last_cps_kernel(const __half* __restrict__ act, const float* __restrict__ w,
                                     const float* __restrict__ bias,
                                     const float* __restrict__ stats,
                                     float* __restrict__ cps){
    int idx = blockIdx.x * blockDim.x + threadIdx.x;
    if (idx >= BB * 33 * 33) return;
    int j = idx % 33;
    int i = (idx / 33) % 33;
    int b = idx / (33 * 33);
    float cy = (float)(i * 16);
    float cx = (float)(j * 16);
    if (i < 32 && j < 32){
        float mean[16], rstd[16];
        const float invN = 1.f / 1024.f;
        #pragma unroll
        for (int c = 0; c < 16; c++){
            float mm = stats[b * 16 + c] * invN;
            float vv = stats[256 + b * 16 + c] * invN - mm * mm;
            mean[c] = mm;
            rstd[c] = rsqrtf(vv + 1e-5f);
        }
        float a0 = bias[0], a1 = bias[1];
        for (int ky = 0; ky < 3; ky++){
            int iy = i + ky - 1;
            if (iy < 0 || iy >= 32) continue;
            for (int kx = 0; kx < 3; kx++){
                int ix = j + kx - 1;
                if (ix < 0 || ix >= 32) continue;
                const __half* ip = act + (((size_t)b * 32 + iy) * 32 + ix) * 16;
                const float* wp = w + (ky * 3 + kx) * 32;  // (kh,kw,16,2)
                #pragma unroll
                for (int ci = 0; ci < 16; ci++){
                    float v = gelu_tanh((__half2float(ip[ci]) - mean[ci]) * rstd[ci]);
                    a0 += v * wp[ci * 2];
                    a1 += v * wp[ci * 2 + 1];
                }
            }
        }
        cy += tanhf(a0) * 8.f;
        cx += tanhf(a1) * 8.f;
    }
    cps[idx * 2] = cy;
    cps[idx * 2 + 1] = cx;
}

// ---------------- Area loss: 16-lane group per area, single-pass variance ----------------
__global__ __launch_bounds__(256) void area_loss_kernel(
        const float* __restrict__ img, const float* __restrict__ cps,
        float* __restrict__ acc){
    __shared__ float sv[16];
    int t = threadIdx.x;
    int lane = t & 63;
    int wv = t >> 6;
    int g = lane >> 4;
    int l2 = lane & 15;
    int aidx = blockIdx.x * 16 + wv * 4 + g;   // 0 .. 65535
    int b = aidx >> 12;
    int rem = aidx & 4095;
    int o = rem >> 10;
    int ar = rem & 1023;
    int by = ar >> 5;
    int bx = ar & 31;
    int sy = (o & 2) ? 8 : 0;
    int sx = (o & 1) ? 8 : 0;
    float cpy = cps[((b * 33 + by) * 33 + bx) * 2 + 0];
    float cpx = cps[((b * 33 + by) * 33 + bx) * 2 + 1];
    int y0 = sy - 8 + by * 16;
    int x0 = sx - 8 + bx * 16;
    int x = x0 + l2;
    bool xok = (x >= 0 && x < WW);
    float dx = (float)x - cpx;
    float dx2 = dx * dx;
    float A = 0.f, Bs = 0.f, C = 0.f, D = 0.f, E = 0.f;
    #pragma unroll
    for (int k = 0; k < 16; k++){
        int y = y0 + k;
        float r = 0.f;
        if (xok && y >= 0 && y < HH)
            r = img[((size_t)b * HH + y) * WW + x];
        float dy = (float)y - cpy;
        float m = __expf(-(dy * dy + dx2) * (1.f / 128.f));
        m = diff_round(diff_round(m));
        float rm = r * m;
        float m2 = m * m;
        A += m; Bs += rm; E += m2;
        D += rm * m2;
        C += rm * rm * m2;
    }
    #pragma unroll
    for (int off = 8; off >= 1; off >>= 1){
        A  += __shfl_xor(A, off);
        Bs += __shfl_xor(Bs, off);
        C  += __shfl_xor(C, off);
        D  += __shfl_xor(D, off);
        E  += __shfl_xor(E, off);
    }
    if (l2 == 0){
        float rden = __builtin_amdgcn_rcpf(A + 1e-7f);
        float mean = (Bs + 256.f * 1e-7f) * rden;
        float sdev = C - 2.f * mean * D + mean * mean * E;
        float varr = (sdev + 256.f * 1e-7f) * rden;
        sv[wv * 4 + g] = varr;
    }
    __syncthreads();
    if (t == 0){
        float s = 0.f;
        #pragma unroll
        for (int i2 = 0; i2 < 16; i2++) s += sv[i2];
        atomicAdd(&acc[blockIdx.x & 63], s);
    }
}

// ---------------- Edge sampling loss (recomputes farid inline; no edge buffer) ----------------
__device__ __forceinline__ float farid_at(const float* __restrict__ ib, int y, int x){
    const float fp[5] = {0.03032f, 0.249724f, 0.439911f, 0.249724f, 0.03032f};
    const float fd[5] = {0.10455f, 0.292315f, 0.0f, -0.292315f, -0.10455f};
    float gxx = 0.f, gyy = 0.f;
    #pragma unroll
    for (int i = 0; i < 5; i++){
        int yy = y + i - 2;
        if (yy < 0 || yy >= HH) continue;
        #pragma unroll
        for (int j = 0; j < 5; j++){
            int xx = x + j - 2;
            if (xx < 0 || xx >= WW) continue;
            float v = ib[yy * WW + xx];
            gxx += fp[i] * fd[j] * v;
            gyy += fd[i] * fp[j] * v;
        }
    }
    return sqrtf(gxx * gxx + gyy * gyy + 1e-8f);
}

__global__ void edge_loss_kernel(const float* __restrict__ img, const float* __restrict__ cps,
                                 float* __restrict__ acc){
    __shared__ float s1[256];
    int idx = blockIdx.x * blockDim.x + threadIdx.x;
    float v = 0.f;
    if (idx < BB * 1089){
        int b = idx / 1089;
        int p = idx % 1089;
        float y = cps[((size_t)b * 1089 + p) * 2 + 0];
        float x = cps[((size_t)b * 1089 + p) * 2 + 1];
        y = fminf(fmaxf(y, 0.f), 510.999f);
        x = fminf(fmaxf(x, 0.f), 510.999f);
        int y0 = (int)floorf(y);
        int x0 = (int)floorf(x);
        float wy = y - (float)y0;
        float wx = x - (float)x0;
        const float* ib = img + (size_t)b * HH * WW;
        float v00 = farid_at(ib, y0, x0);
        float v01 = farid_at(ib, y0, x0 + 1);
        float v10 = farid_at(ib, y0 + 1, x0);
        float v11 = farid_at(ib, y0 + 1, x0 + 1);
        v = v00 * (1 - wy) * (1 - wx) + v01 * (1 - wy) * wx + v10 * wy * (1 - wx) + v11 * wy * wx;
    }
    int t = threadIdx.x;
    s1[t] = v;
    __syncthreads();
    for (int off = 128; off > 0; off >>= 1){
        if (t < off) s1[t] += s1[t + off];
        __syncthreads();
    }
    if (t == 0) atomicAdd(&acc[64 + (blockIdx.x & 3)], s1[0]);
}

__global__ void finalize_kernel(const float* __restrict__ lacc, float* __restrict__ out){
    float a = 0.f, e = 0.f;
    for (int i = 0; i < 64; i++) a += lacc[i];
    for (int i = 0; i < 4; i++) e += lacc[64 + i];
    out[0] = (a / 65536.f) * (e / 17424.f);
}

extern "C" void kernel_launch(void* const* d_in, const int* in_sizes, int n_in,
                              void* d_out, int out_size, void* d_ws, size_t ws_size,
                              hipStream_t stream) {
    const float* image  = (const float*)d_in[0];
    const float* w_first= (const float*)d_in[1];
    const float* b_first= (const float*)d_in[2];
    const float* w_mid  = (const float*)d_in[3];
    const float* b_mid  = (const float*)d_in[4];
    const float* w_last = (const float*)d_in[5];
    const float* b_last = (const float*)d_in[6];
    float* out = (float*)d_out;
    char* ws = (char*)d_ws;

    // ---- workspace layout (all activations fp16, stored pre-norm; no edge buffer) ----
    float* stats = (float*)ws;                 // 8 layers * 512 floats
    float* lacc  = stats + 8 * 512;            // 128 floats
    size_t off = (8 * 512 + 128) * sizeof(float);
    __half* act1 = (__half*)(ws + off); off += (size_t)BB * 512 * 512 * 16 * 2;
    __half* act2 = (__half*)(ws + off); off += (size_t)BB * 256 * 256 * 16 * 2;
    __half* act3 = (__half*)(ws + off); off += (size_t)BB * 128 * 128 * 16 * 2;
    __half* act4 = (__half*)(ws + off); off += (size_t)BB * 64 * 64 * 16 * 2;
    __half* act5 = (__half*)(ws + off); off += (size_t)BB * 32 * 32 * 16 * 2;
    __half* act6 = (__half*)(ws + off); off += (size_t)BB * 32 * 32 * 16 * 2;

    hipMemsetAsync(ws, 0, (8 * 512 + 128) * sizeof(float), stream);

    // fused farid + conv_first (MFMA) + stats0
    farid_conv_first_kernel<<<16 * 32 * 16, 256, 0, stream>>>(
        image, w_first, b_first, act1, stats + 0 * 512);

    // mid 0: 512 -> 256, s2 p0 (LDS-staged)
    conv_mfma_s2_kernel<<<16 * 16 * 16, 256, 0, stream>>>(
        act1, w_mid + 0 * 2304, b_mid + 0, act2, stats + 0 * 512, stats + 1 * 512,
        512, 512, 256, 256);
    // mid 1: 256 -> 128, s2 p0
    conv_mfma_s2_kernel<<<16 * 8 * 8, 256, 0, stream>>>(
        act2, w_mid + 1 * 2304, b_mid + 16, act3, stats + 1 * 512, stats + 2 * 512,
        256, 256, 128, 128);
    // mid 2: 128 -> 64, s2 p0
    conv_mfma_s2_kernel<<<16 * 4 * 4, 256, 0, stream>>>(
        act3, w_mid + 2 * 2304, b_mid + 32, act4, stats + 2 * 512, stats + 3 * 512,
        128, 128, 64, 64);
    // mid 3: 64 -> 32, s2 p0
    conv_mfma_s2_kernel<<<16 * 2 * 2, 256, 0, stream>>>(
        act4, w_mid + 3 * 2304, b_mid + 48, act5, stats + 3 * 512, stats + 4 * 512,
        64, 64, 32, 32);
    // mid 4: 32 -> 32, s1 p1
    conv_mfma_kernel<1,1><<<16 * 2 * 2, 256, 0, stream>>>(
        act5, w_mid + 4 * 2304, b_mid + 64, act6, stats + 4 * 512, stats + 5 * 512,
        32, 32, 32, 32);
    // mid 5
    conv_mfma_kernel<1,1><<<16 * 2 * 2, 256, 0, stream>>>(
        act6, w_mid + 5 * 2304, b_mid + 80, act5, stats + 5 * 512, stats + 6 * 512,
        32, 32, 32, 32);
    // mid 6
    conv_mfma_kernel<1,1><<<16 * 2 * 2, 256, 0, stream>>>(
        act5, w_mid + 6 * 2304, b_mid + 96, act6, stats + 6 * 512, stats + 7 * 512,
        32, 32, 32, 32);

    // last conv + tanh + control points -> d_out[1..]
    float* cps_out = out + 1;
    conv_last_cps_kernel<<<(BB * 33 * 33 + 255) / 256, 256, 0, stream>>>(
        act6, w_last, b_last, stats + 7 * 512, cps_out);

    // losses
    area_loss_kernel<<<4096, 256, 0, stream>>>(image, cps_out, lacc);
    edge_loss_kernel<<<(BB * 1089 + 255) / 256, 256, 0, stream>>>(image, cps_out, lacc);
    finalize_kernel<<<1, 1, 0, stream>>>(lacc, out);
}

// Round 13
// 296.120 us; speedup vs baseline: 4.1389x; 1.0887x over previous
//
#include <hip/hip_runtime.h>
#include <hip/hip_fp16.h>
#include <math.h>

#define BB 16
#define HH 512
#define WW 512

typedef _Float16 half8 __attribute__((ext_vector_type(8)));
typedef float f32x4 __attribute__((ext_vector_type(4)));

// ---------- helpers ----------
__device__ __forceinline__ float gelu_tanh(float v){
    float u = 0.7978845608028654f * (v + 0.044715f * v * v * v);
    float e = __expf(2.f * u);
    return v - v * __builtin_amdgcn_rcpf(e + 1.f);
}
__device__ __forceinline__ float diff_round(float x){
    const float TWO_PI = 6.283185307179586f;
    const float INV_TWO_PI = 0.15915494309189535f;
    return x - __sinf(TWO_PI * x) * INV_TWO_PI;
}

// ---------------- Fused Farid (separable) + first conv via MFMA ----------------
// Block = 32x16 outputs. simg fp32 22x38 (halo3) -> separable H passes ->
// combined half2{img,edge} tile 18x34 (halo1) -> 1 MFMA per 16-pixel tile (K=18).
__global__ __launch_bounds__(256) void farid_conv_first_kernel(
        const float* __restrict__ img, const float* __restrict__ w,
        const float* __restrict__ bias,
        __half* __restrict__ out, float* __restrict__ stats_out){
    __shared__ float simg[22 * 40];        // img tile, halo 3
    __shared__ float sHd[22 * 34];         // horizontal d-filtered
    __shared__ float sHp[22 * 34];         // horizontal p-filtered
    __shared__ __half2 stile[18 * 34];     // {img, edge} tile, halo 1
    __shared__ float sred[2][4][16];
    int t = threadIdx.x;
    int bid = blockIdx.x;
    int tx0 = (bid & 15) << 5;             // 16 x-tiles of 32
    int ty0 = ((bid >> 4) & 31) << 4;      // 32 y-tiles of 16
    int b   = bid >> 9;
    const float* ib = img + (size_t)b * HH * WW;

    // stage img [ty0-3, ty0+19) x [tx0-3, tx0+35), zero OOB
    for (int i = t; i < 22 * 38; i += 256){
        int r = i / 38, c = i - r * 38;
        int gy = ty0 - 3 + r, gx = tx0 - 3 + c;
        float v = 0.f;
        if (gy >= 0 && gy < HH && gx >= 0 && gx < WW) v = ib[gy * WW + gx];
        simg[r * 40 + c] = v;
    }
    __syncthreads();

    const float fp[5] = {0.03032f, 0.249724f, 0.439911f, 0.249724f, 0.03032f};
    const float fd[5] = {0.10455f, 0.292315f, 0.0f, -0.292315f, -0.10455f};

    // horizontal passes: H[r][c] over simg cols c..c+4  (22 x 34)
    for (int i = t; i < 22 * 34; i += 256){
        int r = i / 34, c = i - r * 34;
        const float* sp = simg + r * 40 + c;
        float hd = 0.f, hp = 0.f;
        #pragma unroll
        for (int j = 0; j < 5; j++){
            float v = sp[j];
            hd += fd[j] * v;
            hp += fp[j] * v;
        }
        sHd[i] = hd;
        sHp[i] = hp;
    }
    __syncthreads();

    // vertical passes + magnitude -> combined tile [18 x 34]
    for (int i = t; i < 18 * 34; i += 256){
        int r = i / 34, c = i - r * 34;
        int gy = ty0 - 1 + r, gx = tx0 - 1 + c;
        float e = 0.f;
        float iv = simg[(r + 2) * 40 + (c + 2)];
        if (gy >= 0 && gy < HH && gx >= 0 && gx < WW){
            float gxx = 0.f, gyy = 0.f;
            #pragma unroll
            for (int k = 0; k < 5; k++){
                gxx += fp[k] * sHd[(r + k) * 34 + c];   // kx = outer(p,d)
                gyy += fd[k] * sHp[(r + k) * 34 + c];   // ky = outer(d,p)
            }
            e = sqrtf(gxx * gxx + gyy * gyy + 1e-8f);
        } else {
            iv = 0.f;
        }
        stile[i] = __floats2half2_rn(iv, e);
    }
    __syncthreads();

    // ---- MFMA conv: 32 tiles of (16 px x 16 outch), 8 per wave ----
    int lane = t & 63;
    int wv = t >> 6;
    int col = lane & 15;
    int g = lane >> 4;

    union { half8 v; _Float16 e[8]; } bf;
    #pragma unroll
    for (int j = 0; j < 8; j++){
        int k = 8 * g + j;
        int tap = k >> 1;
        bf.e[j] = (tap < 9) ? (_Float16)w[tap * 32 + (k & 1) * 16 + col] : (_Float16)0.f;
    }
    int dd[4]; int tv[4];
    #pragma unroll
    for (int jj = 0; jj < 4; jj++){
        int tap = 4 * g + jj;
        tv[jj] = (tap < 9);
        int tp = tv[jj] ? tap : 0;
        dd[jj] = (tp / 3) * 34 + (tp % 3);
    }
    float bia = bias[col];
    float ssum = 0.f, ssq = 0.f;

    #pragma unroll
    for (int i = 0; i < 8; i++){
        int tid = wv * 8 + i;
        int row = tid >> 1, xt = tid & 1;
        int base = row * 34 + xt * 16 + col;
        union { half8 v; unsigned u[4]; } af;
        #pragma unroll
        for (int jj = 0; jj < 4; jj++)
            af.u[jj] = tv[jj] ? *(const unsigned*)&stile[base + dd[jj]] : 0u;
        f32x4 acc = {bia, bia, bia, bia};
        acc = __builtin_amdgcn_mfma_f32_16x16x32_f16(af.v, bf.v, acc, 0, 0, 0);
        int y = ty0 + row;
        int xb = tx0 + xt * 16 + 4 * g;
        #pragma unroll
        for (int rg = 0; rg < 4; rg++){
            float v = acc[rg];
            out[(((size_t)b * HH + y) * WW + xb + rg) * 16 + col] = __float2half(v);
            ssum += v;
            ssq += v * v;
        }
    }

    ssum += __shfl_xor(ssum, 16); ssq += __shfl_xor(ssq, 16);
    ssum += __shfl_xor(ssum, 32); ssq += __shfl_xor(ssq, 32);
    if (lane < 16){ sred[0][wv][lane] = ssum; sred[1][wv][lane] = ssq; }
    __syncthreads();
    if (t < 32){
        int isq = t >> 4, c = t & 15;
        float a = sred[isq][0][c] + sred[isq][1][c] + sred[isq][2][c] + sred[isq][3][c];
        atomicAdd(&stats_out[isq * 256 + b * 16 + c], a);
    }
}

// ---------------- Stride-2 MFMA conv with LDS-staged normalized input ----------------
__global__ __launch_bounds__(256) void conv_mfma_s2_kernel(
        const __half* __restrict__ in, const float* __restrict__ w,
        const float* __restrict__ bias, __half* __restrict__ out,
        const float* __restrict__ stats_in, float* __restrict__ stats_out,
        int Hin, int Win, int Hout, int Wout){
    __shared__ uint4 stile[2244];          // 2*2*17*33 blocks of 16B = 35904 B
    __shared__ float snm[32];
    __shared__ float sred[2][4][16];
    int t = threadIdx.x;
    int nTx = Wout >> 4;
    int nTy = Hout >> 4;
    int bid = blockIdx.x;
    int tx = bid % nTx;
    int ty = (bid / nTx) % nTy;
    int b  = bid / (nTx * nTy);

    if (t < 16){
        float invN = 1.f / (float)(Hin * Win);
        float mm = stats_in[b * 16 + t] * invN;
        float vv = stats_in[256 + b * 16 + t] * invN - mm * mm;
        snm[t] = mm;
        snm[16 + t] = rsqrtf(vv + 1e-5f);
    }
    __syncthreads();

    int iy0 = ty << 5, ix0 = tx << 5;
    for (int i = t; i < 33 * 33; i += 256){
        int lr = i / 33, lc = i - lr * 33;
        int gy = iy0 + lr, gx = ix0 + lc;
        uint4 h0 = {0,0,0,0}, h1 = {0,0,0,0};
        if (gy < Hin && gx < Win){
            const uint4* ap = (const uint4*)(in + ((((size_t)b * Hin + gy) * Win + gx) << 4));
            uint4 u0 = ap[0], u1 = ap[1];
            unsigned* pu0 = reinterpret_cast<unsigned*>(&u0);
            unsigned* pr0 = reinterpret_cast<unsigned*>(&h0);
            unsigned* pu1 = reinterpret_cast<unsigned*>(&u1);
            unsigned* pr1 = reinterpret_cast<unsigned*>(&h1);
            #pragma unroll
            for (int q = 0; q < 4; q++){
                __half2 hh = *reinterpret_cast<__half2*>(&pu0[q]);
                float2 f = __half22float2(hh);
                float a0 = gelu_tanh((f.x - snm[2*q])   * snm[16 + 2*q]);
                float a1 = gelu_tanh((f.y - snm[2*q+1]) * snm[16 + 2*q+1]);
                __half2 o = __floats2half2_rn(a0, a1);
                pr0[q] = *reinterpret_cast<unsigned*>(&o);
            }
            #pragma unroll
            for (int q = 0; q < 4; q++){
                __half2 hh = *reinterpret_cast<__half2*>(&pu1[q]);
                float2 f = __half22float2(hh);
                float a0 = gelu_tanh((f.x - snm[8 + 2*q])   * snm[24 + 2*q]);
                float a1 = gelu_tanh((f.y - snm[8 + 2*q+1]) * snm[24 + 2*q+1]);
                __half2 o = __floats2half2_rn(a0, a1);
                pr1[q] = *reinterpret_cast<unsigned*>(&o);
            }
        }
        int parity = lc & 1, me = lc >> 1;
        stile[((parity * 2 + 0) * 17 + me) * 33 + lr] = h0;
        stile[((parity * 2 + 1) * 17 + me) * 33 + lr] = h1;
    }
    __syncthreads();

    int lane = t & 63;
    int wv = t >> 6;
    int col = lane & 15;
    int g = lane >> 4;
    int h = g & 1;
    int ci0 = h * 8;
    int tsel = g >> 1;

    half8 bfrag[5];
    #pragma unroll
    for (int p = 0; p < 5; p++){
        int tp = 2 * p + tsel;
        #pragma unroll
        for (int j = 0; j < 8; j++)
            bfrag[p][j] = (tp < 9) ? (_Float16)w[(tp * 16 + ci0 + j) * 16 + col]
                                   : (_Float16)0.f;
    }
    float bia = bias[col];
    float ssum = 0.f, ssq = 0.f;

    #pragma unroll
    for (int s = 0; s < 4; s++){
        int rl = wv * 4 + s;
        f32x4 acc = {bia, bia, bia, bia};
        #pragma unroll
        for (int p = 0; p < 5; p++){
            int tp = 2 * p + tsel;
            half8 afrag;
            #pragma unroll
            for (int j = 0; j < 8; j++) afrag[j] = (_Float16)0.f;
            if (tp < 9){
                int ky = tp / 3, kx = tp - ky * 3;
                int lr = 2 * rl + ky;
                int lc = 2 * col + kx;
                int parity = lc & 1, me = lc >> 1;
                afrag = *(const half8*)&stile[((parity * 2 + h) * 17 + me) * 33 + lr];
            }
            acc = __builtin_amdgcn_mfma_f32_16x16x32_f16(afrag, bfrag[p], acc, 0, 0, 0);
        }
        int r = (ty << 4) + rl;
        #pragma unroll
        for (int rg = 0; rg < 4; rg++){
            int px = (tx << 4) + 4 * g + rg;
            float v = acc[rg];
            out[(((size_t)b * Hout + r) * Wout + px) * 16 + col] = __float2half(v);
            ssum += v;
            ssq += v * v;
        }
    }

    ssum += __shfl_xor(ssum, 16); ssq += __shfl_xor(ssq, 16);
    ssum += __shfl_xor(ssum, 32); ssq += __shfl_xor(ssq, 32);
    if (lane < 16){ sred[0][wv][lane] = ssum; sred[1][wv][lane] = ssq; }
    __syncthreads();
    if (t < 32){
        int isq = t >> 4, c = t & 15;
        float a = sred[isq][0][c] + sred[isq][1][c] + sred[isq][2][c] + sred[isq][3][c];
        atomicAdd(&stats_out[isq * 256 + b * 16 + c], a);
    }
}

// ---------------- Tail kernel: mid4+mid5+mid6+conv_last+cps, one block per batch ----------------
// 16 blocks x 1024 threads. Whole 32x32x16 image in LDS; stats exact per block.
__global__ __launch_bounds__(1024) void tail_kernel(
        const __half* __restrict__ act_in,       // mid3 output (raw), 16x32x32x16
        const float* __restrict__ stats_in,      // stats4 (for act_in)
        const float* __restrict__ w_mid, const float* __restrict__ b_mid,
        const float* __restrict__ w_last, const float* __restrict__ b_last,
        float* __restrict__ cps){
    __shared__ __half bufA[32 * 32 * 16];   // raw layer outputs
    __shared__ __half bufB[32 * 32 * 16];   // gelu'd inputs
    __shared__ _Float16 wl[2304];
    __shared__ float swl[288];
    __shared__ float sb[16];
    __shared__ float sbl[2];
    __shared__ float snm[32];
    __shared__ float sred2[2][16][16];
    int t = threadIdx.x;
    int b = blockIdx.x;
    int lane = t & 63;
    int wv = t >> 6;

    // load act_in -> bufA (raw)
    {
        const uint4* src = (const uint4*)(act_in + (size_t)b * 16384);
        uint4* dst = (uint4*)bufA;
        #pragma unroll
        for (int i = 0; i < 2; i++) dst[t + 1024 * i] = src[t + 1024 * i];
    }
    // snm from global stats4
    if (t < 16){
        float mm = stats_in[b * 16 + t] * (1.f / 1024.f);
        float vv = stats_in[256 + b * 16 + t] * (1.f / 1024.f) - mm * mm;
        snm[t] = mm;
        snm[16 + t] = rsqrtf(vv + 1e-5f);
    }

    for (int L = 0; L < 3; L++){
        // stage weights for this layer
        const float* wsrc = w_mid + (4 + L) * 2304;
        __syncthreads();
        for (int i = t; i < 2304; i += 1024) wl[i] = (_Float16)wsrc[i];
        if (t < 16) sb[t] = b_mid[(4 + L) * 16 + t];
        __syncthreads();

        // gelu pass: bufB = gelu(norm(bufA))
        #pragma unroll
        for (int i2 = 0; i2 < 2; i2++){
            int i = t + 1024 * i2;
            uint4 u = ((uint4*)bufA)[i];
            int ch0 = (i & 1) * 8;
            unsigned* pu = reinterpret_cast<unsigned*>(&u);
            #pragma unroll
            for (int q = 0; q < 4; q++){
                __half2 hh = *reinterpret_cast<__half2*>(&pu[q]);
                float2 f = __half22float2(hh);
                float a0 = gelu_tanh((f.x - snm[ch0 + 2*q])   * snm[16 + ch0 + 2*q]);
                float a1 = gelu_tanh((f.y - snm[ch0 + 2*q+1]) * snm[16 + ch0 + 2*q+1]);
                __half2 o = __floats2half2_rn(a0, a1);
                pu[q] = *reinterpret_cast<unsigned*>(&o);
            }
            ((uint4*)bufB)[i] = u;
        }
        __syncthreads();

        // conv s1 p1 via MFMA: 64 tiles, wave wv does tiles 4wv..4wv+3
        int col = lane & 15;
        int g = lane >> 4;
        int ci0 = (g & 1) * 8;
        int tsel = g >> 1;
        half8 bfrag[5];
        #pragma unroll
        for (int p = 0; p < 5; p++){
            int tp = 2 * p + tsel;
            #pragma unroll
            for (int j = 0; j < 8; j++)
                bfrag[p][j] = (tp < 9) ? wl[(tp * 16 + ci0 + j) * 16 + col] : (_Float16)0.f;
        }
        float bia = sb[col];
        float ssum = 0.f, ssq = 0.f;
        f32x4 accs[4];
        #pragma unroll
        for (int s = 0; s < 4; s++){
            int tid = wv * 4 + s;
            int y = tid >> 1, x0 = (tid & 1) * 16;
            f32x4 acc = {bia, bia, bia, bia};
            #pragma unroll
            for (int p = 0; p < 5; p++){
                int tp = 2 * p + tsel;
                int ky = tp / 3, kx = tp - ky * 3;
                int iy = y + ky - 1;
                int ix = x0 + col + kx - 1;
                bool valid = (tp < 9) && (iy >= 0) && (iy < 32) && (ix >= 0) && (ix < 32);
                half8 afrag;
                #pragma unroll
                for (int j = 0; j < 8; j++) afrag[j] = (_Float16)0.f;
                if (valid)
                    afrag = *(const half8*)&bufB[(iy * 32 + ix) * 16 + ci0];
                acc = __builtin_amdgcn_mfma_f32_16x16x32_f16(afrag, bfrag[p], acc, 0, 0, 0);
            }
            accs[s] = acc;
            #pragma unroll
            for (int rg = 0; rg < 4; rg++){ ssum += acc[rg]; ssq += acc[rg] * acc[rg]; }
        }
        __syncthreads();
        #pragma unroll
        for (int s = 0; s < 4; s++){
            int tid = wv * 4 + s;
            int y = tid >> 1, x0 = (tid & 1) * 16;
            #pragma unroll
            for (int rg = 0; rg < 4; rg++){
                int px = x0 + 4 * g + rg;
                bufA[(y * 32 + px) * 16 + col] = __float2half(accs[s][rg]);
            }
        }
        // stats (exact, block-local)
        ssum += __shfl_xor(ssum, 16); ssq += __shfl_xor(ssq, 16);
        ssum += __shfl_xor(ssum, 32); ssq += __shfl_xor(ssq, 32);
        if (lane < 16){ sred2[0][wv][lane] = ssum; sred2[1][wv][lane] = ssq; }
        __syncthreads();
        if (t < 16){
            float s = 0.f, q = 0.f;
            #pragma unroll
            for (int k = 0; k < 16; k++){ s += sred2[0][k][t]; q += sred2[1][k][t]; }
            float mean = s * (1.f / 1024.f);
            float var = q * (1.f / 1024.f) - mean * mean;
            snm[t] = mean;
            snm[16 + t] = rsqrtf(var + 1e-5f);
        }
    }
    __syncthreads();

    // final gelu pass (act6 normalized with stats7)
    #pragma unroll
    for (int i2 = 0; i2 < 2; i2++){
        int i = t + 1024 * i2;
        uint4 u = ((uint4*)bufA)[i];
        int ch0 = (i & 1) * 8;
        unsigned* pu = reinterpret_cast<unsigned*>(&u);
        #pragma unroll
        for (int q = 0; q < 4; q++){
            __half2 hh = *reinterpret_cast<__half2*>(&pu[q]);
            float2 f = __half22float2(hh);
            float a0 = gelu_tanh((f.x - snm[ch0 + 2*q])   * snm[16 + ch0 + 2*q]);
            float a1 = gelu_tanh((f.y - snm[ch0 + 2*q+1]) * snm[16 + ch0 + 2*q+1]);
            __half2 o = __floats2half2_rn(a0, a1);
            pu[q] = *reinterpret_cast<unsigned*>(&o);
        }
        ((uint4*)bufB)[i] = u;
    }
    if (t < 288) swl[t] = w_last[t];
    if (t < 2) sbl[t] = b_last[t];
    __syncthreads();

    // conv_last (16->2) + tanh + cps; one thread per pixel
    {
        int i = t >> 5, j = t & 31;
        float a0 = sbl[0], a1 = sbl[1];
        #pragma unroll
        for (int ky = 0; ky < 3; ky++){
            int iy = i + ky - 1;
            if (iy < 0 || iy >= 32) continue;
            #pragma unroll
            for (int kx = 0; kx < 3; kx++){
                int ix = j + kx - 1;
                if (ix < 0 || ix >= 32) continue;
                const __half* ip = &bufB[(iy * 32 + ix) * 16];
                const float* wp = swl + (ky * 3 + kx) * 32;
                #pragma unroll
                for (int ci = 0; ci < 16; ci++){
                    float v = __half2float(ip[ci]);
                    a0 += v * wp[ci * 2];
                    a1 += v * wp[ci * 2 + 1];
                }
            }
        }
        float cy = (float)(i * 16) + tanhf(a0) * 8.f;
        float cx = (float)(j * 16) + tanhf(a1) * 8.f;
        float* cp = cps + (((size_t)b * 33 + i) * 33 + j) * 2;
        cp[0] = cy;
        cp[1] = cx;
    }
    // padded grid entries (row i=32: 33 entries; col j=32: 32 entries)
    if (t < 65){
        int i, j;
        if (t < 33){ i = 32; j = t; }
        else { i = t - 33; j = 32; }
        float* cp = cps + (((size_t)b * 33 + i) * 33 + j) * 2;
        cp[0] = (float)(i * 16);
        cp[1] = (float)(j * 16);
    }
}

// ---------------- Merged losses: blocks [0,4096) area, [4096,4165) edge ----------------
__device__ __forceinline__ float farid_at(const float* __restrict__ ib, int y, int x){
    const float fp[5] = {0.03032f, 0.249724f, 0.439911f, 0.249724f, 0.03032f};
    const float fd[5] = {0.10455f, 0.292315f, 0.0f, -0.292315f, -0.10455f};
    float gxx = 0.f, gyy = 0.f;
    #pragma unroll
    for (int i = 0; i < 5; i++){
        int yy = y + i - 2;
        if (yy < 0 || yy >= HH) continue;
        #pragma unroll
        for (int j = 0; j < 5; j++){
            int xx = x + j - 2;
            if (xx < 0 || xx >= WW) continue;
            float v = ib[yy * WW + xx];
            gxx += fp[i] * fd[j] * v;
            gyy += fd[i] * fp[j] * v;
        }
    }
    return sqrtf(gxx * gxx + gyy * gyy + 1e-8f);
}

__global__ __launch_bounds__(256) void losses_kernel(
        const float* __restrict__ img, const float* __restrict__ cps,
        float* __restrict__ acc){
    __shared__ float sh[256];
    int t = threadIdx.x;
    if (blockIdx.x < 4096){
        // ---- area loss: 16-lane group per area ----
        int lane = t & 63;
        int wv = t >> 6;
        int g = lane >> 4;
        int l2 = lane & 15;
        int aidx = blockIdx.x * 16 + wv * 4 + g;
        int b = aidx >> 12;
        int rem = aidx & 4095;
        int o = rem >> 10;
        int ar = rem & 1023;
        int by = ar >> 5;
        int bx = ar & 31;
        int sy = (o & 2) ? 8 : 0;
        int sx = (o & 1) ? 8 : 0;
        float cpy = cps[((b * 33 + by) * 33 + bx) * 2 + 0];
        float cpx = cps[((b * 33 + by) * 33 + bx) * 2 + 1];
        int y0 = sy - 8 + by * 16;
        int x0 = sx - 8 + bx * 16;
        int x = x0 + l2;
        bool xok = (x >= 0 && x < WW);
        float dx = (float)x - cpx;
        float dx2 = dx * dx;
        float A = 0.f, Bs = 0.f, C = 0.f, D = 0.f, E = 0.f;
        #pragma unroll
        for (int k = 0; k < 16; k++){
            int y = y0 + k;
            float r = 0.f;
            if (xok && y >= 0 && y < HH)
                r = img[((size_t)b * HH + y) * WW + x];
            float dy = (float)y - cpy;
            float m = __expf(-(dy * dy + dx2) * (1.f / 128.f));
            m = diff_round(diff_round(m));
            float rm = r * m;
            float m2 = m * m;
            A += m; Bs += rm; E += m2;
            D += rm * m2;
            C += rm * rm * m2;
        }
        #pragma unroll
        for (int off = 8; off >= 1; off >>= 1){
            A  += __shfl_xor(A, off);
            Bs += __shfl_xor(Bs, off);
            C  += __shfl_xor(C, off);
            D  += __shfl_xor(D, off);
            E  += __shfl_xor(E, off);
        }
        if (l2 == 0){
            float rden = __builtin_amdgcn_rcpf(A + 1e-7f);
            float mean = (Bs + 256.f * 1e-7f) * rden;
            float sdev = C - 2.f * mean * D + mean * mean * E;
            sh[wv * 4 + g] = (sdev + 256.f * 1e-7f) * rden;
        }
        __syncthreads();
        if (t == 0){
            float s = 0.f;
            #pragma unroll
            for (int i2 = 0; i2 < 16; i2++) s += sh[i2];
            atomicAdd(&acc[blockIdx.x & 63], s);
        }
    } else {
        // ---- edge loss (farid recomputed inline) ----
        int idx = (blockIdx.x - 4096) * 256 + t;
        float v = 0.f;
        if (idx < BB * 1089){
            int b = idx / 1089;
            int p = idx % 1089;
            float y = cps[((size_t)b * 1089 + p) * 2 + 0];
            float x = cps[((size_t)b * 1089 + p) * 2 + 1];
            y = fminf(fmaxf(y, 0.f), 510.999f);
            x = fminf(fmaxf(x, 0.f), 510.999f);
            int y0 = (int)floorf(y);
            int x0 = (int)floorf(x);
            float wy = y - (float)y0;
            float wx = x - (float)x0;
            const float* ib = img + (size_t)b * HH * WW;
            float v00 = farid_at(ib, y0, x0);
            float v01 = farid_at(ib, y0, x0 + 1);
            float v10 = farid_at(ib, y0 + 1, x0);
            float v11 = farid_at(ib, y0 + 1, x0 + 1);
            v = v00 * (1 - wy) * (1 - wx) + v01 * (1 - wy) * wx + v10 * wy * (1 - wx) + v11 * wy * wx;
        }
        sh[t] = v;
        __syncthreads();
        for (int off = 128; off > 0; off >>= 1){
            if (t < off) sh[t] += sh[t + off];
            __syncthreads();
        }
        if (t == 0) atomicAdd(&acc[64 + (blockIdx.x & 3)], sh[0]);
    }
}

__global__ void finalize_kernel(const float* __restrict__ lacc, float* __restrict__ out){
    float a = 0.f, e = 0.f;
    for (int i = 0; i < 64; i++) a += lacc[i];
    for (int i = 0; i < 4; i++) e += lacc[64 + i];
    out[0] = (a / 65536.f) * (e / 17424.f);
}

extern "C" void kernel_launch(void* const* d_in, const int* in_sizes, int n_in,
                              void* d_out, int out_size, void* d_ws, size_t ws_size,
                              hipStream_t stream) {
    const float* image  = (const float*)d_in[0];
    const float* w_first= (const float*)d_in[1];
    const float* b_first= (const float*)d_in[2];
    const float* w_mid  = (const float*)d_in[3];
    const float* b_mid  = (const float*)d_in[4];
    const float* w_last = (const float*)d_in[5];
    const float* b_last = (const float*)d_in[6];
    float* out = (float*)d_out;
    char* ws = (char*)d_ws;

    // ---- workspace layout ----
    float* stats = (float*)ws;                 // 8 layers * 512 floats (0..4 used)
    float* lacc  = stats + 8 * 512;            // 128 floats
    size_t off = (8 * 512 + 128) * sizeof(float);
    __half* act1 = (__half*)(ws + off); off += (size_t)BB * 512 * 512 * 16 * 2;
    __half* act2 = (__half*)(ws + off); off += (size_t)BB * 256 * 256 * 16 * 2;
    __half* act3 = (__half*)(ws + off); off += (size_t)BB * 128 * 128 * 16 * 2;
    __half* act4 = (__half*)(ws + off); off += (size_t)BB * 64 * 64 * 16 * 2;
    __half* act5 = (__half*)(ws + off); off += (size_t)BB * 32 * 32 * 16 * 2;

    hipMemsetAsync(ws, 0, (8 * 512 + 128) * sizeof(float), stream);

    // fused farid (separable) + conv_first (MFMA) + stats0
    farid_conv_first_kernel<<<16 * 32 * 16, 256, 0, stream>>>(
        image, w_first, b_first, act1, stats + 0 * 512);

    // mid 0..3: stride-2, LDS-staged
    conv_mfma_s2_kernel<<<16 * 16 * 16, 256, 0, stream>>>(
        act1, w_mid + 0 * 2304, b_mid + 0, act2, stats + 0 * 512, stats + 1 * 512,
        512, 512, 256, 256);
    conv_mfma_s2_kernel<<<16 * 8 * 8, 256, 0, stream>>>(
        act2, w_mid + 1 * 2304, b_mid + 16, act3, stats + 1 * 512, stats + 2 * 512,
        256, 256, 128, 128);
    conv_mfma_s2_kernel<<<16 * 4 * 4, 256, 0, stream>>>(
        act3, w_mid + 2 * 2304, b_mid + 32, act4, stats + 2 * 512, stats + 3 * 512,
        128, 128, 64, 64);
    conv_mfma_s2_kernel<<<16 * 2 * 2, 256, 0, stream>>>(
        act4, w_mid + 3 * 2304, b_mid + 48, act5, stats + 3 * 512, stats + 4 * 512,
        64, 64, 32, 32);

    // tail: mid4+mid5+mid6+conv_last+cps in one kernel -> d_out[1..]
    float* cps_out = out + 1;
    tail_kernel<<<16, 1024, 0, stream>>>(
        act5, stats + 4 * 512, w_mid, b_mid, w_last, b_last, cps_out);

    // merged losses + finalize
    losses_kernel<<<4096 + 69, 256, 0, stream>>>(image, cps_out, lacc);
    finalize_kernel<<<1, 1, 0, stream>>>(lacc, out);
}